// Round 13
// baseline (5033.392 us; speedup 1.0000x reference)
//
#include <hip/hip_runtime.h>
#include <hip/hip_bf16.h>

#define NEG 0.2f

typedef __attribute__((ext_vector_type(8))) short short8;  // 8 bf16 (4 VGPR)
typedef __attribute__((ext_vector_type(4))) float f32x4;

// bf16 helpers (manual RNE pack / unpack, branch-free, no NaN inputs here)
__device__ __forceinline__ unsigned short f2bf(float f) {
    unsigned u = __float_as_uint(f);
    u += 0x7fffu + ((u >> 16) & 1u);
    return (unsigned short)(u >> 16);
}
__device__ __forceinline__ unsigned pack2bf(float a, float b) {
    return (unsigned)f2bf(a) | ((unsigned)f2bf(b) << 16);
}
__device__ __forceinline__ float bflo(unsigned u) { return __uint_as_float(u << 16); }
__device__ __forceinline__ float bfhi(unsigned u) { return __uint_as_float(u & 0xffff0000u); }

__device__ __forceinline__ short8 asfrag(uint4 v) {
    union { uint4 u; short8 s; } x; x.u = v; return x.s;
}
__device__ __forceinline__ f32x4 mfma_bf16(short8 a, short8 b, f32x4 c) {
    return __builtin_amdgcn_mfma_f32_16x16x32_bf16(a, b, c, 0, 0, 0);
}
__device__ __forceinline__ float tanh_fast(float x) {
    x = fminf(fmaxf(x, -15.f), 15.f);
    float t = __expf(2.f * x);
    return (t - 1.f) / (t + 1.f);
}

// ---------------------------------------------------------------------------
// P0: pre-pack weight matrices into MFMA B-fragment order (once).
// block 0: proj_w [128x128], block 1: k_w [128x128], block 2: out_w [128x64].
// ---------------------------------------------------------------------------
__global__ __launch_bounds__(256) void prep_bfrag(
    const float* __restrict__ pw, const float* __restrict__ kw,
    const float* __restrict__ ow,
    uint4* __restrict__ bfpw, uint4* __restrict__ bfkw, uint4* __restrict__ bfow)
{
    int b = blockIdx.x;
    const float* src = (b == 0) ? pw : (b == 1) ? kw : ow;
    uint4* dst = (b == 0) ? bfpw : (b == 1) ? bfkw : bfow;
    int ncol  = (b == 2) ? 64 : 128;
    int slots = (b == 2) ? 1024 : 2048;
    for (int i = threadIdx.x; i < slots; i += 256) {
        int nt = i >> 8, kt = (i >> 6) & 3, lane = i & 63;
        int row0 = kt * 32 + ((lane >> 4) << 3);
        int col  = nt * 16 + (lane & 15);
        float e[8];
        #pragma unroll
        for (int j = 0; j < 8; ++j) e[j] = src[(row0 + j) * ncol + col];
        uint4 v;
        v.x = pack2bf(e[0], e[1]); v.y = pack2bf(e[2], e[3]);
        v.z = pack2bf(e[4], e[5]); v.w = pack2bf(e[6], e[7]);
        dst[i] = v;
    }
}

// ---------------------------------------------------------------------------
// K1: h = bf16(x) @ bf16(proj_w) + proj_b via MFMA; store h bf16.
// ---------------------------------------------------------------------------
__global__ __launch_bounds__(256) void proj_mfma(
    const float* __restrict__ x, const uint4* __restrict__ bfg,
    const float* __restrict__ pb, unsigned short* __restrict__ hst, int N)
{
    __shared__ uint4 Bf[2048];   // 32 KB
    __shared__ float pbs[128];
    int t = threadIdx.x;
    for (int i = t; i < 2048; i += 256) Bf[i] = bfg[i];
    if (t < 128) pbs[t] = pb[t];
    __syncthreads();
    int wid = t >> 6, l = t & 63, l15 = l & 15, lhi = l >> 4;
    float bv[8];
    #pragma unroll
    for (int nt = 0; nt < 8; ++nt) bv[nt] = pbs[nt * 16 + l15];
    int ntiles = (N + 15) >> 4;
    const float4* X4 = reinterpret_cast<const float4*>(x);
    for (int rt = blockIdx.x * 4 + wid; rt < ntiles; rt += gridDim.x * 4) {
        int row = rt * 16 + l15;
        f32x4 acc[8];
        #pragma unroll
        for (int nt = 0; nt < 8; ++nt) acc[nt] = (f32x4)(0.f);
        #pragma unroll
        for (int kt = 0; kt < 4; ++kt) {
            uint4 af = make_uint4(0u, 0u, 0u, 0u);
            if (row < N) {
                float4 xa = X4[(size_t)row * 32 + kt * 8 + lhi * 2];
                float4 xb = X4[(size_t)row * 32 + kt * 8 + lhi * 2 + 1];
                af.x = pack2bf(xa.x, xa.y); af.y = pack2bf(xa.z, xa.w);
                af.z = pack2bf(xb.x, xb.y); af.w = pack2bf(xb.z, xb.w);
            }
            short8 a = asfrag(af);
            #pragma unroll
            for (int nt = 0; nt < 8; ++nt)
                acc[nt] = mfma_bf16(a, asfrag(Bf[nt * 256 + kt * 64 + l]), acc[nt]);
        }
        #pragma unroll
        for (int r = 0; r < 4; ++r) {
            int orow = rt * 16 + lhi * 4 + r;
            if (orow < N) {
                #pragma unroll
                for (int nt = 0; nt < 8; ++nt)
                    hst[(size_t)orow * 128 + nt * 16 + l15] = f2bf(acc[nt][r] + bv[nt]);
            }
        }
    }
}

// ---------------------------------------------------------------------------
// K2: per-node attention coefficients from bf16 h (memory-bound).
// ---------------------------------------------------------------------------
__global__ __launch_bounds__(256) void alpha_kernel(
    const unsigned* __restrict__ hbf,
    const float* __restrict__ ls0, const float* __restrict__ ld0,
    const float* __restrict__ ls1, const float* __restrict__ ld1,
    float* __restrict__ as0, float* __restrict__ ad0,
    float* __restrict__ as1, float* __restrict__ ad1, int N)
{
    __shared__ float lin[512];
    int t = threadIdx.x;
    for (int i = t; i < 128; i += 256) {
        lin[i] = ls0[i]; lin[128 + i] = ld0[i];
        lin[256 + i] = ls1[i]; lin[384 + i] = ld1[i];
    }
    __syncthreads();
    int idx = blockIdx.x * 256 + t;
    if (idx >= N * 8) return;
    int node = idx >> 3, head = idx & 7;
    const uint4* H = reinterpret_cast<const uint4*>(hbf);
    uint4 va = H[(size_t)node * 16 + head * 2];
    uint4 vb = H[(size_t)node * 16 + head * 2 + 1];
    float h[16];
    h[0] = bflo(va.x); h[1] = bfhi(va.x); h[2] = bflo(va.y); h[3] = bfhi(va.y);
    h[4] = bflo(va.z); h[5] = bfhi(va.z); h[6] = bflo(va.w); h[7] = bfhi(va.w);
    h[8] = bflo(vb.x); h[9] = bfhi(vb.x); h[10] = bflo(vb.y); h[11] = bfhi(vb.y);
    h[12] = bflo(vb.z); h[13] = bfhi(vb.z); h[14] = bflo(vb.w); h[15] = bfhi(vb.w);
    int base = head * 16;
    float d0 = 0.f, d1 = 0.f, d2 = 0.f, d3 = 0.f;
    #pragma unroll
    for (int d = 0; d < 16; ++d) {
        float hv = h[d];
        d0 = fmaf(hv, lin[base + d], d0);
        d1 = fmaf(hv, lin[128 + base + d], d1);
        d2 = fmaf(hv, lin[256 + base + d], d2);
        d3 = fmaf(hv, lin[384 + base + d], d3);
    }
    as0[idx] = d0; ad0[idx] = d1; as1[idx] = d2; ad1[idx] = d3;
}

// ---------------------------------------------------------------------------
// CSR build v4: ballot-based single-pass partition (no LDS atomics), packed
// u32 staging (15-bit region-local dst | 17-bit src).  Per 64-edge wave tile
// and region: one leader atomicAdd reserves the span; lanes compute their
// slot via popcount of the ballot mask.  hist2/fill2 then scatter within
// L2-resident region slices (temporal+spatial locality).
// ---------------------------------------------------------------------------
__global__ __launch_bounds__(256) void partition_kernel(
    const int* __restrict__ ei0, int E0, const int* __restrict__ ei1, int E1,
    unsigned* __restrict__ stage, int cap, int* __restrict__ regionCur, int rsize)
{
    int mp = blockIdx.x & 1;
    int b  = blockIdx.x >> 1;
    const int* ei = mp ? ei1 : ei0;
    int E = mp ? E1 : E0;
    unsigned* st = stage + (size_t)mp * 8 * cap;
    int* rc = regionCur + mp * 8;
    int lane = threadIdx.x & 63;
    int nwaves = (gridDim.x >> 1) * 4;
    int gw = b * 4 + (threadIdx.x >> 6);
    for (int base = gw * 64; base < E; base += nwaves * 64) {
        int e = base + lane;
        bool valid = e < E;
        int d = valid ? ei[E + e] : 0;
        int s = valid ? ei[e] : 0;
        int r = valid ? (d / rsize) : 8;
        unsigned packed = ((unsigned)(d - r * rsize) << 17) | (unsigned)s;
        #pragma unroll
        for (int rr = 0; rr < 8; ++rr) {
            unsigned long long mask = __ballot(r == rr);
            if (mask == 0ull) continue;          // wave-uniform
            int cnt = __popcll(mask);
            int leader = __ffsll((unsigned long long)mask) - 1;
            int gbase = 0;
            if (lane == leader) gbase = atomicAdd(&rc[rr], cnt);
            gbase = __shfl(gbase, leader);
            if (r == rr) {
                int pos = __popcll(mask & ((1ull << lane) - 1ull));
                st[(size_t)rr * cap + gbase + pos] = packed;
            }
        }
    }
}

__global__ __launch_bounds__(256) void hist2_kernel(
    const unsigned* __restrict__ stage, int cap, const int* __restrict__ regionCur,
    int* __restrict__ deg0, int* __restrict__ deg1, int rsize)
{
    int r = blockIdx.x & 7;
    int mp = (blockIdx.x >> 3) & 1;
    int sub = blockIdx.x >> 4;                // 0..127
    const unsigned* st = stage + ((size_t)mp * 8 + r) * cap;
    int cnt = regionCur[mp * 8 + r];
    int dbase = r * rsize;
    int* deg = mp ? deg1 : deg0;
    for (int i = sub * 256 + threadIdx.x; i < cnt; i += 128 * 256)
        atomicAdd(&deg[dbase + (int)(st[i] >> 17)], 1);
}

__global__ __launch_bounds__(256) void fill2_kernel(
    const unsigned* __restrict__ stage, int cap, const int* __restrict__ regionCur,
    const int* __restrict__ off0, int* __restrict__ cur0, int* __restrict__ perm0,
    const int* __restrict__ off1, int* __restrict__ cur1, int* __restrict__ perm1,
    int rsize)
{
    int r = blockIdx.x & 7;
    int mp = (blockIdx.x >> 3) & 1;
    int sub = blockIdx.x >> 4;                // 0..127
    const unsigned* st = stage + ((size_t)mp * 8 + r) * cap;
    int cnt = regionCur[mp * 8 + r];
    int dbase = r * rsize;
    const int* off = mp ? off1 : off0;
    int* cur = mp ? cur1 : cur0;
    int* perm = mp ? perm1 : perm0;
    for (int i = sub * 256 + threadIdx.x; i < cnt; i += 128 * 256) {
        unsigned v = st[i];
        int d = dbase + (int)(v >> 17);
        int s = (int)(v & 0x1FFFFu);
        int pos = atomicAdd(&cur[d], 1);
        perm[off[d] + pos] = s;
    }
}

// ---------------------------------------------------------------------------
// Scans (fused over both metapaths).
// ---------------------------------------------------------------------------
__global__ __launch_bounds__(256) void scan1_fused(
    const int* __restrict__ in0, int* __restrict__ out0,
    const int* __restrict__ in1, int* __restrict__ out1,
    int* __restrict__ bsums, int n, int nb)
{
    __shared__ int sh[256];
    int mp = (blockIdx.x >= (unsigned)nb);
    int blk = blockIdx.x - (mp ? nb : 0);
    const int* in = mp ? in1 : in0;
    int* out = mp ? out1 : out0;
    int t = threadIdx.x;
    int i = blk * 256 + t;
    int v = (i < n) ? in[i] : 0;
    sh[t] = v;
    __syncthreads();
    for (int ofs = 1; ofs < 256; ofs <<= 1) {
        int xv = (t >= ofs) ? sh[t - ofs] : 0;
        __syncthreads();
        sh[t] += xv;
        __syncthreads();
    }
    if (i < n) out[i] = sh[t] - v;          // exclusive
    if (t == 255) bsums[mp * 512 + blk] = sh[255];
}

__global__ __launch_bounds__(512) void scan2_fused(int* __restrict__ bs, int nb)
{
    __shared__ int sh[512];
    int t = threadIdx.x;
    int* b = bs + blockIdx.x * 512;
    int v = (t < nb) ? b[t] : 0;
    sh[t] = v;
    __syncthreads();
    for (int ofs = 1; ofs < 512; ofs <<= 1) {
        int xv = (t >= ofs) ? sh[t - ofs] : 0;
        __syncthreads();
        sh[t] += xv;
        __syncthreads();
    }
    if (t < nb) b[t] = sh[t] - v;          // exclusive
}

__global__ __launch_bounds__(256) void scan3_fused(
    int* __restrict__ out0, int* __restrict__ out1,
    const int* __restrict__ bs, int n, int nb)
{
    int mp = (blockIdx.x >= (unsigned)nb);
    int blk = blockIdx.x - (mp ? nb : 0);
    int* out = mp ? out1 : out0;
    int i = blk * 256 + threadIdx.x;
    if (i < n) out[i] += bs[mp * 512 + blk];
}

// ---------------------------------------------------------------------------
// K3: per-destination aggregation (fused mp0+mp1), lane-specialized weights.
// One 64-lane wave per (mp, node); lane owns dims {2*lane, 2*lane+1}.
// ---------------------------------------------------------------------------
__global__ __launch_bounds__(256) void agg_fused(
    const int* __restrict__ off0, const int* __restrict__ perm0,
    const float* __restrict__ as0, const float* __restrict__ ad0,
    const int* __restrict__ off1, const int* __restrict__ perm1,
    const float* __restrict__ as1, const float* __restrict__ ad1,
    const unsigned* __restrict__ hbf,
    unsigned* __restrict__ o0, unsigned* __restrict__ o1, int N)
{
    int mp = blockIdx.x & 1;
    int wid = (blockIdx.x >> 1) * 4 + (threadIdx.x >> 6);
    int lane = threadIdx.x & 63;
    if (wid >= N) return;
    const int* off = mp ? off1 : off0;
    const int* perm = mp ? perm1 : perm0;
    const float* asrc = mp ? as1 : as0;
    const float* adst = mp ? ad1 : ad0;
    unsigned* outm = mp ? o1 : o0;
    int start = off[wid], end = off[wid + 1];
    int h2 = lane >> 3;            // head: owns dims AND weight computation
    int esel = lane & 7;           // edge slot this lane computes weight for
    int wsrc = lane & 56;          // shuffle base: lane (wsrc|k) holds w[k][h2]
    float av = adst[wid * 8 + h2];
    float p0 = 0.f, p1 = 0.f, q0 = 0.f, q1 = 0.f;
    float sA = 0.f, sB = 0.f;
    for (int i = start; i < end; i += 8) {
        int idx = i + esel;
        int sm = perm[idx < end ? idx : start];
        float alv = asrc[sm * 8 + h2] + av;
        alv = alv > 0.f ? alv : NEG * alv;
        float wm = (idx < end) ? __expf(alv) : 0.f;
        #pragma unroll
        for (int k = 0; k < 8; ++k) {
            int sk = __shfl(sm, k);                 // perm[i+k]
            float wk = __shfl(wm, wsrc | k);        // weight for (edge k, h2)
            unsigned u = hbf[(unsigned)(sk * 64) + lane];
            if (k & 1) {
                q0 = fmaf(bflo(u), wk, q0);
                q1 = fmaf(bfhi(u), wk, q1);
                sB += wk;
            } else {
                p0 = fmaf(bflo(u), wk, p0);
                p1 = fmaf(bfhi(u), wk, p1);
                sA += wk;
            }
        }
    }
    float acc0 = p0 + q0, acc1 = p1 + q1, ssum = sA + sB;
    float inv = 1.f / (ssum + 1e-16f);
    acc0 *= inv; acc1 *= inv;
    acc0 = acc0 > 0.f ? acc0 : 0.f;   // relu
    acc1 = acc1 > 0.f ? acc1 : 0.f;
    outm[(size_t)wid * 64 + lane] = pack2bf(acc0, acc1);
}

// ---------------------------------------------------------------------------
// K4: semantic-attention scores via MFMA over bf16 out0/out1.
// ---------------------------------------------------------------------------
__global__ __launch_bounds__(256) void score_mfma(
    const unsigned* __restrict__ o0, const unsigned* __restrict__ o1,
    const uint4* __restrict__ bfg, const float* __restrict__ kb,
    const float* __restrict__ q, float* __restrict__ partials, int N)
{
    __shared__ uint4 Bf[2048];   // 32 KB (k_w fragments)
    __shared__ float kbs[128], qs[128];
    __shared__ float red[2];
    int t = threadIdx.x;
    for (int i = t; i < 2048; i += 256) Bf[i] = bfg[i];
    if (t < 128) { kbs[t] = kb[t]; qs[t] = q[t]; }
    if (t < 2) red[t] = 0.f;
    __syncthreads();
    int wid = t >> 6, l = t & 63, l15 = l & 15, lhi = l >> 4;
    float qv[8], kbv[8];
    #pragma unroll
    for (int nt = 0; nt < 8; ++nt) {
        qv[nt] = qs[nt * 16 + l15];
        kbv[nt] = kbs[nt * 16 + l15];
    }
    int ntiles = (N + 15) >> 4;
    int ttiles = 2 * ntiles;
    const uint4* A0 = reinterpret_cast<const uint4*>(o0);
    const uint4* A1 = reinterpret_cast<const uint4*>(o1);
    for (int tid = blockIdx.x * 4 + wid; tid < ttiles; tid += gridDim.x * 4) {
        int m = (tid >= ntiles);
        int rt = tid - (m ? ntiles : 0);
        const uint4* A = m ? A1 : A0;
        int row = rt * 16 + l15;
        f32x4 acc[8];
        #pragma unroll
        for (int nt = 0; nt < 8; ++nt) acc[nt] = (f32x4)(0.f);
        #pragma unroll
        for (int kt = 0; kt < 4; ++kt) {
            uint4 av = (row < N) ? A[(size_t)row * 16 + kt * 4 + lhi]
                                 : make_uint4(0u, 0u, 0u, 0u);
            short8 a = asfrag(av);
            #pragma unroll
            for (int nt = 0; nt < 8; ++nt)
                acc[nt] = mfma_bf16(a, asfrag(Bf[nt * 256 + kt * 64 + l]), acc[nt]);
        }
        float partial = 0.f;
        int rbase = rt * 16 + lhi * 4;
        #pragma unroll
        for (int r = 0; r < 4; ++r) {
            if (rbase + r < N) {
                #pragma unroll
                for (int nt = 0; nt < 8; ++nt)
                    partial += qv[nt] * tanh_fast(acc[nt][r] + kbv[nt]);
            }
        }
        partial += __shfl_xor(partial, 1);
        partial += __shfl_xor(partial, 2);
        partial += __shfl_xor(partial, 4);
        partial += __shfl_xor(partial, 8);
        partial += __shfl_xor(partial, 16);
        partial += __shfl_xor(partial, 32);
        if (l == 0) atomicAdd(&red[m], partial);
    }
    __syncthreads();
    if (t < 2) partials[blockIdx.x * 2 + t] = red[t];
}

__global__ __launch_bounds__(256) void beta_kernel(
    const float* __restrict__ partials, int G, float invN, float* __restrict__ beta)
{
    __shared__ float r0[256], r1[256];
    int t = threadIdx.x;
    float s0 = 0.f, s1 = 0.f;
    for (int i = t; i < G; i += 256) { s0 += partials[i * 2]; s1 += partials[i * 2 + 1]; }
    r0[t] = s0; r1[t] = s1; __syncthreads();
    for (int o = 128; o > 0; o >>= 1) {
        if (t < o) { r0[t] += r0[t + o]; r1[t] += r1[t + o]; }
        __syncthreads();
    }
    if (t == 0) {
        float a = r0[0] * invN, b = r1[0] * invN;
        float mx = fmaxf(a, b);
        float ea = __expf(a - mx), eb = __expf(b - mx);
        float inv = 1.f / (ea + eb);
        beta[0] = ea * inv; beta[1] = eb * inv;
    }
}

// ---------------------------------------------------------------------------
// K6: y = (b0*out0 + b1*out1) @ out_w + out_b via MFMA (f32 output).
// ---------------------------------------------------------------------------
__global__ __launch_bounds__(256) void final_mfma(
    const unsigned* __restrict__ o0, const unsigned* __restrict__ o1,
    const uint4* __restrict__ bfg, const float* __restrict__ ob,
    const float* __restrict__ beta, float* __restrict__ y, int N)
{
    __shared__ uint4 Bf[1024];   // 16 KB (out_w fragments)
    __shared__ float obs[64];
    int t = threadIdx.x;
    for (int i = t; i < 1024; i += 256) Bf[i] = bfg[i];
    if (t < 64) obs[t] = ob[t];
    __syncthreads();
    float b0 = beta[0], b1 = beta[1];
    int wid = t >> 6, l = t & 63, l15 = l & 15, lhi = l >> 4;
    float obv[4];
    #pragma unroll
    for (int nt = 0; nt < 4; ++nt) obv[nt] = obs[nt * 16 + l15];
    int ntiles = (N + 15) >> 4;
    const uint4* A0 = reinterpret_cast<const uint4*>(o0);
    const uint4* A1 = reinterpret_cast<const uint4*>(o1);
    for (int rt = blockIdx.x * 4 + wid; rt < ntiles; rt += gridDim.x * 4) {
        int row = rt * 16 + l15;
        f32x4 acc[4];
        #pragma unroll
        for (int nt = 0; nt < 4; ++nt) acc[nt] = (f32x4)(0.f);
        #pragma unroll
        for (int kt = 0; kt < 4; ++kt) {
            uint4 af = make_uint4(0u, 0u, 0u, 0u);
            if (row < N) {
                uint4 a0 = A0[(size_t)row * 16 + kt * 4 + lhi];
                uint4 a1 = A1[(size_t)row * 16 + kt * 4 + lhi];
                af.x = pack2bf(b0 * bflo(a0.x) + b1 * bflo(a1.x),
                               b0 * bfhi(a0.x) + b1 * bfhi(a1.x));
                af.y = pack2bf(b0 * bflo(a0.y) + b1 * bflo(a1.y),
                               b0 * bfhi(a0.y) + b1 * bfhi(a1.y));
                af.z = pack2bf(b0 * bflo(a0.z) + b1 * bflo(a1.z),
                               b0 * bfhi(a0.z) + b1 * bfhi(a1.z));
                af.w = pack2bf(b0 * bflo(a0.w) + b1 * bflo(a1.w),
                               b0 * bfhi(a0.w) + b1 * bfhi(a1.w));
            }
            short8 a = asfrag(af);
            #pragma unroll
            for (int nt = 0; nt < 4; ++nt)
                acc[nt] = mfma_bf16(a, asfrag(Bf[nt * 256 + kt * 64 + l]), acc[nt]);
        }
        #pragma unroll
        for (int r = 0; r < 4; ++r) {
            int orow = rt * 16 + lhi * 4 + r;
            if (orow < N) {
                #pragma unroll
                for (int nt = 0; nt < 4; ++nt)
                    y[(size_t)orow * 64 + nt * 16 + l15] = acc[nt][r] + obv[nt];
            }
        }
    }
}

// ---------------------------------------------------------------------------
extern "C" void kernel_launch(void* const* d_in, const int* in_sizes, int n_in,
                              void* d_out, int out_size, void* d_ws, size_t ws_size,
                              hipStream_t stream)
{
    const float* x   = (const float*)d_in[0];
    const int*   ei0 = (const int*)d_in[1];
    const int*   ei1 = (const int*)d_in[2];
    const float* pw  = (const float*)d_in[3];
    const float* pb  = (const float*)d_in[4];
    const float* ls0 = (const float*)d_in[5];
    const float* ld0 = (const float*)d_in[6];
    const float* ls1 = (const float*)d_in[7];
    const float* ld1 = (const float*)d_in[8];
    const float* kw  = (const float*)d_in[9];
    const float* kb  = (const float*)d_in[10];
    const float* q   = (const float*)d_in[11];
    const float* ow  = (const float*)d_in[12];
    const float* ob  = (const float*)d_in[13];
    int N  = in_sizes[0] / 128;
    int E0 = in_sizes[1] / 2;
    int E1 = in_sizes[2] / 2;

    char* w = (char*)d_ws;
    size_t o = 0;
    auto alloc = [&](size_t bytes) -> void* {
        void* p = w + o;
        o += (bytes + 255) & ~(size_t)255;
        return p;
    };
    unsigned* hbf  = (unsigned*)alloc((size_t)N * 128 * 2);   // bf16 h
    float* as0  = (float*)alloc((size_t)N * 8 * 4);
    float* ad0  = (float*)alloc((size_t)N * 8 * 4);
    float* as1  = (float*)alloc((size_t)N * 8 * 4);
    float* ad1  = (float*)alloc((size_t)N * 8 * 4);
    unsigned* out0 = (unsigned*)alloc((size_t)N * 128 * 2);   // bf16 out
    unsigned* out1 = (unsigned*)alloc((size_t)N * 128 * 2);
    char*  zbase = w + o;                       // contiguous zeroed region
    int* deg0 = (int*)alloc((size_t)(N + 1) * 4);
    int* cur0 = (int*)alloc((size_t)N * 4);
    int* deg1 = (int*)alloc((size_t)(N + 1) * 4);
    int* cur1 = (int*)alloc((size_t)N * 4);
    int* regionCur = (int*)alloc(16 * 4);
    size_t zbytes = (w + o) - zbase;
    int* off0 = (int*)alloc((size_t)(N + 1) * 4);
    int* off1 = (int*)alloc((size_t)(N + 1) * 4);
    int* bsums = (int*)alloc(1024 * 4);
    int* perm0 = (int*)alloc((size_t)E0 * 4);
    int* perm1 = (int*)alloc((size_t)E1 * 4);
    float* partials = (float*)alloc((size_t)2 * 2048 * 4);
    float* beta = (float*)alloc(256);
    uint4* bfpw = (uint4*)alloc(2048 * 16);
    uint4* bfkw = (uint4*)alloc(2048 * 16);
    uint4* bfow = (uint4*)alloc(1024 * 16);
    int Emax = E0 > E1 ? E0 : E1;
    int cap = Emax / 8 + Emax / 16 + 1024;     // 1.5x expected + slack
    unsigned* stage = (unsigned*)alloc((size_t)2 * 8 * cap * 4);

    int rsize = (N + 7) / 8;   // dst-region size for XCD ownership

    hipMemsetAsync(zbase, 0, zbytes, stream);

    prep_bfrag<<<3, 256, 0, stream>>>(pw, kw, ow, bfpw, bfkw, bfow);

    proj_mfma<<<512, 256, 0, stream>>>(x, bfpw, pb, (unsigned short*)hbf, N);

    int ablocks = (N * 8 + 255) / 256;
    alpha_kernel<<<ablocks, 256, 0, stream>>>(hbf, ls0, ld0, ls1, ld1,
                                              as0, ad0, as1, ad1, N);

    partition_kernel<<<1024, 256, 0, stream>>>(ei0, E0, ei1, E1,
                                               stage, cap, regionCur, rsize);

    hist2_kernel<<<2048, 256, 0, stream>>>(stage, cap, regionCur,
                                           deg0, deg1, rsize);

    int n1 = N + 1;
    int nb = (n1 + 255) / 256;   // must be <= 512
    scan1_fused<<<2 * nb, 256, 0, stream>>>(deg0, off0, deg1, off1, bsums, n1, nb);
    scan2_fused<<<2, 512, 0, stream>>>(bsums, nb);
    scan3_fused<<<2 * nb, 256, 0, stream>>>(off0, off1, bsums, n1, nb);

    fill2_kernel<<<2048, 256, 0, stream>>>(stage, cap, regionCur,
                                           off0, cur0, perm0,
                                           off1, cur1, perm1, rsize);

    int aggBlocks = 2 * ((N + 3) / 4);
    agg_fused<<<aggBlocks, 256, 0, stream>>>(off0, perm0, as0, ad0,
                                             off1, perm1, as1, ad1,
                                             hbf, out0, out1, N);

    const int SG = 512;
    score_mfma<<<SG, 256, 0, stream>>>(out0, out1, bfkw, kb, q, partials, N);
    beta_kernel<<<1, 256, 0, stream>>>(partials, SG, 1.0f / (float)N, beta);
    final_mfma<<<512, 256, 0, stream>>>(out0, out1, bfow, ob, beta, (float*)d_out, N);
}

// Round 14
// 520.575 us; speedup vs baseline: 9.6689x; 9.6689x over previous
//
#include <hip/hip_runtime.h>
#include <hip/hip_bf16.h>

#define NEG 0.2f

typedef __attribute__((ext_vector_type(8))) short short8;  // 8 bf16 (4 VGPR)
typedef __attribute__((ext_vector_type(4))) float f32x4;

// bf16 helpers (manual RNE pack / unpack, branch-free, no NaN inputs here)
__device__ __forceinline__ unsigned short f2bf(float f) {
    unsigned u = __float_as_uint(f);
    u += 0x7fffu + ((u >> 16) & 1u);
    return (unsigned short)(u >> 16);
}
__device__ __forceinline__ unsigned pack2bf(float a, float b) {
    return (unsigned)f2bf(a) | ((unsigned)f2bf(b) << 16);
}
__device__ __forceinline__ float bflo(unsigned u) { return __uint_as_float(u << 16); }
__device__ __forceinline__ float bfhi(unsigned u) { return __uint_as_float(u & 0xffff0000u); }

__device__ __forceinline__ short8 asfrag(uint4 v) {
    union { uint4 u; short8 s; } x; x.u = v; return x.s;
}
__device__ __forceinline__ f32x4 mfma_bf16(short8 a, short8 b, f32x4 c) {
    return __builtin_amdgcn_mfma_f32_16x16x32_bf16(a, b, c, 0, 0, 0);
}
__device__ __forceinline__ float tanh_fast(float x) {
    x = fminf(fmaxf(x, -15.f), 15.f);
    float t = __expf(2.f * x);
    return (t - 1.f) / (t + 1.f);
}

// ---------------------------------------------------------------------------
// P0: pre-pack weight matrices into MFMA B-fragment order (once).
// block 0: proj_w [128x128], block 1: k_w [128x128], block 2: out_w [128x64].
// ---------------------------------------------------------------------------
__global__ __launch_bounds__(256) void prep_bfrag(
    const float* __restrict__ pw, const float* __restrict__ kw,
    const float* __restrict__ ow,
    uint4* __restrict__ bfpw, uint4* __restrict__ bfkw, uint4* __restrict__ bfow)
{
    int b = blockIdx.x;
    const float* src = (b == 0) ? pw : (b == 1) ? kw : ow;
    uint4* dst = (b == 0) ? bfpw : (b == 1) ? bfkw : bfow;
    int ncol  = (b == 2) ? 64 : 128;
    int slots = (b == 2) ? 1024 : 2048;
    for (int i = threadIdx.x; i < slots; i += 256) {
        int nt = i >> 8, kt = (i >> 6) & 3, lane = i & 63;
        int row0 = kt * 32 + ((lane >> 4) << 3);
        int col  = nt * 16 + (lane & 15);
        float e[8];
        #pragma unroll
        for (int j = 0; j < 8; ++j) e[j] = src[(row0 + j) * ncol + col];
        uint4 v;
        v.x = pack2bf(e[0], e[1]); v.y = pack2bf(e[2], e[3]);
        v.z = pack2bf(e[4], e[5]); v.w = pack2bf(e[6], e[7]);
        dst[i] = v;
    }
}

// ---------------------------------------------------------------------------
// K1: h = bf16(x) @ bf16(proj_w) + proj_b via MFMA; store h bf16.
// ---------------------------------------------------------------------------
__global__ __launch_bounds__(256) void proj_mfma(
    const float* __restrict__ x, const uint4* __restrict__ bfg,
    const float* __restrict__ pb, unsigned short* __restrict__ hst, int N)
{
    __shared__ uint4 Bf[2048];   // 32 KB
    __shared__ float pbs[128];
    int t = threadIdx.x;
    for (int i = t; i < 2048; i += 256) Bf[i] = bfg[i];
    if (t < 128) pbs[t] = pb[t];
    __syncthreads();
    int wid = t >> 6, l = t & 63, l15 = l & 15, lhi = l >> 4;
    float bv[8];
    #pragma unroll
    for (int nt = 0; nt < 8; ++nt) bv[nt] = pbs[nt * 16 + l15];
    int ntiles = (N + 15) >> 4;
    const float4* X4 = reinterpret_cast<const float4*>(x);
    for (int rt = blockIdx.x * 4 + wid; rt < ntiles; rt += gridDim.x * 4) {
        int row = rt * 16 + l15;
        f32x4 acc[8];
        #pragma unroll
        for (int nt = 0; nt < 8; ++nt) acc[nt] = (f32x4)(0.f);
        #pragma unroll
        for (int kt = 0; kt < 4; ++kt) {
            uint4 af = make_uint4(0u, 0u, 0u, 0u);
            if (row < N) {
                float4 xa = X4[(size_t)row * 32 + kt * 8 + lhi * 2];
                float4 xb = X4[(size_t)row * 32 + kt * 8 + lhi * 2 + 1];
                af.x = pack2bf(xa.x, xa.y); af.y = pack2bf(xa.z, xa.w);
                af.z = pack2bf(xb.x, xb.y); af.w = pack2bf(xb.z, xb.w);
            }
            short8 a = asfrag(af);
            #pragma unroll
            for (int nt = 0; nt < 8; ++nt)
                acc[nt] = mfma_bf16(a, asfrag(Bf[nt * 256 + kt * 64 + l]), acc[nt]);
        }
        #pragma unroll
        for (int r = 0; r < 4; ++r) {
            int orow = rt * 16 + lhi * 4 + r;
            if (orow < N) {
                #pragma unroll
                for (int nt = 0; nt < 8; ++nt)
                    hst[(size_t)orow * 128 + nt * 16 + l15] = f2bf(acc[nt][r] + bv[nt]);
            }
        }
    }
}

// ---------------------------------------------------------------------------
// K2: per-node attention coefficients from bf16 h (memory-bound).
// ---------------------------------------------------------------------------
__global__ __launch_bounds__(256) void alpha_kernel(
    const unsigned* __restrict__ hbf,
    const float* __restrict__ ls0, const float* __restrict__ ld0,
    const float* __restrict__ ls1, const float* __restrict__ ld1,
    float* __restrict__ as0, float* __restrict__ ad0,
    float* __restrict__ as1, float* __restrict__ ad1, int N)
{
    __shared__ float lin[512];
    int t = threadIdx.x;
    for (int i = t; i < 128; i += 256) {
        lin[i] = ls0[i]; lin[128 + i] = ld0[i];
        lin[256 + i] = ls1[i]; lin[384 + i] = ld1[i];
    }
    __syncthreads();
    int idx = blockIdx.x * 256 + t;
    if (idx >= N * 8) return;
    int node = idx >> 3, head = idx & 7;
    const uint4* H = reinterpret_cast<const uint4*>(hbf);
    uint4 va = H[(size_t)node * 16 + head * 2];
    uint4 vb = H[(size_t)node * 16 + head * 2 + 1];
    float h[16];
    h[0] = bflo(va.x); h[1] = bfhi(va.x); h[2] = bflo(va.y); h[3] = bfhi(va.y);
    h[4] = bflo(va.z); h[5] = bfhi(va.z); h[6] = bflo(va.w); h[7] = bfhi(va.w);
    h[8] = bflo(vb.x); h[9] = bfhi(vb.x); h[10] = bflo(vb.y); h[11] = bfhi(vb.y);
    h[12] = bflo(vb.z); h[13] = bfhi(vb.z); h[14] = bflo(vb.w); h[15] = bfhi(vb.w);
    int base = head * 16;
    float d0 = 0.f, d1 = 0.f, d2 = 0.f, d3 = 0.f;
    #pragma unroll
    for (int d = 0; d < 16; ++d) {
        float hv = h[d];
        d0 = fmaf(hv, lin[base + d], d0);
        d1 = fmaf(hv, lin[128 + base + d], d1);
        d2 = fmaf(hv, lin[256 + base + d], d2);
        d3 = fmaf(hv, lin[384 + base + d], d3);
    }
    as0[idx] = d0; ad0[idx] = d1; as1[idx] = d2; ad1[idx] = d3;
}

// ---------------------------------------------------------------------------
// CSR build v5: ZERO-ATOMIC two-pass partition.
// count: per 64-edge wave-tile, 8 ballots; lane r accumulates region-r count
//        in a REGISTER; one 8-int write per wave.  No atomics.
// scanw: 16 blocks exclusive-scan the [mp][r][W] count matrix -> each wave's
//        exact staging base per region + region totals.  No contention.
// scatter: identical tile traversal; position = scanned base + popc(ballot
//        mask below lane); bases advance in registers.  No atomics.
// Then hist2/fill2 scatter within L2-resident region slices as before.
// ---------------------------------------------------------------------------
#define PW 2048   // waves per metapath in count/scatter (512 blocks x 4)

__global__ __launch_bounds__(256) void count_kernel(
    const int* __restrict__ ei0, int E0, const int* __restrict__ ei1, int E1,
    int* __restrict__ wcnt, int rsize)      // wcnt[mp][8][PW]
{
    int mp = blockIdx.x & 1;
    int b  = blockIdx.x >> 1;
    const int* ei = mp ? ei1 : ei0;
    int E = mp ? E1 : E0;
    int lane = threadIdx.x & 63;
    int gw = b * 4 + (threadIdx.x >> 6);
    int myCnt = 0;
    for (int base = gw * 64; base < E; base += PW * 64) {
        int e = base + lane;
        int r = (e < E) ? (ei[E + e] / rsize) : 8;
        #pragma unroll
        for (int rr = 0; rr < 8; ++rr) {
            unsigned long long mask = __ballot(r == rr);
            if (lane == rr) myCnt += __popcll(mask);
        }
    }
    if (lane < 8) wcnt[(mp * 8 + lane) * PW + gw] = myCnt;
}

__global__ __launch_bounds__(256) void scanw_kernel(
    int* __restrict__ wcnt, int* __restrict__ regionCur)
{
    // one block per (mp*8 + r) row of PW counts; exclusive scan in place
    int* p = wcnt + blockIdx.x * PW;
    int t = threadIdx.x;
    __shared__ int tsum[256];
    int v[8];
    int s = 0;
    #pragma unroll
    for (int j = 0; j < 8; ++j) { v[j] = p[t * 8 + j]; s += v[j]; }
    tsum[t] = s;
    __syncthreads();
    for (int ofs = 1; ofs < 256; ofs <<= 1) {
        int x = (t >= ofs) ? tsum[t - ofs] : 0;
        __syncthreads();
        tsum[t] += x;
        __syncthreads();
    }
    int base = (t > 0) ? tsum[t - 1] : 0;   // exclusive
    #pragma unroll
    for (int j = 0; j < 8; ++j) {
        int val = v[j];
        p[t * 8 + j] = base;
        base += val;
    }
    if (t == 255) regionCur[blockIdx.x] = tsum[255];
}

__global__ __launch_bounds__(256) void scatter_kernel(
    const int* __restrict__ ei0, int E0, const int* __restrict__ ei1, int E1,
    const int* __restrict__ wcnt, unsigned* __restrict__ stage, int cap, int rsize)
{
    int mp = blockIdx.x & 1;
    int b  = blockIdx.x >> 1;
    const int* ei = mp ? ei1 : ei0;
    int E = mp ? E1 : E0;
    unsigned* st = stage + (size_t)mp * 8 * cap;
    int lane = threadIdx.x & 63;
    int gw = b * 4 + (threadIdx.x >> 6);
    int myBase = (lane < 8) ? wcnt[(mp * 8 + lane) * PW + gw] : 0;
    for (int base = gw * 64; base < E; base += PW * 64) {
        int e = base + lane;
        bool valid = e < E;
        int d = valid ? ei[E + e] : 0;
        int s = valid ? ei[e] : 0;
        int r = valid ? (d / rsize) : 8;
        unsigned packed = ((unsigned)(d - r * rsize) << 17) | (unsigned)s;
        #pragma unroll
        for (int rr = 0; rr < 8; ++rr) {
            unsigned long long mask = __ballot(r == rr);
            int bse = __shfl(myBase, rr);
            if (r == rr) {
                int pos = __popcll(mask & ((1ull << lane) - 1ull));
                st[(size_t)rr * cap + bse + pos] = packed;
            }
            if (lane == rr) myBase += __popcll(mask);
        }
    }
}

__global__ __launch_bounds__(256) void hist2_kernel(
    const unsigned* __restrict__ stage, int cap, const int* __restrict__ regionCur,
    int* __restrict__ deg0, int* __restrict__ deg1, int rsize)
{
    int r = blockIdx.x & 7;
    int mp = (blockIdx.x >> 3) & 1;
    int sub = blockIdx.x >> 4;                // 0..127
    const unsigned* st = stage + ((size_t)mp * 8 + r) * cap;
    int cnt = regionCur[mp * 8 + r];
    int dbase = r * rsize;
    int* deg = mp ? deg1 : deg0;
    for (int i = sub * 256 + threadIdx.x; i < cnt; i += 128 * 256)
        atomicAdd(&deg[dbase + (int)(st[i] >> 17)], 1);
}

__global__ __launch_bounds__(256) void fill2_kernel(
    const unsigned* __restrict__ stage, int cap, const int* __restrict__ regionCur,
    const int* __restrict__ off0, int* __restrict__ cur0, int* __restrict__ perm0,
    const int* __restrict__ off1, int* __restrict__ cur1, int* __restrict__ perm1,
    int rsize)
{
    int r = blockIdx.x & 7;
    int mp = (blockIdx.x >> 3) & 1;
    int sub = blockIdx.x >> 4;                // 0..127
    const unsigned* st = stage + ((size_t)mp * 8 + r) * cap;
    int cnt = regionCur[mp * 8 + r];
    int dbase = r * rsize;
    const int* off = mp ? off1 : off0;
    int* cur = mp ? cur1 : cur0;
    int* perm = mp ? perm1 : perm0;
    for (int i = sub * 256 + threadIdx.x; i < cnt; i += 128 * 256) {
        unsigned v = st[i];
        int d = dbase + (int)(v >> 17);
        int s = (int)(v & 0x1FFFFu);
        int pos = atomicAdd(&cur[d], 1);
        perm[off[d] + pos] = s;
    }
}

// ---------------------------------------------------------------------------
// Scans (fused over both metapaths).
// ---------------------------------------------------------------------------
__global__ __launch_bounds__(256) void scan1_fused(
    const int* __restrict__ in0, int* __restrict__ out0,
    const int* __restrict__ in1, int* __restrict__ out1,
    int* __restrict__ bsums, int n, int nb)
{
    __shared__ int sh[256];
    int mp = (blockIdx.x >= (unsigned)nb);
    int blk = blockIdx.x - (mp ? nb : 0);
    const int* in = mp ? in1 : in0;
    int* out = mp ? out1 : out0;
    int t = threadIdx.x;
    int i = blk * 256 + t;
    int v = (i < n) ? in[i] : 0;
    sh[t] = v;
    __syncthreads();
    for (int ofs = 1; ofs < 256; ofs <<= 1) {
        int xv = (t >= ofs) ? sh[t - ofs] : 0;
        __syncthreads();
        sh[t] += xv;
        __syncthreads();
    }
    if (i < n) out[i] = sh[t] - v;          // exclusive
    if (t == 255) bsums[mp * 512 + blk] = sh[255];
}

__global__ __launch_bounds__(512) void scan2_fused(int* __restrict__ bs, int nb)
{
    __shared__ int sh[512];
    int t = threadIdx.x;
    int* b = bs + blockIdx.x * 512;
    int v = (t < nb) ? b[t] : 0;
    sh[t] = v;
    __syncthreads();
    for (int ofs = 1; ofs < 512; ofs <<= 1) {
        int xv = (t >= ofs) ? sh[t - ofs] : 0;
        __syncthreads();
        sh[t] += xv;
        __syncthreads();
    }
    if (t < nb) b[t] = sh[t] - v;          // exclusive
}

__global__ __launch_bounds__(256) void scan3_fused(
    int* __restrict__ out0, int* __restrict__ out1,
    const int* __restrict__ bs, int n, int nb)
{
    int mp = (blockIdx.x >= (unsigned)nb);
    int blk = blockIdx.x - (mp ? nb : 0);
    int* out = mp ? out1 : out0;
    int i = blk * 256 + threadIdx.x;
    if (i < n) out[i] += bs[mp * 512 + blk];
}

// ---------------------------------------------------------------------------
// K3: per-destination aggregation (fused mp0+mp1), lane-specialized weights.
// One 64-lane wave per (mp, node); lane owns dims {2*lane, 2*lane+1}.
// ---------------------------------------------------------------------------
__global__ __launch_bounds__(256) void agg_fused(
    const int* __restrict__ off0, const int* __restrict__ perm0,
    const float* __restrict__ as0, const float* __restrict__ ad0,
    const int* __restrict__ off1, const int* __restrict__ perm1,
    const float* __restrict__ as1, const float* __restrict__ ad1,
    const unsigned* __restrict__ hbf,
    unsigned* __restrict__ o0, unsigned* __restrict__ o1, int N)
{
    int mp = blockIdx.x & 1;
    int wid = (blockIdx.x >> 1) * 4 + (threadIdx.x >> 6);
    int lane = threadIdx.x & 63;
    if (wid >= N) return;
    const int* off = mp ? off1 : off0;
    const int* perm = mp ? perm1 : perm0;
    const float* asrc = mp ? as1 : as0;
    const float* adst = mp ? ad1 : ad0;
    unsigned* outm = mp ? o1 : o0;
    int start = off[wid], end = off[wid + 1];
    int h2 = lane >> 3;            // head: owns dims AND weight computation
    int esel = lane & 7;           // edge slot this lane computes weight for
    int wsrc = lane & 56;          // shuffle base: lane (wsrc|k) holds w[k][h2]
    float av = adst[wid * 8 + h2];
    float p0 = 0.f, p1 = 0.f, q0 = 0.f, q1 = 0.f;
    float sA = 0.f, sB = 0.f;
    for (int i = start; i < end; i += 8) {
        int idx = i + esel;
        int sm = perm[idx < end ? idx : start];
        float alv = asrc[sm * 8 + h2] + av;
        alv = alv > 0.f ? alv : NEG * alv;
        float wm = (idx < end) ? __expf(alv) : 0.f;
        #pragma unroll
        for (int k = 0; k < 8; ++k) {
            int sk = __shfl(sm, k);                 // perm[i+k]
            float wk = __shfl(wm, wsrc | k);        // weight for (edge k, h2)
            unsigned u = hbf[(unsigned)(sk * 64) + lane];
            if (k & 1) {
                q0 = fmaf(bflo(u), wk, q0);
                q1 = fmaf(bfhi(u), wk, q1);
                sB += wk;
            } else {
                p0 = fmaf(bflo(u), wk, p0);
                p1 = fmaf(bfhi(u), wk, p1);
                sA += wk;
            }
        }
    }
    float acc0 = p0 + q0, acc1 = p1 + q1, ssum = sA + sB;
    float inv = 1.f / (ssum + 1e-16f);
    acc0 *= inv; acc1 *= inv;
    acc0 = acc0 > 0.f ? acc0 : 0.f;   // relu
    acc1 = acc1 > 0.f ? acc1 : 0.f;
    outm[(size_t)wid * 64 + lane] = pack2bf(acc0, acc1);
}

// ---------------------------------------------------------------------------
// K4: semantic-attention scores via MFMA over bf16 out0/out1.
// ---------------------------------------------------------------------------
__global__ __launch_bounds__(256) void score_mfma(
    const unsigned* __restrict__ o0, const unsigned* __restrict__ o1,
    const uint4* __restrict__ bfg, const float* __restrict__ kb,
    const float* __restrict__ q, float* __restrict__ partials, int N)
{
    __shared__ uint4 Bf[2048];   // 32 KB (k_w fragments)
    __shared__ float kbs[128], qs[128];
    __shared__ float red[2];
    int t = threadIdx.x;
    for (int i = t; i < 2048; i += 256) Bf[i] = bfg[i];
    if (t < 128) { kbs[t] = kb[t]; qs[t] = q[t]; }
    if (t < 2) red[t] = 0.f;
    __syncthreads();
    int wid = t >> 6, l = t & 63, l15 = l & 15, lhi = l >> 4;
    float qv[8], kbv[8];
    #pragma unroll
    for (int nt = 0; nt < 8; ++nt) {
        qv[nt] = qs[nt * 16 + l15];
        kbv[nt] = kbs[nt * 16 + l15];
    }
    int ntiles = (N + 15) >> 4;
    int ttiles = 2 * ntiles;
    const uint4* A0 = reinterpret_cast<const uint4*>(o0);
    const uint4* A1 = reinterpret_cast<const uint4*>(o1);
    for (int tid = blockIdx.x * 4 + wid; tid < ttiles; tid += gridDim.x * 4) {
        int m = (tid >= ntiles);
        int rt = tid - (m ? ntiles : 0);
        const uint4* A = m ? A1 : A0;
        int row = rt * 16 + l15;
        f32x4 acc[8];
        #pragma unroll
        for (int nt = 0; nt < 8; ++nt) acc[nt] = (f32x4)(0.f);
        #pragma unroll
        for (int kt = 0; kt < 4; ++kt) {
            uint4 av = (row < N) ? A[(size_t)row * 16 + kt * 4 + lhi]
                                 : make_uint4(0u, 0u, 0u, 0u);
            short8 a = asfrag(av);
            #pragma unroll
            for (int nt = 0; nt < 8; ++nt)
                acc[nt] = mfma_bf16(a, asfrag(Bf[nt * 256 + kt * 64 + l]), acc[nt]);
        }
        float partial = 0.f;
        int rbase = rt * 16 + lhi * 4;
        #pragma unroll
        for (int r = 0; r < 4; ++r) {
            if (rbase + r < N) {
                #pragma unroll
                for (int nt = 0; nt < 8; ++nt)
                    partial += qv[nt] * tanh_fast(acc[nt][r] + kbv[nt]);
            }
        }
        partial += __shfl_xor(partial, 1);
        partial += __shfl_xor(partial, 2);
        partial += __shfl_xor(partial, 4);
        partial += __shfl_xor(partial, 8);
        partial += __shfl_xor(partial, 16);
        partial += __shfl_xor(partial, 32);
        if (l == 0) atomicAdd(&red[m], partial);
    }
    __syncthreads();
    if (t < 2) partials[blockIdx.x * 2 + t] = red[t];
}

__global__ __launch_bounds__(256) void beta_kernel(
    const float* __restrict__ partials, int G, float invN, float* __restrict__ beta)
{
    __shared__ float r0[256], r1[256];
    int t = threadIdx.x;
    float s0 = 0.f, s1 = 0.f;
    for (int i = t; i < G; i += 256) { s0 += partials[i * 2]; s1 += partials[i * 2 + 1]; }
    r0[t] = s0; r1[t] = s1; __syncthreads();
    for (int o = 128; o > 0; o >>= 1) {
        if (t < o) { r0[t] += r0[t + o]; r1[t] += r1[t + o]; }
        __syncthreads();
    }
    if (t == 0) {
        float a = r0[0] * invN, b = r1[0] * invN;
        float mx = fmaxf(a, b);
        float ea = __expf(a - mx), eb = __expf(b - mx);
        float inv = 1.f / (ea + eb);
        beta[0] = ea * inv; beta[1] = eb * inv;
    }
}

// ---------------------------------------------------------------------------
// K6: y = (b0*out0 + b1*out1) @ out_w + out_b via MFMA (f32 output).
// ---------------------------------------------------------------------------
__global__ __launch_bounds__(256) void final_mfma(
    const unsigned* __restrict__ o0, const unsigned* __restrict__ o1,
    const uint4* __restrict__ bfg, const float* __restrict__ ob,
    const float* __restrict__ beta, float* __restrict__ y, int N)
{
    __shared__ uint4 Bf[1024];   // 16 KB (out_w fragments)
    __shared__ float obs[64];
    int t = threadIdx.x;
    for (int i = t; i < 1024; i += 256) Bf[i] = bfg[i];
    if (t < 64) obs[t] = ob[t];
    __syncthreads();
    float b0 = beta[0], b1 = beta[1];
    int wid = t >> 6, l = t & 63, l15 = l & 15, lhi = l >> 4;
    float obv[4];
    #pragma unroll
    for (int nt = 0; nt < 4; ++nt) obv[nt] = obs[nt * 16 + l15];
    int ntiles = (N + 15) >> 4;
    const uint4* A0 = reinterpret_cast<const uint4*>(o0);
    const uint4* A1 = reinterpret_cast<const uint4*>(o1);
    for (int rt = blockIdx.x * 4 + wid; rt < ntiles; rt += gridDim.x * 4) {
        int row = rt * 16 + l15;
        f32x4 acc[4];
        #pragma unroll
        for (int nt = 0; nt < 4; ++nt) acc[nt] = (f32x4)(0.f);
        #pragma unroll
        for (int kt = 0; kt < 4; ++kt) {
            uint4 af = make_uint4(0u, 0u, 0u, 0u);
            if (row < N) {
                uint4 a0 = A0[(size_t)row * 16 + kt * 4 + lhi];
                uint4 a1 = A1[(size_t)row * 16 + kt * 4 + lhi];
                af.x = pack2bf(b0 * bflo(a0.x) + b1 * bflo(a1.x),
                               b0 * bfhi(a0.x) + b1 * bfhi(a1.x));
                af.y = pack2bf(b0 * bflo(a0.y) + b1 * bflo(a1.y),
                               b0 * bfhi(a0.y) + b1 * bfhi(a1.y));
                af.z = pack2bf(b0 * bflo(a0.z) + b1 * bflo(a1.z),
                               b0 * bfhi(a0.z) + b1 * bfhi(a1.z));
                af.w = pack2bf(b0 * bflo(a0.w) + b1 * bflo(a1.w),
                               b0 * bfhi(a0.w) + b1 * bfhi(a1.w));
            }
            short8 a = asfrag(af);
            #pragma unroll
            for (int nt = 0; nt < 4; ++nt)
                acc[nt] = mfma_bf16(a, asfrag(Bf[nt * 256 + kt * 64 + l]), acc[nt]);
        }
        #pragma unroll
        for (int r = 0; r < 4; ++r) {
            int orow = rt * 16 + lhi * 4 + r;
            if (orow < N) {
                #pragma unroll
                for (int nt = 0; nt < 4; ++nt)
                    y[(size_t)orow * 64 + nt * 16 + l15] = acc[nt][r] + obv[nt];
            }
        }
    }
}

// ---------------------------------------------------------------------------
extern "C" void kernel_launch(void* const* d_in, const int* in_sizes, int n_in,
                              void* d_out, int out_size, void* d_ws, size_t ws_size,
                              hipStream_t stream)
{
    const float* x   = (const float*)d_in[0];
    const int*   ei0 = (const int*)d_in[1];
    const int*   ei1 = (const int*)d_in[2];
    const float* pw  = (const float*)d_in[3];
    const float* pb  = (const float*)d_in[4];
    const float* ls0 = (const float*)d_in[5];
    const float* ld0 = (const float*)d_in[6];
    const float* ls1 = (const float*)d_in[7];
    const float* ld1 = (const float*)d_in[8];
    const float* kw  = (const float*)d_in[9];
    const float* kb  = (const float*)d_in[10];
    const float* q   = (const float*)d_in[11];
    const float* ow  = (const float*)d_in[12];
    const float* ob  = (const float*)d_in[13];
    int N  = in_sizes[0] / 128;
    int E0 = in_sizes[1] / 2;
    int E1 = in_sizes[2] / 2;

    char* w = (char*)d_ws;
    size_t o = 0;
    auto alloc = [&](size_t bytes) -> void* {
        void* p = w + o;
        o += (bytes + 255) & ~(size_t)255;
        return p;
    };
    unsigned* hbf  = (unsigned*)alloc((size_t)N * 128 * 2);   // bf16 h
    float* as0  = (float*)alloc((size_t)N * 8 * 4);
    float* ad0  = (float*)alloc((size_t)N * 8 * 4);
    float* as1  = (float*)alloc((size_t)N * 8 * 4);
    float* ad1  = (float*)alloc((size_t)N * 8 * 4);
    unsigned* out0 = (unsigned*)alloc((size_t)N * 128 * 2);   // bf16 out
    unsigned* out1 = (unsigned*)alloc((size_t)N * 128 * 2);
    char*  zbase = w + o;                       // contiguous zeroed region
    int* deg0 = (int*)alloc((size_t)(N + 1) * 4);
    int* cur0 = (int*)alloc((size_t)N * 4);
    int* deg1 = (int*)alloc((size_t)(N + 1) * 4);
    int* cur1 = (int*)alloc((size_t)N * 4);
    int* regionCur = (int*)alloc(16 * 4);
    size_t zbytes = (w + o) - zbase;
    int* off0 = (int*)alloc((size_t)(N + 1) * 4);
    int* off1 = (int*)alloc((size_t)(N + 1) * 4);
    int* bsums = (int*)alloc(1024 * 4);
    int* perm0 = (int*)alloc((size_t)E0 * 4);
    int* perm1 = (int*)alloc((size_t)E1 * 4);
    float* partials = (float*)alloc((size_t)2 * 2048 * 4);
    float* beta = (float*)alloc(256);
    uint4* bfpw = (uint4*)alloc(2048 * 16);
    uint4* bfkw = (uint4*)alloc(2048 * 16);
    uint4* bfow = (uint4*)alloc(1024 * 16);
    int Emax = E0 > E1 ? E0 : E1;
    int cap = Emax / 8 + Emax / 16 + 1024;     // 1.5x expected + slack
    unsigned* stage = (unsigned*)alloc((size_t)2 * 8 * cap * 4);
    int* wcnt = (int*)alloc((size_t)16 * PW * 4);

    int rsize = (N + 7) / 8;   // dst-region size for XCD ownership

    hipMemsetAsync(zbase, 0, zbytes, stream);

    prep_bfrag<<<3, 256, 0, stream>>>(pw, kw, ow, bfpw, bfkw, bfow);

    proj_mfma<<<512, 256, 0, stream>>>(x, bfpw, pb, (unsigned short*)hbf, N);

    int ablocks = (N * 8 + 255) / 256;
    alpha_kernel<<<ablocks, 256, 0, stream>>>(hbf, ls0, ld0, ls1, ld1,
                                              as0, ad0, as1, ad1, N);

    count_kernel<<<1024, 256, 0, stream>>>(ei0, E0, ei1, E1, wcnt, rsize);
    scanw_kernel<<<16, 256, 0, stream>>>(wcnt, regionCur);
    scatter_kernel<<<1024, 256, 0, stream>>>(ei0, E0, ei1, E1,
                                             wcnt, stage, cap, rsize);

    hist2_kernel<<<2048, 256, 0, stream>>>(stage, cap, regionCur,
                                           deg0, deg1, rsize);

    int n1 = N + 1;
    int nb = (n1 + 255) / 256;   // must be <= 512
    scan1_fused<<<2 * nb, 256, 0, stream>>>(deg0, off0, deg1, off1, bsums, n1, nb);
    scan2_fused<<<2, 512, 0, stream>>>(bsums, nb);
    scan3_fused<<<2 * nb, 256, 0, stream>>>(off0, off1, bsums, n1, nb);

    fill2_kernel<<<2048, 256, 0, stream>>>(stage, cap, regionCur,
                                           off0, cur0, perm0,
                                           off1, cur1, perm1, rsize);

    int aggBlocks = 2 * ((N + 3) / 4);
    agg_fused<<<aggBlocks, 256, 0, stream>>>(off0, perm0, as0, ad0,
                                             off1, perm1, as1, ad1,
                                             hbf, out0, out1, N);

    const int SG = 512;
    score_mfma<<<SG, 256, 0, stream>>>(out0, out1, bfkw, kb, q, partials, N);
    beta_kernel<<<1, 256, 0, stream>>>(partials, SG, 1.0f / (float)N, beta);
    final_mfma<<<512, 256, 0, stream>>>(out0, out1, bfow, ob, beta, (float*)d_out, N);
}

// Round 15
// 514.135 us; speedup vs baseline: 9.7900x; 1.0125x over previous
//
#include <hip/hip_runtime.h>
#include <hip/hip_bf16.h>

#define NEG 0.2f

typedef __attribute__((ext_vector_type(8))) short short8;  // 8 bf16 (4 VGPR)
typedef __attribute__((ext_vector_type(4))) float f32x4;

// bf16 helpers (manual RNE pack / unpack, branch-free, no NaN inputs here)
__device__ __forceinline__ unsigned short f2bf(float f) {
    unsigned u = __float_as_uint(f);
    u += 0x7fffu + ((u >> 16) & 1u);
    return (unsigned short)(u >> 16);
}
__device__ __forceinline__ unsigned pack2bf(float a, float b) {
    return (unsigned)f2bf(a) | ((unsigned)f2bf(b) << 16);
}
__device__ __forceinline__ float bflo(unsigned u) { return __uint_as_float(u << 16); }
__device__ __forceinline__ float bfhi(unsigned u) { return __uint_as_float(u & 0xffff0000u); }

__device__ __forceinline__ short8 asfrag(uint4 v) {
    union { uint4 u; short8 s; } x; x.u = v; return x.s;
}
__device__ __forceinline__ f32x4 mfma_bf16(short8 a, short8 b, f32x4 c) {
    return __builtin_amdgcn_mfma_f32_16x16x32_bf16(a, b, c, 0, 0, 0);
}
__device__ __forceinline__ float tanh_fast(float x) {
    x = fminf(fmaxf(x, -15.f), 15.f);
    float t = __expf(2.f * x);
    return (t - 1.f) / (t + 1.f);
}

// ---------------------------------------------------------------------------
// P0: pre-pack weight matrices into MFMA B-fragment order (once).
// block 0: proj_w [128x128], block 1: k_w [128x128], block 2: out_w [128x64].
// ---------------------------------------------------------------------------
__global__ __launch_bounds__(256) void prep_bfrag(
    const float* __restrict__ pw, const float* __restrict__ kw,
    const float* __restrict__ ow,
    uint4* __restrict__ bfpw, uint4* __restrict__ bfkw, uint4* __restrict__ bfow)
{
    int b = blockIdx.x;
    const float* src = (b == 0) ? pw : (b == 1) ? kw : ow;
    uint4* dst = (b == 0) ? bfpw : (b == 1) ? bfkw : bfow;
    int ncol  = (b == 2) ? 64 : 128;
    int slots = (b == 2) ? 1024 : 2048;
    for (int i = threadIdx.x; i < slots; i += 256) {
        int nt = i >> 8, kt = (i >> 6) & 3, lane = i & 63;
        int row0 = kt * 32 + ((lane >> 4) << 3);
        int col  = nt * 16 + (lane & 15);
        float e[8];
        #pragma unroll
        for (int j = 0; j < 8; ++j) e[j] = src[(row0 + j) * ncol + col];
        uint4 v;
        v.x = pack2bf(e[0], e[1]); v.y = pack2bf(e[2], e[3]);
        v.z = pack2bf(e[4], e[5]); v.w = pack2bf(e[6], e[7]);
        dst[i] = v;
    }
}

// ---------------------------------------------------------------------------
// K1: h = bf16(x) @ bf16(proj_w) + proj_b via MFMA; store h bf16.
// ---------------------------------------------------------------------------
__global__ __launch_bounds__(256) void proj_mfma(
    const float* __restrict__ x, const uint4* __restrict__ bfg,
    const float* __restrict__ pb, unsigned short* __restrict__ hst, int N)
{
    __shared__ uint4 Bf[2048];   // 32 KB
    __shared__ float pbs[128];
    int t = threadIdx.x;
    for (int i = t; i < 2048; i += 256) Bf[i] = bfg[i];
    if (t < 128) pbs[t] = pb[t];
    __syncthreads();
    int wid = t >> 6, l = t & 63, l15 = l & 15, lhi = l >> 4;
    float bv[8];
    #pragma unroll
    for (int nt = 0; nt < 8; ++nt) bv[nt] = pbs[nt * 16 + l15];
    int ntiles = (N + 15) >> 4;
    const float4* X4 = reinterpret_cast<const float4*>(x);
    for (int rt = blockIdx.x * 4 + wid; rt < ntiles; rt += gridDim.x * 4) {
        int row = rt * 16 + l15;
        f32x4 acc[8];
        #pragma unroll
        for (int nt = 0; nt < 8; ++nt) acc[nt] = (f32x4)(0.f);
        #pragma unroll
        for (int kt = 0; kt < 4; ++kt) {
            uint4 af = make_uint4(0u, 0u, 0u, 0u);
            if (row < N) {
                float4 xa = X4[(size_t)row * 32 + kt * 8 + lhi * 2];
                float4 xb = X4[(size_t)row * 32 + kt * 8 + lhi * 2 + 1];
                af.x = pack2bf(xa.x, xa.y); af.y = pack2bf(xa.z, xa.w);
                af.z = pack2bf(xb.x, xb.y); af.w = pack2bf(xb.z, xb.w);
            }
            short8 a = asfrag(af);
            #pragma unroll
            for (int nt = 0; nt < 8; ++nt)
                acc[nt] = mfma_bf16(a, asfrag(Bf[nt * 256 + kt * 64 + l]), acc[nt]);
        }
        #pragma unroll
        for (int r = 0; r < 4; ++r) {
            int orow = rt * 16 + lhi * 4 + r;
            if (orow < N) {
                #pragma unroll
                for (int nt = 0; nt < 8; ++nt)
                    hst[(size_t)orow * 128 + nt * 16 + l15] = f2bf(acc[nt][r] + bv[nt]);
            }
        }
    }
}

// ---------------------------------------------------------------------------
// K2: per-node attention coefficients from bf16 h (memory-bound).
// ---------------------------------------------------------------------------
__global__ __launch_bounds__(256) void alpha_kernel(
    const unsigned* __restrict__ hbf,
    const float* __restrict__ ls0, const float* __restrict__ ld0,
    const float* __restrict__ ls1, const float* __restrict__ ld1,
    float* __restrict__ as0, float* __restrict__ ad0,
    float* __restrict__ as1, float* __restrict__ ad1, int N)
{
    __shared__ float lin[512];
    int t = threadIdx.x;
    for (int i = t; i < 128; i += 256) {
        lin[i] = ls0[i]; lin[128 + i] = ld0[i];
        lin[256 + i] = ls1[i]; lin[384 + i] = ld1[i];
    }
    __syncthreads();
    int idx = blockIdx.x * 256 + t;
    if (idx >= N * 8) return;
    int node = idx >> 3, head = idx & 7;
    const uint4* H = reinterpret_cast<const uint4*>(hbf);
    uint4 va = H[(size_t)node * 16 + head * 2];
    uint4 vb = H[(size_t)node * 16 + head * 2 + 1];
    float h[16];
    h[0] = bflo(va.x); h[1] = bfhi(va.x); h[2] = bflo(va.y); h[3] = bfhi(va.y);
    h[4] = bflo(va.z); h[5] = bfhi(va.z); h[6] = bflo(va.w); h[7] = bfhi(va.w);
    h[8] = bflo(vb.x); h[9] = bfhi(vb.x); h[10] = bflo(vb.y); h[11] = bfhi(vb.y);
    h[12] = bflo(vb.z); h[13] = bfhi(vb.z); h[14] = bflo(vb.w); h[15] = bfhi(vb.w);
    int base = head * 16;
    float d0 = 0.f, d1 = 0.f, d2 = 0.f, d3 = 0.f;
    #pragma unroll
    for (int d = 0; d < 16; ++d) {
        float hv = h[d];
        d0 = fmaf(hv, lin[base + d], d0);
        d1 = fmaf(hv, lin[128 + base + d], d1);
        d2 = fmaf(hv, lin[256 + base + d], d2);
        d3 = fmaf(hv, lin[384 + base + d], d3);
    }
    as0[idx] = d0; ad0[idx] = d1; as1[idx] = d2; ad1[idx] = d3;
}

// ---------------------------------------------------------------------------
// CSR build v5: ZERO-ATOMIC two-pass partition (count / scanw / scatter),
// then hist2/fill2 scatter within L2-resident region slices.
// ---------------------------------------------------------------------------
#define PW 2048   // waves per metapath in count/scatter (512 blocks x 4)

__global__ __launch_bounds__(256) void count_kernel(
    const int* __restrict__ ei0, int E0, const int* __restrict__ ei1, int E1,
    int* __restrict__ wcnt, int rsize)      // wcnt[mp][8][PW]
{
    int mp = blockIdx.x & 1;
    int b  = blockIdx.x >> 1;
    const int* ei = mp ? ei1 : ei0;
    int E = mp ? E1 : E0;
    int lane = threadIdx.x & 63;
    int gw = b * 4 + (threadIdx.x >> 6);
    int myCnt = 0;
    for (int base = gw * 64; base < E; base += PW * 64) {
        int e = base + lane;
        int r = (e < E) ? (ei[E + e] / rsize) : 8;
        #pragma unroll
        for (int rr = 0; rr < 8; ++rr) {
            unsigned long long mask = __ballot(r == rr);
            if (lane == rr) myCnt += __popcll(mask);
        }
    }
    if (lane < 8) wcnt[(mp * 8 + lane) * PW + gw] = myCnt;
}

__global__ __launch_bounds__(256) void scanw_kernel(
    int* __restrict__ wcnt, int* __restrict__ regionCur)
{
    // one block per (mp*8 + r) row of PW counts; exclusive scan in place
    int* p = wcnt + blockIdx.x * PW;
    int t = threadIdx.x;
    __shared__ int tsum[256];
    int v[8];
    int s = 0;
    #pragma unroll
    for (int j = 0; j < 8; ++j) { v[j] = p[t * 8 + j]; s += v[j]; }
    tsum[t] = s;
    __syncthreads();
    for (int ofs = 1; ofs < 256; ofs <<= 1) {
        int x = (t >= ofs) ? tsum[t - ofs] : 0;
        __syncthreads();
        tsum[t] += x;
        __syncthreads();
    }
    int base = (t > 0) ? tsum[t - 1] : 0;   // exclusive
    #pragma unroll
    for (int j = 0; j < 8; ++j) {
        int val = v[j];
        p[t * 8 + j] = base;
        base += val;
    }
    if (t == 255) regionCur[blockIdx.x] = tsum[255];
}

__global__ __launch_bounds__(256) void scatter_kernel(
    const int* __restrict__ ei0, int E0, const int* __restrict__ ei1, int E1,
    const int* __restrict__ wcnt, unsigned* __restrict__ stage, int cap, int rsize)
{
    int mp = blockIdx.x & 1;
    int b  = blockIdx.x >> 1;
    const int* ei = mp ? ei1 : ei0;
    int E = mp ? E1 : E0;
    unsigned* st = stage + (size_t)mp * 8 * cap;
    int lane = threadIdx.x & 63;
    int gw = b * 4 + (threadIdx.x >> 6);
    int myBase = (lane < 8) ? wcnt[(mp * 8 + lane) * PW + gw] : 0;
    for (int base = gw * 64; base < E; base += PW * 64) {
        int e = base + lane;
        bool valid = e < E;
        int d = valid ? ei[E + e] : 0;
        int s = valid ? ei[e] : 0;
        int r = valid ? (d / rsize) : 8;
        unsigned packed = ((unsigned)(d - r * rsize) << 17) | (unsigned)s;
        #pragma unroll
        for (int rr = 0; rr < 8; ++rr) {
            unsigned long long mask = __ballot(r == rr);
            int bse = __shfl(myBase, rr);
            if (r == rr) {
                int pos = __popcll(mask & ((1ull << lane) - 1ull));
                st[(size_t)rr * cap + bse + pos] = packed;
            }
            if (lane == rr) myBase += __popcll(mask);
        }
    }
}

__global__ __launch_bounds__(256) void hist2_kernel(
    const unsigned* __restrict__ stage, int cap, const int* __restrict__ regionCur,
    int* __restrict__ deg0, int* __restrict__ deg1, int rsize)
{
    int r = blockIdx.x & 7;
    int mp = (blockIdx.x >> 3) & 1;
    int sub = blockIdx.x >> 4;                // 0..127
    const unsigned* st = stage + ((size_t)mp * 8 + r) * cap;
    int cnt = regionCur[mp * 8 + r];
    int dbase = r * rsize;
    int* deg = mp ? deg1 : deg0;
    for (int i = sub * 256 + threadIdx.x; i < cnt; i += 128 * 256)
        atomicAdd(&deg[dbase + (int)(st[i] >> 17)], 1);
}

__global__ __launch_bounds__(256) void fill2_kernel(
    const unsigned* __restrict__ stage, int cap, const int* __restrict__ regionCur,
    const int* __restrict__ off0, int* __restrict__ cur0, int* __restrict__ perm0,
    const int* __restrict__ off1, int* __restrict__ cur1, int* __restrict__ perm1,
    int rsize)
{
    int r = blockIdx.x & 7;
    int mp = (blockIdx.x >> 3) & 1;
    int sub = blockIdx.x >> 4;                // 0..127
    const unsigned* st = stage + ((size_t)mp * 8 + r) * cap;
    int cnt = regionCur[mp * 8 + r];
    int dbase = r * rsize;
    const int* off = mp ? off1 : off0;
    int* cur = mp ? cur1 : cur0;
    int* perm = mp ? perm1 : perm0;
    for (int i = sub * 256 + threadIdx.x; i < cnt; i += 128 * 256) {
        unsigned v = st[i];
        int d = dbase + (int)(v >> 17);
        int s = (int)(v & 0x1FFFFu);
        int pos = atomicAdd(&cur[d], 1);
        perm[off[d] + pos] = s;
    }
}

// ---------------------------------------------------------------------------
// Scans (fused over both metapaths).
// ---------------------------------------------------------------------------
__global__ __launch_bounds__(256) void scan1_fused(
    const int* __restrict__ in0, int* __restrict__ out0,
    const int* __restrict__ in1, int* __restrict__ out1,
    int* __restrict__ bsums, int n, int nb)
{
    __shared__ int sh[256];
    int mp = (blockIdx.x >= (unsigned)nb);
    int blk = blockIdx.x - (mp ? nb : 0);
    const int* in = mp ? in1 : in0;
    int* out = mp ? out1 : out0;
    int t = threadIdx.x;
    int i = blk * 256 + t;
    int v = (i < n) ? in[i] : 0;
    sh[t] = v;
    __syncthreads();
    for (int ofs = 1; ofs < 256; ofs <<= 1) {
        int xv = (t >= ofs) ? sh[t - ofs] : 0;
        __syncthreads();
        sh[t] += xv;
        __syncthreads();
    }
    if (i < n) out[i] = sh[t] - v;          // exclusive
    if (t == 255) bsums[mp * 512 + blk] = sh[255];
}

__global__ __launch_bounds__(512) void scan2_fused(int* __restrict__ bs, int nb)
{
    __shared__ int sh[512];
    int t = threadIdx.x;
    int* b = bs + blockIdx.x * 512;
    int v = (t < nb) ? b[t] : 0;
    sh[t] = v;
    __syncthreads();
    for (int ofs = 1; ofs < 512; ofs <<= 1) {
        int xv = (t >= ofs) ? sh[t - ofs] : 0;
        __syncthreads();
        sh[t] += xv;
        __syncthreads();
    }
    if (t < nb) b[t] = sh[t] - v;          // exclusive
}

__global__ __launch_bounds__(256) void scan3_fused(
    int* __restrict__ out0, int* __restrict__ out1,
    const int* __restrict__ bs, int n, int nb)
{
    int mp = (blockIdx.x >= (unsigned)nb);
    int blk = blockIdx.x - (mp ? nb : 0);
    int* out = mp ? out1 : out0;
    int i = blk * 256 + threadIdx.x;
    if (i < n) out[i] += bs[mp * 512 + blk];
}

// ---------------------------------------------------------------------------
// K3: per-destination aggregation (fused mp0+mp1).
// Lane-specialized weights (R9) + explicit batched gather arrays (R8):
// per 8-edge batch, broadcast all 8 src ids, ISSUE ALL 8 hbf GATHERS
// back-to-back into u[8] (they depend only on the fast perm load, so they
// overlap the slow asrc gather), THEN do the weight shuffles + FMA chain.
// This needs ~16 extra VGPRs (sk[8]+u[8]) so the compiler can keep 8
// gathers in flight (R14's VGPR=32 build serialized them: load->use per k).
// ---------------------------------------------------------------------------
__global__ __launch_bounds__(256) void agg_fused(
    const int* __restrict__ off0, const int* __restrict__ perm0,
    const float* __restrict__ as0, const float* __restrict__ ad0,
    const int* __restrict__ off1, const int* __restrict__ perm1,
    const float* __restrict__ as1, const float* __restrict__ ad1,
    const unsigned* __restrict__ hbf,
    unsigned* __restrict__ o0, unsigned* __restrict__ o1, int N)
{
    int mp = blockIdx.x & 1;
    int wid = (blockIdx.x >> 1) * 4 + (threadIdx.x >> 6);
    int lane = threadIdx.x & 63;
    if (wid >= N) return;
    const int* off = mp ? off1 : off0;
    const int* perm = mp ? perm1 : perm0;
    const float* asrc = mp ? as1 : as0;
    const float* adst = mp ? ad1 : ad0;
    unsigned* outm = mp ? o1 : o0;
    int start = off[wid], end = off[wid + 1];
    int h2 = lane >> 3;            // head: owns dims AND weight computation
    int esel = lane & 7;           // edge slot this lane computes weight for
    int wsrc = lane & 56;          // shuffle base: lane (wsrc|k) holds w[k][h2]
    float av = adst[wid * 8 + h2];
    float p0 = 0.f, p1 = 0.f, q0 = 0.f, q1 = 0.f;
    float sA = 0.f, sB = 0.f;
    for (int i = start; i < end; i += 8) {
        int idx = i + esel;
        int sm = perm[idx < end ? idx : start];
        // broadcast all 8 source ids first (one waitcnt on perm load)
        int sk[8];
        #pragma unroll
        for (int k = 0; k < 8; ++k) sk[k] = __shfl(sm, k);
        // issue all 8 h-row gathers back-to-back (overlap asrc gather below)
        unsigned u[8];
        #pragma unroll
        for (int k = 0; k < 8; ++k) u[k] = hbf[(unsigned)(sk[k] * 64) + lane];
        // this lane's softmax weight for (edge esel, head h2)
        float alv = asrc[sm * 8 + h2] + av;
        alv = alv > 0.f ? alv : NEG * alv;
        float wm = (idx < end) ? __expf(alv) : 0.f;
        // redistribute weights + accumulate
        #pragma unroll
        for (int k = 0; k < 8; ++k) {
            float wk = __shfl(wm, wsrc | k);
            if (k & 1) {
                q0 = fmaf(bflo(u[k]), wk, q0);
                q1 = fmaf(bfhi(u[k]), wk, q1);
                sB += wk;
            } else {
                p0 = fmaf(bflo(u[k]), wk, p0);
                p1 = fmaf(bfhi(u[k]), wk, p1);
                sA += wk;
            }
        }
    }
    float acc0 = p0 + q0, acc1 = p1 + q1, ssum = sA + sB;
    float inv = 1.f / (ssum + 1e-16f);
    acc0 *= inv; acc1 *= inv;
    acc0 = acc0 > 0.f ? acc0 : 0.f;   // relu
    acc1 = acc1 > 0.f ? acc1 : 0.f;
    outm[(size_t)wid * 64 + lane] = pack2bf(acc0, acc1);
}

// ---------------------------------------------------------------------------
// K4: semantic-attention scores via MFMA over bf16 out0/out1.
// ---------------------------------------------------------------------------
__global__ __launch_bounds__(256) void score_mfma(
    const unsigned* __restrict__ o0, const unsigned* __restrict__ o1,
    const uint4* __restrict__ bfg, const float* __restrict__ kb,
    const float* __restrict__ q, float* __restrict__ partials, int N)
{
    __shared__ uint4 Bf[2048];   // 32 KB (k_w fragments)
    __shared__ float kbs[128], qs[128];
    __shared__ float red[2];
    int t = threadIdx.x;
    for (int i = t; i < 2048; i += 256) Bf[i] = bfg[i];
    if (t < 128) { kbs[t] = kb[t]; qs[t] = q[t]; }
    if (t < 2) red[t] = 0.f;
    __syncthreads();
    int wid = t >> 6, l = t & 63, l15 = l & 15, lhi = l >> 4;
    float qv[8], kbv[8];
    #pragma unroll
    for (int nt = 0; nt < 8; ++nt) {
        qv[nt] = qs[nt * 16 + l15];
        kbv[nt] = kbs[nt * 16 + l15];
    }
    int ntiles = (N + 15) >> 4;
    int ttiles = 2 * ntiles;
    const uint4* A0 = reinterpret_cast<const uint4*>(o0);
    const uint4* A1 = reinterpret_cast<const uint4*>(o1);
    for (int tid = blockIdx.x * 4 + wid; tid < ttiles; tid += gridDim.x * 4) {
        int m = (tid >= ntiles);
        int rt = tid - (m ? ntiles : 0);
        const uint4* A = m ? A1 : A0;
        int row = rt * 16 + l15;
        f32x4 acc[8];
        #pragma unroll
        for (int nt = 0; nt < 8; ++nt) acc[nt] = (f32x4)(0.f);
        #pragma unroll
        for (int kt = 0; kt < 4; ++kt) {
            uint4 av = (row < N) ? A[(size_t)row * 16 + kt * 4 + lhi]
                                 : make_uint4(0u, 0u, 0u, 0u);
            short8 a = asfrag(av);
            #pragma unroll
            for (int nt = 0; nt < 8; ++nt)
                acc[nt] = mfma_bf16(a, asfrag(Bf[nt * 256 + kt * 64 + l]), acc[nt]);
        }
        float partial = 0.f;
        int rbase = rt * 16 + lhi * 4;
        #pragma unroll
        for (int r = 0; r < 4; ++r) {
            if (rbase + r < N) {
                #pragma unroll
                for (int nt = 0; nt < 8; ++nt)
                    partial += qv[nt] * tanh_fast(acc[nt][r] + kbv[nt]);
            }
        }
        partial += __shfl_xor(partial, 1);
        partial += __shfl_xor(partial, 2);
        partial += __shfl_xor(partial, 4);
        partial += __shfl_xor(partial, 8);
        partial += __shfl_xor(partial, 16);
        partial += __shfl_xor(partial, 32);
        if (l == 0) atomicAdd(&red[m], partial);
    }
    __syncthreads();
    if (t < 2) partials[blockIdx.x * 2 + t] = red[t];
}

__global__ __launch_bounds__(256) void beta_kernel(
    const float* __restrict__ partials, int G, float invN, float* __restrict__ beta)
{
    __shared__ float r0[256], r1[256];
    int t = threadIdx.x;
    float s0 = 0.f, s1 = 0.f;
    for (int i = t; i < G; i += 256) { s0 += partials[i * 2]; s1 += partials[i * 2 + 1]; }
    r0[t] = s0; r1[t] = s1; __syncthreads();
    for (int o = 128; o > 0; o >>= 1) {
        if (t < o) { r0[t] += r0[t + o]; r1[t] += r1[t + o]; }
        __syncthreads();
    }
    if (t == 0) {
        float a = r0[0] * invN, b = r1[0] * invN;
        float mx = fmaxf(a, b);
        float ea = __expf(a - mx), eb = __expf(b - mx);
        float inv = 1.f / (ea + eb);
        beta[0] = ea * inv; beta[1] = eb * inv;
    }
}

// ---------------------------------------------------------------------------
// K6: y = (b0*out0 + b1*out1) @ out_w + out_b via MFMA (f32 output).
// ---------------------------------------------------------------------------
__global__ __launch_bounds__(256) void final_mfma(
    const unsigned* __restrict__ o0, const unsigned* __restrict__ o1,
    const uint4* __restrict__ bfg, const float* __restrict__ ob,
    const float* __restrict__ beta, float* __restrict__ y, int N)
{
    __shared__ uint4 Bf[1024];   // 16 KB (out_w fragments)
    __shared__ float obs[64];
    int t = threadIdx.x;
    for (int i = t; i < 1024; i += 256) Bf[i] = bfg[i];
    if (t < 64) obs[t] = ob[t];
    __syncthreads();
    float b0 = beta[0], b1 = beta[1];
    int wid = t >> 6, l = t & 63, l15 = l & 15, lhi = l >> 4;
    float obv[4];
    #pragma unroll
    for (int nt = 0; nt < 4; ++nt) obv[nt] = obs[nt * 16 + l15];
    int ntiles = (N + 15) >> 4;
    const uint4* A0 = reinterpret_cast<const uint4*>(o0);
    const uint4* A1 = reinterpret_cast<const uint4*>(o1);
    for (int rt = blockIdx.x * 4 + wid; rt < ntiles; rt += gridDim.x * 4) {
        int row = rt * 16 + l15;
        f32x4 acc[4];
        #pragma unroll
        for (int nt = 0; nt < 4; ++nt) acc[nt] = (f32x4)(0.f);
        #pragma unroll
        for (int kt = 0; kt < 4; ++kt) {
            uint4 af = make_uint4(0u, 0u, 0u, 0u);
            if (row < N) {
                uint4 a0 = A0[(size_t)row * 16 + kt * 4 + lhi];
                uint4 a1 = A1[(size_t)row * 16 + kt * 4 + lhi];
                af.x = pack2bf(b0 * bflo(a0.x) + b1 * bflo(a1.x),
                               b0 * bfhi(a0.x) + b1 * bfhi(a1.x));
                af.y = pack2bf(b0 * bflo(a0.y) + b1 * bflo(a1.y),
                               b0 * bfhi(a0.y) + b1 * bfhi(a1.y));
                af.z = pack2bf(b0 * bflo(a0.z) + b1 * bflo(a1.z),
                               b0 * bfhi(a0.z) + b1 * bfhi(a1.z));
                af.w = pack2bf(b0 * bflo(a0.w) + b1 * bflo(a1.w),
                               b0 * bfhi(a0.w) + b1 * bfhi(a1.w));
            }
            short8 a = asfrag(af);
            #pragma unroll
            for (int nt = 0; nt < 4; ++nt)
                acc[nt] = mfma_bf16(a, asfrag(Bf[nt * 256 + kt * 64 + l]), acc[nt]);
        }
        #pragma unroll
        for (int r = 0; r < 4; ++r) {
            int orow = rt * 16 + lhi * 4 + r;
            if (orow < N) {
                #pragma unroll
                for (int nt = 0; nt < 4; ++nt)
                    y[(size_t)orow * 64 + nt * 16 + l15] = acc[nt][r] + obv[nt];
            }
        }
    }
}

// ---------------------------------------------------------------------------
extern "C" void kernel_launch(void* const* d_in, const int* in_sizes, int n_in,
                              void* d_out, int out_size, void* d_ws, size_t ws_size,
                              hipStream_t stream)
{
    const float* x   = (const float*)d_in[0];
    const int*   ei0 = (const int*)d_in[1];
    const int*   ei1 = (const int*)d_in[2];
    const float* pw  = (const float*)d_in[3];
    const float* pb  = (const float*)d_in[4];
    const float* ls0 = (const float*)d_in[5];
    const float* ld0 = (const float*)d_in[6];
    const float* ls1 = (const float*)d_in[7];
    const float* ld1 = (const float*)d_in[8];
    const float* kw  = (const float*)d_in[9];
    const float* kb  = (const float*)d_in[10];
    const float* q   = (const float*)d_in[11];
    const float* ow  = (const float*)d_in[12];
    const float* ob  = (const float*)d_in[13];
    int N  = in_sizes[0] / 128;
    int E0 = in_sizes[1] / 2;
    int E1 = in_sizes[2] / 2;

    char* w = (char*)d_ws;
    size_t o = 0;
    auto alloc = [&](size_t bytes) -> void* {
        void* p = w + o;
        o += (bytes + 255) & ~(size_t)255;
        return p;
    };
    unsigned* hbf  = (unsigned*)alloc((size_t)N * 128 * 2);   // bf16 h
    float* as0  = (float*)alloc((size_t)N * 8 * 4);
    float* ad0  = (float*)alloc((size_t)N * 8 * 4);
    float* as1  = (float*)alloc((size_t)N * 8 * 4);
    float* ad1  = (float*)alloc((size_t)N * 8 * 4);
    unsigned* out0 = (unsigned*)alloc((size_t)N * 128 * 2);   // bf16 out
    unsigned* out1 = (unsigned*)alloc((size_t)N * 128 * 2);
    char*  zbase = w + o;                       // contiguous zeroed region
    int* deg0 = (int*)alloc((size_t)(N + 1) * 4);
    int* cur0 = (int*)alloc((size_t)N * 4);
    int* deg1 = (int*)alloc((size_t)(N + 1) * 4);
    int* cur1 = (int*)alloc((size_t)N * 4);
    int* regionCur = (int*)alloc(16 * 4);
    size_t zbytes = (w + o) - zbase;
    int* off0 = (int*)alloc((size_t)(N + 1) * 4);
    int* off1 = (int*)alloc((size_t)(N + 1) * 4);
    int* bsums = (int*)alloc(1024 * 4);
    int* perm0 = (int*)alloc((size_t)E0 * 4);
    int* perm1 = (int*)alloc((size_t)E1 * 4);
    float* partials = (float*)alloc((size_t)2 * 2048 * 4);
    float* beta = (float*)alloc(256);
    uint4* bfpw = (uint4*)alloc(2048 * 16);
    uint4* bfkw = (uint4*)alloc(2048 * 16);
    uint4* bfow = (uint4*)alloc(1024 * 16);
    int Emax = E0 > E1 ? E0 : E1;
    int cap = Emax / 8 + Emax / 16 + 1024;     // 1.5x expected + slack
    unsigned* stage = (unsigned*)alloc((size_t)2 * 8 * cap * 4);
    int* wcnt = (int*)alloc((size_t)16 * PW * 4);

    int rsize = (N + 7) / 8;   // dst-region size for XCD ownership

    hipMemsetAsync(zbase, 0, zbytes, stream);

    prep_bfrag<<<3, 256, 0, stream>>>(pw, kw, ow, bfpw, bfkw, bfow);

    proj_mfma<<<512, 256, 0, stream>>>(x, bfpw, pb, (unsigned short*)hbf, N);

    int ablocks = (N * 8 + 255) / 256;
    alpha_kernel<<<ablocks, 256, 0, stream>>>(hbf, ls0, ld0, ls1, ld1,
                                              as0, ad0, as1, ad1, N);

    count_kernel<<<1024, 256, 0, stream>>>(ei0, E0, ei1, E1, wcnt, rsize);
    scanw_kernel<<<16, 256, 0, stream>>>(wcnt, regionCur);
    scatter_kernel<<<1024, 256, 0, stream>>>(ei0, E0, ei1, E1,
                                             wcnt, stage, cap, rsize);

    hist2_kernel<<<2048, 256, 0, stream>>>(stage, cap, regionCur,
                                           deg0, deg1, rsize);

    int n1 = N + 1;
    int nb = (n1 + 255) / 256;   // must be <= 512
    scan1_fused<<<2 * nb, 256, 0, stream>>>(deg0, off0, deg1, off1, bsums, n1, nb);
    scan2_fused<<<2, 512, 0, stream>>>(bsums, nb);
    scan3_fused<<<2 * nb, 256, 0, stream>>>(off0, off1, bsums, n1, nb);

    fill2_kernel<<<2048, 256, 0, stream>>>(stage, cap, regionCur,
                                           off0, cur0, perm0,
                                           off1, cur1, perm1, rsize);

    int aggBlocks = 2 * ((N + 3) / 4);
    agg_fused<<<aggBlocks, 256, 0, stream>>>(off0, perm0, as0, ad0,
                                             off1, perm1, as1, ad1,
                                             hbf, out0, out1, N);

    const int SG = 512;
    score_mfma<<<SG, 256, 0, stream>>>(out0, out1, bfkw, kb, q, partials, N);
    beta_kernel<<<1, 256, 0, stream>>>(partials, SG, 1.0f / (float)N, beta);
    final_mfma<<<512, 256, 0, stream>>>(out0, out1, bfow, ob, beta, (float*)d_out, N);
}

// Round 17
// 501.796 us; speedup vs baseline: 10.0308x; 1.0246x over previous
//
#include <hip/hip_runtime.h>
#include <hip/hip_bf16.h>

#define NEG 0.2f

typedef __attribute__((ext_vector_type(8))) short short8;  // 8 bf16 (4 VGPR)
typedef __attribute__((ext_vector_type(4))) float f32x4;

// bf16 helpers (manual RNE pack / unpack, branch-free, no NaN inputs here)
__device__ __forceinline__ unsigned short f2bf(float f) {
    unsigned u = __float_as_uint(f);
    u += 0x7fffu + ((u >> 16) & 1u);
    return (unsigned short)(u >> 16);
}
__device__ __forceinline__ unsigned pack2bf(float a, float b) {
    return (unsigned)f2bf(a) | ((unsigned)f2bf(b) << 16);
}
__device__ __forceinline__ float bflo(unsigned u) { return __uint_as_float(u << 16); }
__device__ __forceinline__ float bfhi(unsigned u) { return __uint_as_float(u & 0xffff0000u); }

__device__ __forceinline__ short8 asfrag(uint4 v) {
    union { uint4 u; short8 s; } x; x.u = v; return x.s;
}
__device__ __forceinline__ f32x4 mfma_bf16(short8 a, short8 b, f32x4 c) {
    return __builtin_amdgcn_mfma_f32_16x16x32_bf16(a, b, c, 0, 0, 0);
}
__device__ __forceinline__ float tanh_fast(float x) {
    x = fminf(fmaxf(x, -15.f), 15.f);
    float t = __expf(2.f * x);
    return (t - 1.f) / (t + 1.f);
}

#define PW 2048   // waves per metapath in count/scatter (512 blocks x 4)

// ---------------------------------------------------------------------------
// device helpers for the fused phases
// ---------------------------------------------------------------------------
__device__ void prep_dev(int b, const float* __restrict__ pw,
                         const float* __restrict__ kw, const float* __restrict__ ow,
                         uint4* __restrict__ bfpw, uint4* __restrict__ bfkw,
                         uint4* __restrict__ bfow)
{
    const float* src = (b == 0) ? pw : (b == 1) ? kw : ow;
    uint4* dst = (b == 0) ? bfpw : (b == 1) ? bfkw : bfow;
    int ncol  = (b == 2) ? 64 : 128;
    int slots = (b == 2) ? 1024 : 2048;
    for (int i = threadIdx.x; i < slots; i += 256) {
        int nt = i >> 8, kt = (i >> 6) & 3, lane = i & 63;
        int row0 = kt * 32 + ((lane >> 4) << 3);
        int col  = nt * 16 + (lane & 15);
        float e[8];
        #pragma unroll
        for (int j = 0; j < 8; ++j) e[j] = src[(row0 + j) * ncol + col];
        uint4 v;
        v.x = pack2bf(e[0], e[1]); v.y = pack2bf(e[2], e[3]);
        v.z = pack2bf(e[4], e[5]); v.w = pack2bf(e[6], e[7]);
        dst[i] = v;
    }
}

__device__ void count_dev(int bb, const int* __restrict__ ei0, int E0,
                          const int* __restrict__ ei1, int E1,
                          int* __restrict__ wcnt, int rsize)
{
    int mp = bb & 1;
    int b  = bb >> 1;
    const int* ei = mp ? ei1 : ei0;
    int E = mp ? E1 : E0;
    int lane = threadIdx.x & 63;
    int gw = b * 4 + (threadIdx.x >> 6);
    int myCnt = 0;
    for (int base = gw * 64; base < E; base += PW * 64) {
        int e = base + lane;
        int r = (e < E) ? (ei[E + e] / rsize) : 8;
        #pragma unroll
        for (int rr = 0; rr < 8; ++rr) {
            unsigned long long mask = __ballot(r == rr);
            if (lane == rr) myCnt += __popcll(mask);
        }
    }
    if (lane < 8) wcnt[(mp * 8 + lane) * PW + gw] = myCnt;
}

// K1: prep (blocks 0-2) + count (blocks 3-1026) — independent work fused.
__global__ __launch_bounds__(256) void prep_count_kernel(
    const float* __restrict__ pw, const float* __restrict__ kw,
    const float* __restrict__ ow,
    uint4* __restrict__ bfpw, uint4* __restrict__ bfkw, uint4* __restrict__ bfow,
    const int* __restrict__ ei0, int E0, const int* __restrict__ ei1, int E1,
    int* __restrict__ wcnt, int rsize)
{
    if (blockIdx.x < 3) prep_dev(blockIdx.x, pw, kw, ow, bfpw, bfkw, bfow);
    else count_dev(blockIdx.x - 3, ei0, E0, ei1, E1, wcnt, rsize);
}

__device__ void scanw_dev(int row, int* __restrict__ wcnt, int* __restrict__ regionCur)
{
    int* p = wcnt + row * PW;
    int t = threadIdx.x;
    __shared__ int tsum[256];
    int v[8];
    int s = 0;
    #pragma unroll
    for (int j = 0; j < 8; ++j) { v[j] = p[t * 8 + j]; s += v[j]; }
    tsum[t] = s;
    __syncthreads();
    for (int ofs = 1; ofs < 256; ofs <<= 1) {
        int x = (t >= ofs) ? tsum[t - ofs] : 0;
        __syncthreads();
        tsum[t] += x;
        __syncthreads();
    }
    int base = (t > 0) ? tsum[t - 1] : 0;   // exclusive
    #pragma unroll
    for (int j = 0; j < 8; ++j) {
        int val = v[j];
        p[t * 8 + j] = base;
        base += val;
    }
    if (t == 255) regionCur[row] = tsum[255];
}

__device__ void proj_dev(int bid, int ngrid, const float* __restrict__ x,
                         const uint4* __restrict__ bfg, const float* __restrict__ pb,
                         unsigned short* __restrict__ hst, int N)
{
    __shared__ uint4 Bf[2048];   // 32 KB
    __shared__ float pbs[128];
    int t = threadIdx.x;
    for (int i = t; i < 2048; i += 256) Bf[i] = bfg[i];
    if (t < 128) pbs[t] = pb[t];
    __syncthreads();
    int wid = t >> 6, l = t & 63, l15 = l & 15, lhi = l >> 4;
    float bv[8];
    #pragma unroll
    for (int nt = 0; nt < 8; ++nt) bv[nt] = pbs[nt * 16 + l15];
    int ntiles = (N + 15) >> 4;
    const float4* X4 = reinterpret_cast<const float4*>(x);
    for (int rt = bid * 4 + wid; rt < ntiles; rt += ngrid * 4) {
        int row = rt * 16 + l15;
        f32x4 acc[8];
        #pragma unroll
        for (int nt = 0; nt < 8; ++nt) acc[nt] = (f32x4)(0.f);
        #pragma unroll
        for (int kt = 0; kt < 4; ++kt) {
            uint4 af = make_uint4(0u, 0u, 0u, 0u);
            if (row < N) {
                float4 xa = X4[(size_t)row * 32 + kt * 8 + lhi * 2];
                float4 xb = X4[(size_t)row * 32 + kt * 8 + lhi * 2 + 1];
                af.x = pack2bf(xa.x, xa.y); af.y = pack2bf(xa.z, xa.w);
                af.z = pack2bf(xb.x, xb.y); af.w = pack2bf(xb.z, xb.w);
            }
            short8 a = asfrag(af);
            #pragma unroll
            for (int nt = 0; nt < 8; ++nt)
                acc[nt] = mfma_bf16(a, asfrag(Bf[nt * 256 + kt * 64 + l]), acc[nt]);
        }
        #pragma unroll
        for (int r = 0; r < 4; ++r) {
            int orow = rt * 16 + lhi * 4 + r;
            if (orow < N) {
                #pragma unroll
                for (int nt = 0; nt < 8; ++nt)
                    hst[(size_t)orow * 128 + nt * 16 + l15] = f2bf(acc[nt][r] + bv[nt]);
            }
        }
    }
}

// K2: scanw (blocks 0-15) + proj (blocks 16-527).
__global__ __launch_bounds__(256) void proj_scanw_kernel(
    const float* __restrict__ x, const uint4* __restrict__ bfg,
    const float* __restrict__ pb, unsigned short* __restrict__ hst, int N,
    int* __restrict__ wcnt, int* __restrict__ regionCur)
{
    if (blockIdx.x < 16) scanw_dev(blockIdx.x, wcnt, regionCur);
    else proj_dev(blockIdx.x - 16, 512, x, bfg, pb, hst, N);
}

__device__ void scatter_dev(int bb, const int* __restrict__ ei0, int E0,
                            const int* __restrict__ ei1, int E1,
                            const int* __restrict__ wcnt,
                            unsigned* __restrict__ stage, int cap, int rsize)
{
    int mp = bb & 1;
    int b  = bb >> 1;
    const int* ei = mp ? ei1 : ei0;
    int E = mp ? E1 : E0;
    unsigned* st = stage + (size_t)mp * 8 * cap;
    int lane = threadIdx.x & 63;
    int gw = b * 4 + (threadIdx.x >> 6);
    int myBase = (lane < 8) ? wcnt[(mp * 8 + lane) * PW + gw] : 0;
    for (int base = gw * 64; base < E; base += PW * 64) {
        int e = base + lane;
        bool valid = e < E;
        int d = valid ? ei[E + e] : 0;
        int s = valid ? ei[e] : 0;
        int r = valid ? (d / rsize) : 8;
        unsigned packed = ((unsigned)(d - r * rsize) << 17) | (unsigned)s;
        #pragma unroll
        for (int rr = 0; rr < 8; ++rr) {
            unsigned long long mask = __ballot(r == rr);
            int bse = __shfl(myBase, rr);
            if (r == rr) {
                int pos = __popcll(mask & ((1ull << lane) - 1ull));
                st[(size_t)rr * cap + bse + pos] = packed;
            }
            if (lane == rr) myBase += __popcll(mask);
        }
    }
}

__device__ void alpha_dev(int bid, const unsigned* __restrict__ hbf,
    const float* __restrict__ ls0, const float* __restrict__ ld0,
    const float* __restrict__ ls1, const float* __restrict__ ld1,
    float* __restrict__ as0, float* __restrict__ ad0,
    float* __restrict__ as1, float* __restrict__ ad1, int N)
{
    __shared__ float lin[512];
    int t = threadIdx.x;
    for (int i = t; i < 128; i += 256) {
        lin[i] = ls0[i]; lin[128 + i] = ld0[i];
        lin[256 + i] = ls1[i]; lin[384 + i] = ld1[i];
    }
    __syncthreads();
    int idx = bid * 256 + t;
    if (idx >= N * 8) return;
    int node = idx >> 3, head = idx & 7;
    const uint4* H = reinterpret_cast<const uint4*>(hbf);
    uint4 va = H[(size_t)node * 16 + head * 2];
    uint4 vb = H[(size_t)node * 16 + head * 2 + 1];
    float h[16];
    h[0] = bflo(va.x); h[1] = bfhi(va.x); h[2] = bflo(va.y); h[3] = bfhi(va.y);
    h[4] = bflo(va.z); h[5] = bfhi(va.z); h[6] = bflo(va.w); h[7] = bfhi(va.w);
    h[8] = bflo(vb.x); h[9] = bfhi(vb.x); h[10] = bflo(vb.y); h[11] = bfhi(vb.y);
    h[12] = bflo(vb.z); h[13] = bfhi(vb.z); h[14] = bflo(vb.w); h[15] = bfhi(vb.w);
    int base = head * 16;
    float d0 = 0.f, d1 = 0.f, d2 = 0.f, d3 = 0.f;
    #pragma unroll
    for (int d = 0; d < 16; ++d) {
        float hv = h[d];
        d0 = fmaf(hv, lin[base + d], d0);
        d1 = fmaf(hv, lin[128 + base + d], d1);
        d2 = fmaf(hv, lin[256 + base + d], d2);
        d3 = fmaf(hv, lin[384 + base + d], d3);
    }
    as0[idx] = d0; ad0[idx] = d1; as1[idx] = d2; ad1[idx] = d3;
}

// K3: scatter (blocks 0-1023) + alpha (blocks 1024+).
__global__ __launch_bounds__(256) void alpha_scatter_kernel(
    const int* __restrict__ ei0, int E0, const int* __restrict__ ei1, int E1,
    const int* __restrict__ wcnt, unsigned* __restrict__ stage, int cap, int rsize,
    const unsigned* __restrict__ hbf,
    const float* __restrict__ ls0, const float* __restrict__ ld0,
    const float* __restrict__ ls1, const float* __restrict__ ld1,
    float* __restrict__ as0, float* __restrict__ ad0,
    float* __restrict__ as1, float* __restrict__ ad1, int N)
{
    if (blockIdx.x < 1024)
        scatter_dev(blockIdx.x, ei0, E0, ei1, E1, wcnt, stage, cap, rsize);
    else
        alpha_dev(blockIdx.x - 1024, hbf, ls0, ld0, ls1, ld1,
                  as0, ad0, as1, ad1, N);
}

__global__ __launch_bounds__(256) void hist2_kernel(
    const unsigned* __restrict__ stage, int cap, const int* __restrict__ regionCur,
    int* __restrict__ deg0, int* __restrict__ deg1, int rsize)
{
    int r = blockIdx.x & 7;
    int mp = (blockIdx.x >> 3) & 1;
    int sub = blockIdx.x >> 4;                // 0..127
    const unsigned* st = stage + ((size_t)mp * 8 + r) * cap;
    int cnt = regionCur[mp * 8 + r];
    int dbase = r * rsize;
    int* deg = mp ? deg1 : deg0;
    for (int i = sub * 256 + threadIdx.x; i < cnt; i += 128 * 256)
        atomicAdd(&deg[dbase + (int)(st[i] >> 17)], 1);
}

__global__ __launch_bounds__(256) void fill2_kernel(
    const unsigned* __restrict__ stage, int cap, const int* __restrict__ regionCur,
    const int* __restrict__ off0, int* __restrict__ cur0, int* __restrict__ perm0,
    const int* __restrict__ off1, int* __restrict__ cur1, int* __restrict__ perm1,
    int rsize)
{
    int r = blockIdx.x & 7;
    int mp = (blockIdx.x >> 3) & 1;
    int sub = blockIdx.x >> 4;                // 0..127
    const unsigned* st = stage + ((size_t)mp * 8 + r) * cap;
    int cnt = regionCur[mp * 8 + r];
    int dbase = r * rsize;
    const int* off = mp ? off1 : off0;
    int* cur = mp ? cur1 : cur0;
    int* perm = mp ? perm1 : perm0;
    for (int i = sub * 256 + threadIdx.x; i < cnt; i += 128 * 256) {
        unsigned v = st[i];
        int d = dbase + (int)(v >> 17);
        int s = (int)(v & 0x1FFFFu);
        int pos = atomicAdd(&cur[d], 1);
        perm[off[d] + pos] = s;
    }
}

// ---------------------------------------------------------------------------
// Scans (fused over both metapaths).
// ---------------------------------------------------------------------------
__global__ __launch_bounds__(256) void scan1_fused(
    const int* __restrict__ in0, int* __restrict__ out0,
    const int* __restrict__ in1, int* __restrict__ out1,
    int* __restrict__ bsums, int n, int nb)
{
    __shared__ int sh[256];
    int mp = (blockIdx.x >= (unsigned)nb);
    int blk = blockIdx.x - (mp ? nb : 0);
    const int* in = mp ? in1 : in0;
    int* out = mp ? out1 : out0;
    int t = threadIdx.x;
    int i = blk * 256 + t;
    int v = (i < n) ? in[i] : 0;
    sh[t] = v;
    __syncthreads();
    for (int ofs = 1; ofs < 256; ofs <<= 1) {
        int xv = (t >= ofs) ? sh[t - ofs] : 0;
        __syncthreads();
        sh[t] += xv;
        __syncthreads();
    }
    if (i < n) out[i] = sh[t] - v;          // exclusive
    if (t == 255) bsums[mp * 512 + blk] = sh[255];
}

__global__ __launch_bounds__(512) void scan2_fused(int* __restrict__ bs, int nb)
{
    __shared__ int sh[512];
    int t = threadIdx.x;
    int* b = bs + blockIdx.x * 512;
    int v = (t < nb) ? b[t] : 0;
    sh[t] = v;
    __syncthreads();
    for (int ofs = 1; ofs < 512; ofs <<= 1) {
        int xv = (t >= ofs) ? sh[t - ofs] : 0;
        __syncthreads();
        sh[t] += xv;
        __syncthreads();
    }
    if (t < nb) b[t] = sh[t] - v;          // exclusive
}

__global__ __launch_bounds__(256) void scan3_fused(
    int* __restrict__ out0, int* __restrict__ out1,
    const int* __restrict__ bs, int n, int nb)
{
    int mp = (blockIdx.x >= (unsigned)nb);
    int blk = blockIdx.x - (mp ? nb : 0);
    int* out = mp ? out1 : out0;
    int i = blk * 256 + threadIdx.x;
    if (i < n) out[i] += bs[mp * 512 + blk];
}

// ---------------------------------------------------------------------------
// K3: per-destination aggregation (fused mp0+mp1).
// Lane-specialized weights + batched gather arrays (R15 structure).
// ---------------------------------------------------------------------------
__global__ __launch_bounds__(256) void agg_fused(
    const int* __restrict__ off0, const int* __restrict__ perm0,
    const float* __restrict__ as0, const float* __restrict__ ad0,
    const int* __restrict__ off1, const int* __restrict__ perm1,
    const float* __restrict__ as1, const float* __restrict__ ad1,
    const unsigned* __restrict__ hbf,
    unsigned* __restrict__ o0, unsigned* __restrict__ o1, int N)
{
    int mp = blockIdx.x & 1;
    int wid = (blockIdx.x >> 1) * 4 + (threadIdx.x >> 6);
    int lane = threadIdx.x & 63;
    if (wid >= N) return;
    const int* off = mp ? off1 : off0;
    const int* perm = mp ? perm1 : perm0;
    const float* asrc = mp ? as1 : as0;
    const float* adst = mp ? ad1 : ad0;
    unsigned* outm = mp ? o1 : o0;
    int start = off[wid], end = off[wid + 1];
    int h2 = lane >> 3;            // head: owns dims AND weight computation
    int esel = lane & 7;           // edge slot this lane computes weight for
    int wsrc = lane & 56;          // shuffle base: lane (wsrc|k) holds w[k][h2]
    float av = adst[wid * 8 + h2];
    float p0 = 0.f, p1 = 0.f, q0 = 0.f, q1 = 0.f;
    float sA = 0.f, sB = 0.f;
    for (int i = start; i < end; i += 8) {
        int idx = i + esel;
        int sm = perm[idx < end ? idx : start];
        int sk[8];
        #pragma unroll
        for (int k = 0; k < 8; ++k) sk[k] = __shfl(sm, k);
        unsigned u[8];
        #pragma unroll
        for (int k = 0; k < 8; ++k) u[k] = hbf[(unsigned)(sk[k] * 64) + lane];
        float alv = asrc[sm * 8 + h2] + av;
        alv = alv > 0.f ? alv : NEG * alv;
        float wm = (idx < end) ? __expf(alv) : 0.f;
        #pragma unroll
        for (int k = 0; k < 8; ++k) {
            float wk = __shfl(wm, wsrc | k);
            if (k & 1) {
                q0 = fmaf(bflo(u[k]), wk, q0);
                q1 = fmaf(bfhi(u[k]), wk, q1);
                sB += wk;
            } else {
                p0 = fmaf(bflo(u[k]), wk, p0);
                p1 = fmaf(bfhi(u[k]), wk, p1);
                sA += wk;
            }
        }
    }
    float acc0 = p0 + q0, acc1 = p1 + q1, ssum = sA + sB;
    float inv = 1.f / (ssum + 1e-16f);
    acc0 *= inv; acc1 *= inv;
    acc0 = acc0 > 0.f ? acc0 : 0.f;   // relu
    acc1 = acc1 > 0.f ? acc1 : 0.f;
    outm[(size_t)wid * 64 + lane] = pack2bf(acc0, acc1);
}

// ---------------------------------------------------------------------------
// K4: semantic-attention scores via MFMA over bf16 out0/out1.
// ---------------------------------------------------------------------------
__global__ __launch_bounds__(256) void score_mfma(
    const unsigned* __restrict__ o0, const unsigned* __restrict__ o1,
    const uint4* __restrict__ bfg, const float* __restrict__ kb,
    const float* __restrict__ q, float* __restrict__ partials, int N)
{
    __shared__ uint4 Bf[2048];   // 32 KB (k_w fragments)
    __shared__ float kbs[128], qs[128];
    __shared__ float red[2];
    int t = threadIdx.x;
    for (int i = t; i < 2048; i += 256) Bf[i] = bfg[i];
    if (t < 128) { kbs[t] = kb[t]; qs[t] = q[t]; }
    if (t < 2) red[t] = 0.f;
    __syncthreads();
    int wid = t >> 6, l = t & 63, l15 = l & 15, lhi = l >> 4;
    float qv[8], kbv[8];
    #pragma unroll
    for (int nt = 0; nt < 8; ++nt) {
        qv[nt] = qs[nt * 16 + l15];
        kbv[nt] = kbs[nt * 16 + l15];
    }
    int ntiles = (N + 15) >> 4;
    int ttiles = 2 * ntiles;
    const uint4* A0 = reinterpret_cast<const uint4*>(o0);
    const uint4* A1 = reinterpret_cast<const uint4*>(o1);
    for (int tid = blockIdx.x * 4 + wid; tid < ttiles; tid += gridDim.x * 4) {
        int m = (tid >= ntiles);
        int rt = tid - (m ? ntiles : 0);
        const uint4* A = m ? A1 : A0;
        int row = rt * 16 + l15;
        f32x4 acc[8];
        #pragma unroll
        for (int nt = 0; nt < 8; ++nt) acc[nt] = (f32x4)(0.f);
        #pragma unroll
        for (int kt = 0; kt < 4; ++kt) {
            uint4 av = (row < N) ? A[(size_t)row * 16 + kt * 4 + lhi]
                                 : make_uint4(0u, 0u, 0u, 0u);
            short8 a = asfrag(av);
            #pragma unroll
            for (int nt = 0; nt < 8; ++nt)
                acc[nt] = mfma_bf16(a, asfrag(Bf[nt * 256 + kt * 64 + l]), acc[nt]);
        }
        float partial = 0.f;
        int rbase = rt * 16 + lhi * 4;
        #pragma unroll
        for (int r = 0; r < 4; ++r) {
            if (rbase + r < N) {
                #pragma unroll
                for (int nt = 0; nt < 8; ++nt)
                    partial += qv[nt] * tanh_fast(acc[nt][r] + kbv[nt]);
            }
        }
        partial += __shfl_xor(partial, 1);
        partial += __shfl_xor(partial, 2);
        partial += __shfl_xor(partial, 4);
        partial += __shfl_xor(partial, 8);
        partial += __shfl_xor(partial, 16);
        partial += __shfl_xor(partial, 32);
        if (l == 0) atomicAdd(&red[m], partial);
    }
    __syncthreads();
    if (t < 2) partials[blockIdx.x * 2 + t] = red[t];
}

__global__ __launch_bounds__(256) void beta_kernel(
    const float* __restrict__ partials, int G, float invN, float* __restrict__ beta)
{
    __shared__ float r0[256], r1[256];
    int t = threadIdx.x;
    float s0 = 0.f, s1 = 0.f;
    for (int i = t; i < G; i += 256) { s0 += partials[i * 2]; s1 += partials[i * 2 + 1]; }
    r0[t] = s0; r1[t] = s1; __syncthreads();
    for (int o = 128; o > 0; o >>= 1) {
        if (t < o) { r0[t] += r0[t + o]; r1[t] += r1[t + o]; }
        __syncthreads();
    }
    if (t == 0) {
        float a = r0[0] * invN, b = r1[0] * invN;
        float mx = fmaxf(a, b);
        float ea = __expf(a - mx), eb = __expf(b - mx);
        float inv = 1.f / (ea + eb);
        beta[0] = ea * inv; beta[1] = eb * inv;
    }
}

// ---------------------------------------------------------------------------
// K6: y = (b0*out0 + b1*out1) @ out_w + out_b via MFMA (f32 output).
// ---------------------------------------------------------------------------
__global__ __launch_bounds__(256) void final_mfma(
    const unsigned* __restrict__ o0, const unsigned* __restrict__ o1,
    const uint4* __restrict__ bfg, const float* __restrict__ ob,
    const float* __restrict__ beta, float* __restrict__ y, int N)
{
    __shared__ uint4 Bf[1024];   // 16 KB (out_w fragments)
    __shared__ float obs[64];
    int t = threadIdx.x;
    for (int i = t; i < 1024; i += 256) Bf[i] = bfg[i];
    if (t < 64) obs[t] = ob[t];
    __syncthreads();
    float b0 = beta[0], b1 = beta[1];
    int wid = t >> 6, l = t & 63, l15 = l & 15, lhi = l >> 4;
    float obv[4];
    #pragma unroll
    for (int nt = 0; nt < 4; ++nt) obv[nt] = obs[nt * 16 + l15];
    int ntiles = (N + 15) >> 4;
    const uint4* A0 = reinterpret_cast<const uint4*>(o0);
    const uint4* A1 = reinterpret_cast<const uint4*>(o1);
    for (int rt = blockIdx.x * 4 + wid; rt < ntiles; rt += gridDim.x * 4) {
        int row = rt * 16 + l15;
        f32x4 acc[4];
        #pragma unroll
        for (int nt = 0; nt < 4; ++nt) acc[nt] = (f32x4)(0.f);
        #pragma unroll
        for (int kt = 0; kt < 4; ++kt) {
            uint4 af = make_uint4(0u, 0u, 0u, 0u);
            if (row < N) {
                uint4 a0 = A0[(size_t)row * 16 + kt * 4 + lhi];
                uint4 a1 = A1[(size_t)row * 16 + kt * 4 + lhi];
                af.x = pack2bf(b0 * bflo(a0.x) + b1 * bflo(a1.x),
                               b0 * bfhi(a0.x) + b1 * bfhi(a1.x));
                af.y = pack2bf(b0 * bflo(a0.y) + b1 * bflo(a1.y),
                               b0 * bfhi(a0.y) + b1 * bfhi(a1.y));
                af.z = pack2bf(b0 * bflo(a0.z) + b1 * bflo(a1.z),
                               b0 * bfhi(a0.z) + b1 * bfhi(a1.z));
                af.w = pack2bf(b0 * bflo(a0.w) + b1 * bflo(a1.w),
                               b0 * bfhi(a0.w) + b1 * bfhi(a1.w));
            }
            short8 a = asfrag(af);
            #pragma unroll
            for (int nt = 0; nt < 4; ++nt)
                acc[nt] = mfma_bf16(a, asfrag(Bf[nt * 256 + kt * 64 + l]), acc[nt]);
        }
        #pragma unroll
        for (int r = 0; r < 4; ++r) {
            int orow = rt * 16 + lhi * 4 + r;
            if (orow < N) {
                #pragma unroll
                for (int nt = 0; nt < 4; ++nt)
                    y[(size_t)orow * 64 + nt * 16 + l15] = acc[nt][r] + obv[nt];
            }
        }
    }
}

// ---------------------------------------------------------------------------
extern "C" void kernel_launch(void* const* d_in, const int* in_sizes, int n_in,
                              void* d_out, int out_size, void* d_ws, size_t ws_size,
                              hipStream_t stream)
{
    const float* x   = (const float*)d_in[0];
    const int*   ei0 = (const int*)d_in[1];
    const int*   ei1 = (const int*)d_in[2];
    const float* pw  = (const float*)d_in[3];
    const float* pb  = (const float*)d_in[4];
    const float* ls0 = (const float*)d_in[5];
    const float* ld0 = (const float*)d_in[6];
    const float* ls1 = (const float*)d_in[7];
    const float* ld1 = (const float*)d_in[8];
    const float* kw  = (const float*)d_in[9];
    const float* kb  = (const float*)d_in[10];
    const float* q   = (const float*)d_in[11];
    const float* ow  = (const float*)d_in[12];
    const float* ob  = (const float*)d_in[13];
    int N  = in_sizes[0] / 128;
    int E0 = in_sizes[1] / 2;
    int E1 = in_sizes[2] / 2;

    char* w = (char*)d_ws;
    size_t o = 0;
    auto alloc = [&](size_t bytes) -> void* {
        void* p = w + o;
        o += (bytes + 255) & ~(size_t)255;
        return p;
    };
    unsigned* hbf  = (unsigned*)alloc((size_t)N * 128 * 2);   // bf16 h
    float* as0  = (float*)alloc((size_t)N * 8 * 4);
    float* ad0  = (float*)alloc((size_t)N * 8 * 4);
    float* as1  = (float*)alloc((size_t)N * 8 * 4);
    float* ad1  = (float*)alloc((size_t)N * 8 * 4);
    unsigned* out0 = (unsigned*)alloc((size_t)N * 128 * 2);   // bf16 out
    unsigned* out1 = (unsigned*)alloc((size_t)N * 128 * 2);
    char*  zbase = w + o;                       // contiguous zeroed region
    int* deg0 = (int*)alloc((size_t)(N + 1) * 4);
    int* cur0 = (int*)alloc((size_t)N * 4);
    int* deg1 = (int*)alloc((size_t)(N + 1) * 4);
    int* cur1 = (int*)alloc((size_t)N * 4);
    int* regionCur = (int*)alloc(16 * 4);
    size_t zbytes = (w + o) - zbase;
    int* off0 = (int*)alloc((size_t)(N + 1) * 4);
    int* off1 = (int*)alloc((size_t)(N + 1) * 4);
    int* bsums = (int*)alloc(1024 * 4);
    int* perm0 = (int*)alloc((size_t)E0 * 4);
    int* perm1 = (int*)alloc((size_t)E1 * 4);
    float* partials = (float*)alloc((size_t)2 * 2048 * 4);
    float* beta = (float*)alloc(256);
    uint4* bfpw = (uint4*)alloc(2048 * 16);
    uint4* bfkw = (uint4*)alloc(2048 * 16);
    uint4* bfow = (uint4*)alloc(1024 * 16);
    int Emax = E0 > E1 ? E0 : E1;
    int cap = Emax / 8 + Emax / 16 + 1024;     // 1.5x expected + slack
    unsigned* stage = (unsigned*)alloc((size_t)2 * 8 * cap * 4);
    int* wcnt = (int*)alloc((size_t)16 * PW * 4);

    int rsize = (N + 7) / 8;   // dst-region size for XCD ownership

    hipMemsetAsync(zbase, 0, zbytes, stream);

    // K1: prep (3 blocks) + count (1024 blocks) — independent
    prep_count_kernel<<<1027, 256, 0, stream>>>(pw, kw, ow, bfpw, bfkw, bfow,
                                                ei0, E0, ei1, E1, wcnt, rsize);

    // K2: scanw (16) + proj (512) — independent
    proj_scanw_kernel<<<528, 256, 0, stream>>>(x, bfpw, pb,
                                               (unsigned short*)hbf, N,
                                               wcnt, regionCur);

    // K3: scatter (1024) + alpha (3125) — independent
    int ablocks = (N * 8 + 255) / 256;
    alpha_scatter_kernel<<<1024 + ablocks, 256, 0, stream>>>(
        ei0, E0, ei1, E1, wcnt, stage, cap, rsize,
        hbf, ls0, ld0, ls1, ld1, as0, ad0, as1, ad1, N);

    hist2_kernel<<<2048, 256, 0, stream>>>(stage, cap, regionCur,
                                           deg0, deg1, rsize);

    int n1 = N + 1;
    int nb = (n1 + 255) / 256;   // must be <= 512
    scan1_fused<<<2 * nb, 256, 0, stream>>>(deg0, off0, deg1, off1, bsums, n1, nb);
    scan2_fused<<<2, 512, 0, stream>>>(bsums, nb);
    scan3_fused<<<2 * nb, 256, 0, stream>>>(off0, off1, bsums, n1, nb);

    fill2_kernel<<<2048, 256, 0, stream>>>(stage, cap, regionCur,
                                           off0, cur0, perm0,
                                           off1, cur1, perm1, rsize);

    int aggBlocks = 2 * ((N + 3) / 4);
    agg_fused<<<aggBlocks, 256, 0, stream>>>(off0, perm0, as0, ad0,
                                             off1, perm1, as1, ad1,
                                             hbf, out0, out1, N);

    const int SG = 512;
    score_mfma<<<SG, 256, 0, stream>>>(out0, out1, bfkw, kb, q, partials, N);
    beta_kernel<<<1, 256, 0, stream>>>(partials, SG, 1.0f / (float)N, beta);
    final_mfma<<<512, 256, 0, stream>>>(out0, out1, bfow, ob, beta, (float*)d_out, N);
}

// Round 18
// 398.939 us; speedup vs baseline: 12.6169x; 1.2578x over previous
//
#include <hip/hip_runtime.h>
#include <hip/hip_bf16.h>

#define NEG 0.2f
#define CAP 64   // per-node bucket capacity; Poisson(16) max over 200K nodes ~45

typedef __attribute__((ext_vector_type(8))) short short8;  // 8 bf16 (4 VGPR)
typedef __attribute__((ext_vector_type(4))) float f32x4;

// bf16 helpers (manual RNE pack / unpack, branch-free, no NaN inputs here)
__device__ __forceinline__ unsigned short f2bf(float f) {
    unsigned u = __float_as_uint(f);
    u += 0x7fffu + ((u >> 16) & 1u);
    return (unsigned short)(u >> 16);
}
__device__ __forceinline__ unsigned pack2bf(float a, float b) {
    return (unsigned)f2bf(a) | ((unsigned)f2bf(b) << 16);
}
__device__ __forceinline__ float bflo(unsigned u) { return __uint_as_float(u << 16); }
__device__ __forceinline__ float bfhi(unsigned u) { return __uint_as_float(u & 0xffff0000u); }

__device__ __forceinline__ short8 asfrag(uint4 v) {
    union { uint4 u; short8 s; } x; x.u = v; return x.s;
}
__device__ __forceinline__ f32x4 mfma_bf16(short8 a, short8 b, f32x4 c) {
    return __builtin_amdgcn_mfma_f32_16x16x32_bf16(a, b, c, 0, 0, 0);
}
__device__ __forceinline__ float tanh_fast(float x) {
    x = fminf(fmaxf(x, -15.f), 15.f);
    float t = __expf(2.f * x);
    return (t - 1.f) / (t + 1.f);
}

#define PW 2048   // waves per metapath in count/scatter (512 blocks x 4)

// ---------------------------------------------------------------------------
// device helpers for the fused phases
// ---------------------------------------------------------------------------
__device__ void prep_dev(int b, const float* __restrict__ pw,
                         const float* __restrict__ kw, const float* __restrict__ ow,
                         uint4* __restrict__ bfpw, uint4* __restrict__ bfkw,
                         uint4* __restrict__ bfow)
{
    const float* src = (b == 0) ? pw : (b == 1) ? kw : ow;
    uint4* dst = (b == 0) ? bfpw : (b == 1) ? bfkw : bfow;
    int ncol  = (b == 2) ? 64 : 128;
    int slots = (b == 2) ? 1024 : 2048;
    for (int i = threadIdx.x; i < slots; i += 256) {
        int nt = i >> 8, kt = (i >> 6) & 3, lane = i & 63;
        int row0 = kt * 32 + ((lane >> 4) << 3);
        int col  = nt * 16 + (lane & 15);
        float e[8];
        #pragma unroll
        for (int j = 0; j < 8; ++j) e[j] = src[(row0 + j) * ncol + col];
        uint4 v;
        v.x = pack2bf(e[0], e[1]); v.y = pack2bf(e[2], e[3]);
        v.z = pack2bf(e[4], e[5]); v.w = pack2bf(e[6], e[7]);
        dst[i] = v;
    }
}

__device__ void count_dev(int bb, const int* __restrict__ ei0, int E0,
                          const int* __restrict__ ei1, int E1,
                          int* __restrict__ wcnt, int rsize)
{
    int mp = bb & 1;
    int b  = bb >> 1;
    const int* ei = mp ? ei1 : ei0;
    int E = mp ? E1 : E0;
    int lane = threadIdx.x & 63;
    int gw = b * 4 + (threadIdx.x >> 6);
    int myCnt = 0;
    for (int base = gw * 64; base < E; base += PW * 64) {
        int e = base + lane;
        int r = (e < E) ? (ei[E + e] / rsize) : 8;
        #pragma unroll
        for (int rr = 0; rr < 8; ++rr) {
            unsigned long long mask = __ballot(r == rr);
            if (lane == rr) myCnt += __popcll(mask);
        }
    }
    if (lane < 8) wcnt[(mp * 8 + lane) * PW + gw] = myCnt;
}

// K1: prep (blocks 0-2) + count (blocks 3-1026) — independent work fused.
__global__ __launch_bounds__(256) void prep_count_kernel(
    const float* __restrict__ pw, const float* __restrict__ kw,
    const float* __restrict__ ow,
    uint4* __restrict__ bfpw, uint4* __restrict__ bfkw, uint4* __restrict__ bfow,
    const int* __restrict__ ei0, int E0, const int* __restrict__ ei1, int E1,
    int* __restrict__ wcnt, int rsize)
{
    if (blockIdx.x < 3) prep_dev(blockIdx.x, pw, kw, ow, bfpw, bfkw, bfow);
    else count_dev(blockIdx.x - 3, ei0, E0, ei1, E1, wcnt, rsize);
}

__device__ void scanw_dev(int row, int* __restrict__ wcnt, int* __restrict__ regionCur)
{
    int* p = wcnt + row * PW;
    int t = threadIdx.x;
    __shared__ int tsum[256];
    int v[8];
    int s = 0;
    #pragma unroll
    for (int j = 0; j < 8; ++j) { v[j] = p[t * 8 + j]; s += v[j]; }
    tsum[t] = s;
    __syncthreads();
    for (int ofs = 1; ofs < 256; ofs <<= 1) {
        int x = (t >= ofs) ? tsum[t - ofs] : 0;
        __syncthreads();
        tsum[t] += x;
        __syncthreads();
    }
    int base = (t > 0) ? tsum[t - 1] : 0;   // exclusive
    #pragma unroll
    for (int j = 0; j < 8; ++j) {
        int val = v[j];
        p[t * 8 + j] = base;
        base += val;
    }
    if (t == 255) regionCur[row] = tsum[255];
}

__device__ void proj_dev(int bid, int ngrid, const float* __restrict__ x,
                         const uint4* __restrict__ bfg, const float* __restrict__ pb,
                         unsigned short* __restrict__ hst, int N)
{
    __shared__ uint4 Bf[2048];   // 32 KB
    __shared__ float pbs[128];
    int t = threadIdx.x;
    for (int i = t; i < 2048; i += 256) Bf[i] = bfg[i];
    if (t < 128) pbs[t] = pb[t];
    __syncthreads();
    int wid = t >> 6, l = t & 63, l15 = l & 15, lhi = l >> 4;
    float bv[8];
    #pragma unroll
    for (int nt = 0; nt < 8; ++nt) bv[nt] = pbs[nt * 16 + l15];
    int ntiles = (N + 15) >> 4;
    const float4* X4 = reinterpret_cast<const float4*>(x);
    for (int rt = bid * 4 + wid; rt < ntiles; rt += ngrid * 4) {
        int row = rt * 16 + l15;
        f32x4 acc[8];
        #pragma unroll
        for (int nt = 0; nt < 8; ++nt) acc[nt] = (f32x4)(0.f);
        #pragma unroll
        for (int kt = 0; kt < 4; ++kt) {
            uint4 af = make_uint4(0u, 0u, 0u, 0u);
            if (row < N) {
                float4 xa = X4[(size_t)row * 32 + kt * 8 + lhi * 2];
                float4 xb = X4[(size_t)row * 32 + kt * 8 + lhi * 2 + 1];
                af.x = pack2bf(xa.x, xa.y); af.y = pack2bf(xa.z, xa.w);
                af.z = pack2bf(xb.x, xb.y); af.w = pack2bf(xb.z, xb.w);
            }
            short8 a = asfrag(af);
            #pragma unroll
            for (int nt = 0; nt < 8; ++nt)
                acc[nt] = mfma_bf16(a, asfrag(Bf[nt * 256 + kt * 64 + l]), acc[nt]);
        }
        #pragma unroll
        for (int r = 0; r < 4; ++r) {
            int orow = rt * 16 + lhi * 4 + r;
            if (orow < N) {
                #pragma unroll
                for (int nt = 0; nt < 8; ++nt)
                    hst[(size_t)orow * 128 + nt * 16 + l15] = f2bf(acc[nt][r] + bv[nt]);
            }
        }
    }
}

// K2: scanw (blocks 0-15) + proj (blocks 16-527).
__global__ __launch_bounds__(256) void proj_scanw_kernel(
    const float* __restrict__ x, const uint4* __restrict__ bfg,
    const float* __restrict__ pb, unsigned short* __restrict__ hst, int N,
    int* __restrict__ wcnt, int* __restrict__ regionCur)
{
    if (blockIdx.x < 16) scanw_dev(blockIdx.x, wcnt, regionCur);
    else proj_dev(blockIdx.x - 16, 512, x, bfg, pb, hst, N);
}

__device__ void scatter_dev(int bb, const int* __restrict__ ei0, int E0,
                            const int* __restrict__ ei1, int E1,
                            const int* __restrict__ wcnt,
                            unsigned* __restrict__ stage, int cap, int rsize)
{
    int mp = bb & 1;
    int b  = bb >> 1;
    const int* ei = mp ? ei1 : ei0;
    int E = mp ? E1 : E0;
    unsigned* st = stage + (size_t)mp * 8 * cap;
    int lane = threadIdx.x & 63;
    int gw = b * 4 + (threadIdx.x >> 6);
    int myBase = (lane < 8) ? wcnt[(mp * 8 + lane) * PW + gw] : 0;
    for (int base = gw * 64; base < E; base += PW * 64) {
        int e = base + lane;
        bool valid = e < E;
        int d = valid ? ei[E + e] : 0;
        int s = valid ? ei[e] : 0;
        int r = valid ? (d / rsize) : 8;
        unsigned packed = ((unsigned)(d - r * rsize) << 17) | (unsigned)s;
        #pragma unroll
        for (int rr = 0; rr < 8; ++rr) {
            unsigned long long mask = __ballot(r == rr);
            int bse = __shfl(myBase, rr);
            if (r == rr) {
                int pos = __popcll(mask & ((1ull << lane) - 1ull));
                st[(size_t)rr * cap + bse + pos] = packed;
            }
            if (lane == rr) myBase += __popcll(mask);
        }
    }
}

__device__ void alpha_dev(int bid, const unsigned* __restrict__ hbf,
    const float* __restrict__ ls0, const float* __restrict__ ld0,
    const float* __restrict__ ls1, const float* __restrict__ ld1,
    float* __restrict__ as0, float* __restrict__ ad0,
    float* __restrict__ as1, float* __restrict__ ad1, int N)
{
    __shared__ float lin[512];
    int t = threadIdx.x;
    for (int i = t; i < 128; i += 256) {
        lin[i] = ls0[i]; lin[128 + i] = ld0[i];
        lin[256 + i] = ls1[i]; lin[384 + i] = ld1[i];
    }
    __syncthreads();
    int idx = bid * 256 + t;
    if (idx >= N * 8) return;
    int node = idx >> 3, head = idx & 7;
    const uint4* H = reinterpret_cast<const uint4*>(hbf);
    uint4 va = H[(size_t)node * 16 + head * 2];
    uint4 vb = H[(size_t)node * 16 + head * 2 + 1];
    float h[16];
    h[0] = bflo(va.x); h[1] = bfhi(va.x); h[2] = bflo(va.y); h[3] = bfhi(va.y);
    h[4] = bflo(va.z); h[5] = bfhi(va.z); h[6] = bflo(va.w); h[7] = bfhi(va.w);
    h[8] = bflo(vb.x); h[9] = bfhi(vb.x); h[10] = bflo(vb.y); h[11] = bfhi(vb.y);
    h[12] = bflo(vb.z); h[13] = bfhi(vb.z); h[14] = bflo(vb.w); h[15] = bfhi(vb.w);
    int base = head * 16;
    float d0 = 0.f, d1 = 0.f, d2 = 0.f, d3 = 0.f;
    #pragma unroll
    for (int d = 0; d < 16; ++d) {
        float hv = h[d];
        d0 = fmaf(hv, lin[base + d], d0);
        d1 = fmaf(hv, lin[128 + base + d], d1);
        d2 = fmaf(hv, lin[256 + base + d], d2);
        d3 = fmaf(hv, lin[384 + base + d], d3);
    }
    as0[idx] = d0; ad0[idx] = d1; as1[idx] = d2; ad1[idx] = d3;
}

// K3: scatter (blocks 0-1023) + alpha (blocks 1024+).
__global__ __launch_bounds__(256) void alpha_scatter_kernel(
    const int* __restrict__ ei0, int E0, const int* __restrict__ ei1, int E1,
    const int* __restrict__ wcnt, unsigned* __restrict__ stage, int cap, int rsize,
    const unsigned* __restrict__ hbf,
    const float* __restrict__ ls0, const float* __restrict__ ld0,
    const float* __restrict__ ls1, const float* __restrict__ ld1,
    float* __restrict__ as0, float* __restrict__ ad0,
    float* __restrict__ as1, float* __restrict__ ad1, int N)
{
    if (blockIdx.x < 1024)
        scatter_dev(blockIdx.x, ei0, E0, ei1, E1, wcnt, stage, cap, rsize);
    else
        alpha_dev(blockIdx.x - 1024, hbf, ls0, ld0, ls1, ld1,
                  as0, ad0, as1, ad1, N);
}

// ---------------------------------------------------------------------------
// K4: bucketed fill — single pass replaces hist2 + scan x3 + fill2.
// perm3[d*CAP + pos], pos = atomicAdd(cnt[d]).  Region-affine blocks keep
// each region's 3.2MB bucket slice + cnt slice L2-resident.  CAP=64 is
// unreachable for Poisson(16) degrees (max ~45 over 200K nodes).
// ---------------------------------------------------------------------------
__global__ __launch_bounds__(256) void fill3_kernel(
    const unsigned* __restrict__ stage, int cap, const int* __restrict__ regionCur,
    int* __restrict__ cnt0, int* __restrict__ perm3_0,
    int* __restrict__ cnt1, int* __restrict__ perm3_1, int rsize)
{
    int r = blockIdx.x & 7;
    int mp = (blockIdx.x >> 3) & 1;
    int sub = blockIdx.x >> 4;                // 0..127
    const unsigned* st = stage + ((size_t)mp * 8 + r) * cap;
    int cnt = regionCur[mp * 8 + r];
    int dbase = r * rsize;
    int* cn = mp ? cnt1 : cnt0;
    int* pm = mp ? perm3_1 : perm3_0;
    for (int i = sub * 256 + threadIdx.x; i < cnt; i += 128 * 256) {
        unsigned v = st[i];
        int d = dbase + (int)(v >> 17);
        int s = (int)(v & 0x1FFFFu);
        int pos = atomicAdd(&cn[d], 1);
        if (pos < CAP) pm[(size_t)d * CAP + pos] = s;
    }
}

// ---------------------------------------------------------------------------
// K5: per-destination aggregation (fused mp0+mp1), bucket layout.
// Lane-specialized weights + batched gather arrays (R15 structure).
// ---------------------------------------------------------------------------
__global__ __launch_bounds__(256) void agg_fused(
    const int* __restrict__ cnt0, const int* __restrict__ perm3_0,
    const float* __restrict__ as0, const float* __restrict__ ad0,
    const int* __restrict__ cnt1, const int* __restrict__ perm3_1,
    const float* __restrict__ as1, const float* __restrict__ ad1,
    const unsigned* __restrict__ hbf,
    unsigned* __restrict__ o0, unsigned* __restrict__ o1, int N)
{
    int mp = blockIdx.x & 1;
    int wid = (blockIdx.x >> 1) * 4 + (threadIdx.x >> 6);
    int lane = threadIdx.x & 63;
    if (wid >= N) return;
    const int* cn = mp ? cnt1 : cnt0;
    const int* perm = mp ? perm3_1 : perm3_0;
    const float* asrc = mp ? as1 : as0;
    const float* adst = mp ? ad1 : ad0;
    unsigned* outm = mp ? o1 : o0;
    int deg = cn[wid];
    deg = deg < CAP ? deg : CAP;
    int start = wid * CAP, end = start + deg;
    int h2 = lane >> 3;            // head: owns dims AND weight computation
    int esel = lane & 7;           // edge slot this lane computes weight for
    int wsrc = lane & 56;          // shuffle base: lane (wsrc|k) holds w[k][h2]
    float av = adst[wid * 8 + h2];
    float p0 = 0.f, p1 = 0.f, q0 = 0.f, q1 = 0.f;
    float sA = 0.f, sB = 0.f;
    for (int i = start; i < end; i += 8) {
        int idx = i + esel;
        int sm = perm[idx < end ? idx : start];
        int sk[8];
        #pragma unroll
        for (int k = 0; k < 8; ++k) sk[k] = __shfl(sm, k);
        unsigned u[8];
        #pragma unroll
        for (int k = 0; k < 8; ++k) u[k] = hbf[(unsigned)(sk[k] * 64) + lane];
        float alv = asrc[sm * 8 + h2] + av;
        alv = alv > 0.f ? alv : NEG * alv;
        float wm = (idx < end) ? __expf(alv) : 0.f;
        #pragma unroll
        for (int k = 0; k < 8; ++k) {
            float wk = __shfl(wm, wsrc | k);
            if (k & 1) {
                q0 = fmaf(bflo(u[k]), wk, q0);
                q1 = fmaf(bfhi(u[k]), wk, q1);
                sB += wk;
            } else {
                p0 = fmaf(bflo(u[k]), wk, p0);
                p1 = fmaf(bfhi(u[k]), wk, p1);
                sA += wk;
            }
        }
    }
    float acc0 = p0 + q0, acc1 = p1 + q1, ssum = sA + sB;
    float inv = 1.f / (ssum + 1e-16f);
    acc0 *= inv; acc1 *= inv;
    acc0 = acc0 > 0.f ? acc0 : 0.f;   // relu
    acc1 = acc1 > 0.f ? acc1 : 0.f;
    outm[(size_t)wid * 64 + lane] = pack2bf(acc0, acc1);
}

// ---------------------------------------------------------------------------
// K6: semantic-attention scores via MFMA over bf16 out0/out1.
// ---------------------------------------------------------------------------
__global__ __launch_bounds__(256) void score_mfma(
    const unsigned* __restrict__ o0, const unsigned* __restrict__ o1,
    const uint4* __restrict__ bfg, const float* __restrict__ kb,
    const float* __restrict__ q, float* __restrict__ partials, int N)
{
    __shared__ uint4 Bf[2048];   // 32 KB (k_w fragments)
    __shared__ float kbs[128], qs[128];
    __shared__ float red[2];
    int t = threadIdx.x;
    for (int i = t; i < 2048; i += 256) Bf[i] = bfg[i];
    if (t < 128) { kbs[t] = kb[t]; qs[t] = q[t]; }
    if (t < 2) red[t] = 0.f;
    __syncthreads();
    int wid = t >> 6, l = t & 63, l15 = l & 15, lhi = l >> 4;
    float qv[8], kbv[8];
    #pragma unroll
    for (int nt = 0; nt < 8; ++nt) {
        qv[nt] = qs[nt * 16 + l15];
        kbv[nt] = kbs[nt * 16 + l15];
    }
    int ntiles = (N + 15) >> 4;
    int ttiles = 2 * ntiles;
    const uint4* A0 = reinterpret_cast<const uint4*>(o0);
    const uint4* A1 = reinterpret_cast<const uint4*>(o1);
    for (int tid = blockIdx.x * 4 + wid; tid < ttiles; tid += gridDim.x * 4) {
        int m = (tid >= ntiles);
        int rt = tid - (m ? ntiles : 0);
        const uint4* A = m ? A1 : A0;
        int row = rt * 16 + l15;
        f32x4 acc[8];
        #pragma unroll
        for (int nt = 0; nt < 8; ++nt) acc[nt] = (f32x4)(0.f);
        #pragma unroll
        for (int kt = 0; kt < 4; ++kt) {
            uint4 av = (row < N) ? A[(size_t)row * 16 + kt * 4 + lhi]
                                 : make_uint4(0u, 0u, 0u, 0u);
            short8 a = asfrag(av);
            #pragma unroll
            for (int nt = 0; nt < 8; ++nt)
                acc[nt] = mfma_bf16(a, asfrag(Bf[nt * 256 + kt * 64 + l]), acc[nt]);
        }
        float partial = 0.f;
        int rbase = rt * 16 + lhi * 4;
        #pragma unroll
        for (int r = 0; r < 4; ++r) {
            if (rbase + r < N) {
                #pragma unroll
                for (int nt = 0; nt < 8; ++nt)
                    partial += qv[nt] * tanh_fast(acc[nt][r] + kbv[nt]);
            }
        }
        partial += __shfl_xor(partial, 1);
        partial += __shfl_xor(partial, 2);
        partial += __shfl_xor(partial, 4);
        partial += __shfl_xor(partial, 8);
        partial += __shfl_xor(partial, 16);
        partial += __shfl_xor(partial, 32);
        if (l == 0) atomicAdd(&red[m], partial);
    }
    __syncthreads();
    if (t < 2) partials[blockIdx.x * 2 + t] = red[t];
}

// ---------------------------------------------------------------------------
// K7: y = (b0*out0 + b1*out1) @ out_w + out_b via MFMA (f32 output).
// beta fused: every block redundantly reduces the 2*SG partials (4KB, L2).
// ---------------------------------------------------------------------------
__global__ __launch_bounds__(256) void final_mfma(
    const unsigned* __restrict__ o0, const unsigned* __restrict__ o1,
    const uint4* __restrict__ bfg, const float* __restrict__ ob,
    const float* __restrict__ partials, int G, float invN,
    float* __restrict__ y, int N)
{
    __shared__ uint4 Bf[1024];   // 16 KB (out_w fragments)
    __shared__ float obs[64];
    __shared__ float r0s[256], r1s[256];
    int t = threadIdx.x;
    for (int i = t; i < 1024; i += 256) Bf[i] = bfg[i];
    if (t < 64) obs[t] = ob[t];
    // inline beta reduction (replicated per block)
    float s0 = 0.f, s1 = 0.f;
    for (int i = t; i < G; i += 256) { s0 += partials[i * 2]; s1 += partials[i * 2 + 1]; }
    r0s[t] = s0; r1s[t] = s1;
    __syncthreads();
    for (int o = 128; o > 0; o >>= 1) {
        if (t < o) { r0s[t] += r0s[t + o]; r1s[t] += r1s[t + o]; }
        __syncthreads();
    }
    float a = r0s[0] * invN, b = r1s[0] * invN;
    float mx = fmaxf(a, b);
    float ea = __expf(a - mx), eb = __expf(b - mx);
    float binv = 1.f / (ea + eb);
    float b0 = ea * binv, b1 = eb * binv;
    int wid = t >> 6, l = t & 63, l15 = l & 15, lhi = l >> 4;
    float obv[4];
    #pragma unroll
    for (int nt = 0; nt < 4; ++nt) obv[nt] = obs[nt * 16 + l15];
    int ntiles = (N + 15) >> 4;
    const uint4* A0 = reinterpret_cast<const uint4*>(o0);
    const uint4* A1 = reinterpret_cast<const uint4*>(o1);
    for (int rt = blockIdx.x * 4 + wid; rt < ntiles; rt += gridDim.x * 4) {
        int row = rt * 16 + l15;
        f32x4 acc[4];
        #pragma unroll
        for (int nt = 0; nt < 4; ++nt) acc[nt] = (f32x4)(0.f);
        #pragma unroll
        for (int kt = 0; kt < 4; ++kt) {
            uint4 af = make_uint4(0u, 0u, 0u, 0u);
            if (row < N) {
                uint4 a0 = A0[(size_t)row * 16 + kt * 4 + lhi];
                uint4 a1 = A1[(size_t)row * 16 + kt * 4 + lhi];
                af.x = pack2bf(b0 * bflo(a0.x) + b1 * bflo(a1.x),
                               b0 * bfhi(a0.x) + b1 * bfhi(a1.x));
                af.y = pack2bf(b0 * bflo(a0.y) + b1 * bflo(a1.y),
                               b0 * bfhi(a0.y) + b1 * bfhi(a1.y));
                af.z = pack2bf(b0 * bflo(a0.z) + b1 * bflo(a1.z),
                               b0 * bfhi(a0.z) + b1 * bfhi(a1.z));
                af.w = pack2bf(b0 * bflo(a0.w) + b1 * bflo(a1.w),
                               b0 * bfhi(a0.w) + b1 * bfhi(a1.w));
            }
            short8 a = asfrag(af);
            #pragma unroll
            for (int nt = 0; nt < 4; ++nt)
                acc[nt] = mfma_bf16(a, asfrag(Bf[nt * 256 + kt * 64 + l]), acc[nt]);
        }
        #pragma unroll
        for (int r = 0; r < 4; ++r) {
            int orow = rt * 16 + lhi * 4 + r;
            if (orow < N) {
                #pragma unroll
                for (int nt = 0; nt < 4; ++nt)
                    y[(size_t)orow * 64 + nt * 16 + l15] = acc[nt][r] + obv[nt];
            }
        }
    }
}

// ---------------------------------------------------------------------------
extern "C" void kernel_launch(void* const* d_in, const int* in_sizes, int n_in,
                              void* d_out, int out_size, void* d_ws, size_t ws_size,
                              hipStream_t stream)
{
    const float* x   = (const float*)d_in[0];
    const int*   ei0 = (const int*)d_in[1];
    const int*   ei1 = (const int*)d_in[2];
    const float* pw  = (const float*)d_in[3];
    const float* pb  = (const float*)d_in[4];
    const float* ls0 = (const float*)d_in[5];
    const float* ld0 = (const float*)d_in[6];
    const float* ls1 = (const float*)d_in[7];
    const float* ld1 = (const float*)d_in[8];
    const float* kw  = (const float*)d_in[9];
    const float* kb  = (const float*)d_in[10];
    const float* q   = (const float*)d_in[11];
    const float* ow  = (const float*)d_in[12];
    const float* ob  = (const float*)d_in[13];
    int N  = in_sizes[0] / 128;
    int E0 = in_sizes[1] / 2;
    int E1 = in_sizes[2] / 2;

    char* w = (char*)d_ws;
    size_t o = 0;
    auto alloc = [&](size_t bytes) -> void* {
        void* p = w + o;
        o += (bytes + 255) & ~(size_t)255;
        return p;
    };
    unsigned* hbf  = (unsigned*)alloc((size_t)N * 128 * 2);   // bf16 h
    float* as0  = (float*)alloc((size_t)N * 8 * 4);
    float* ad0  = (float*)alloc((size_t)N * 8 * 4);
    float* as1  = (float*)alloc((size_t)N * 8 * 4);
    float* ad1  = (float*)alloc((size_t)N * 8 * 4);
    unsigned* out0 = (unsigned*)alloc((size_t)N * 128 * 2);   // bf16 out
    unsigned* out1 = (unsigned*)alloc((size_t)N * 128 * 2);
    char*  zbase = w + o;                       // contiguous zeroed region
    int* cnt0 = (int*)alloc((size_t)N * 4);
    int* cnt1 = (int*)alloc((size_t)N * 4);
    int* regionCur = (int*)alloc(16 * 4);
    size_t zbytes = (w + o) - zbase;
    int* perm3_0 = (int*)alloc((size_t)N * CAP * 4);
    int* perm3_1 = (int*)alloc((size_t)N * CAP * 4);
    float* partials = (float*)alloc((size_t)2 * 2048 * 4);
    uint4* bfpw = (uint4*)alloc(2048 * 16);
    uint4* bfkw = (uint4*)alloc(2048 * 16);
    uint4* bfow = (uint4*)alloc(1024 * 16);
    int Emax = E0 > E1 ? E0 : E1;
    int cap = Emax / 8 + Emax / 16 + 1024;     // 1.5x expected + slack
    unsigned* stage = (unsigned*)alloc((size_t)2 * 8 * cap * 4);
    int* wcnt = (int*)alloc((size_t)16 * PW * 4);

    int rsize = (N + 7) / 8;   // dst-region size for XCD ownership

    hipMemsetAsync(zbase, 0, zbytes, stream);

    // K1: prep (3 blocks) + count (1024 blocks) — independent
    prep_count_kernel<<<1027, 256, 0, stream>>>(pw, kw, ow, bfpw, bfkw, bfow,
                                                ei0, E0, ei1, E1, wcnt, rsize);

    // K2: scanw (16) + proj (512) — independent
    proj_scanw_kernel<<<528, 256, 0, stream>>>(x, bfpw, pb,
                                               (unsigned short*)hbf, N,
                                               wcnt, regionCur);

    // K3: scatter (1024) + alpha — independent
    int ablocks = (N * 8 + 255) / 256;
    alpha_scatter_kernel<<<1024 + ablocks, 256, 0, stream>>>(
        ei0, E0, ei1, E1, wcnt, stage, cap, rsize,
        hbf, ls0, ld0, ls1, ld1, as0, ad0, as1, ad1, N);

    // K4: single-pass bucketed fill (replaces hist2 + scan x3 + fill2)
    fill3_kernel<<<2048, 256, 0, stream>>>(stage, cap, regionCur,
                                           cnt0, perm3_0, cnt1, perm3_1, rsize);

    // K5: aggregation
    int aggBlocks = 2 * ((N + 3) / 4);
    agg_fused<<<aggBlocks, 256, 0, stream>>>(cnt0, perm3_0, as0, ad0,
                                             cnt1, perm3_1, as1, ad1,
                                             hbf, out0, out1, N);

    // K6: semantic scores
    const int SG = 512;
    score_mfma<<<SG, 256, 0, stream>>>(out0, out1, bfkw, kb, q, partials, N);

    // K7: final projection with inlined beta
    final_mfma<<<512, 256, 0, stream>>>(out0, out1, bfow, ob,
                                        partials, SG, 1.0f / (float)N,
                                        (float*)d_out, N);
}

// Round 19
// 397.707 us; speedup vs baseline: 12.6560x; 1.0031x over previous
//
#include <hip/hip_runtime.h>
#include <hip/hip_bf16.h>

#define NEG 0.2f
#define CAP 64    // per-node bucket capacity; Poisson(16) max over 200K nodes ~45
#define JSUB 16   // sub-windows per region (single-owner write windows)

typedef __attribute__((ext_vector_type(8))) short short8;  // 8 bf16 (4 VGPR)
typedef __attribute__((ext_vector_type(4))) float f32x4;

// bf16 helpers (manual RNE pack / unpack, branch-free, no NaN inputs here)
__device__ __forceinline__ unsigned short f2bf(float f) {
    unsigned u = __float_as_uint(f);
    u += 0x7fffu + ((u >> 16) & 1u);
    return (unsigned short)(u >> 16);
}
__device__ __forceinline__ unsigned pack2bf(float a, float b) {
    return (unsigned)f2bf(a) | ((unsigned)f2bf(b) << 16);
}
__device__ __forceinline__ float bflo(unsigned u) { return __uint_as_float(u << 16); }
__device__ __forceinline__ float bfhi(unsigned u) { return __uint_as_float(u & 0xffff0000u); }

__device__ __forceinline__ short8 asfrag(uint4 v) {
    union { uint4 u; short8 s; } x; x.u = v; return x.s;
}
__device__ __forceinline__ f32x4 mfma_bf16(short8 a, short8 b, f32x4 c) {
    return __builtin_amdgcn_mfma_f32_16x16x32_bf16(a, b, c, 0, 0, 0);
}
__device__ __forceinline__ float tanh_fast(float x) {
    x = fminf(fmaxf(x, -15.f), 15.f);
    float t = __expf(2.f * x);
    return (t - 1.f) / (t + 1.f);
}

#define PW 2048   // waves per metapath in count/scatter (512 blocks x 4)

// ---------------------------------------------------------------------------
// device helpers for the fused phases
// ---------------------------------------------------------------------------
__device__ void prep_dev(int b, const float* __restrict__ pw,
                         const float* __restrict__ kw, const float* __restrict__ ow,
                         uint4* __restrict__ bfpw, uint4* __restrict__ bfkw,
                         uint4* __restrict__ bfow)
{
    const float* src = (b == 0) ? pw : (b == 1) ? kw : ow;
    uint4* dst = (b == 0) ? bfpw : (b == 1) ? bfkw : bfow;
    int ncol  = (b == 2) ? 64 : 128;
    int slots = (b == 2) ? 1024 : 2048;
    for (int i = threadIdx.x; i < slots; i += 256) {
        int nt = i >> 8, kt = (i >> 6) & 3, lane = i & 63;
        int row0 = kt * 32 + ((lane >> 4) << 3);
        int col  = nt * 16 + (lane & 15);
        float e[8];
        #pragma unroll
        for (int j = 0; j < 8; ++j) e[j] = src[(row0 + j) * ncol + col];
        uint4 v;
        v.x = pack2bf(e[0], e[1]); v.y = pack2bf(e[2], e[3]);
        v.z = pack2bf(e[4], e[5]); v.w = pack2bf(e[6], e[7]);
        dst[i] = v;
    }
}

__device__ void count_dev(int bb, const int* __restrict__ ei0, int E0,
                          const int* __restrict__ ei1, int E1,
                          int* __restrict__ wcnt, int rsize)
{
    int mp = bb & 1;
    int b  = bb >> 1;
    const int* ei = mp ? ei1 : ei0;
    int E = mp ? E1 : E0;
    int lane = threadIdx.x & 63;
    int gw = b * 4 + (threadIdx.x >> 6);
    int myCnt = 0;
    for (int base = gw * 64; base < E; base += PW * 64) {
        int e = base + lane;
        int r = (e < E) ? (ei[E + e] / rsize) : 8;
        #pragma unroll
        for (int rr = 0; rr < 8; ++rr) {
            unsigned long long mask = __ballot(r == rr);
            if (lane == rr) myCnt += __popcll(mask);
        }
    }
    if (lane < 8) wcnt[(mp * 8 + lane) * PW + gw] = myCnt;
}

// K1: prep (blocks 0-2) + count (blocks 3-1026) — independent work fused.
__global__ __launch_bounds__(256) void prep_count_kernel(
    const float* __restrict__ pw, const float* __restrict__ kw,
    const float* __restrict__ ow,
    uint4* __restrict__ bfpw, uint4* __restrict__ bfkw, uint4* __restrict__ bfow,
    const int* __restrict__ ei0, int E0, const int* __restrict__ ei1, int E1,
    int* __restrict__ wcnt, int rsize)
{
    if (blockIdx.x < 3) prep_dev(blockIdx.x, pw, kw, ow, bfpw, bfkw, bfow);
    else count_dev(blockIdx.x - 3, ei0, E0, ei1, E1, wcnt, rsize);
}

__device__ void scanw_dev(int row, int* __restrict__ wcnt, int* __restrict__ regionCur)
{
    int* p = wcnt + row * PW;
    int t = threadIdx.x;
    __shared__ int tsum[256];
    int v[8];
    int s = 0;
    #pragma unroll
    for (int j = 0; j < 8; ++j) { v[j] = p[t * 8 + j]; s += v[j]; }
    tsum[t] = s;
    __syncthreads();
    for (int ofs = 1; ofs < 256; ofs <<= 1) {
        int x = (t >= ofs) ? tsum[t - ofs] : 0;
        __syncthreads();
        tsum[t] += x;
        __syncthreads();
    }
    int base = (t > 0) ? tsum[t - 1] : 0;   // exclusive
    #pragma unroll
    for (int j = 0; j < 8; ++j) {
        int val = v[j];
        p[t * 8 + j] = base;
        base += val;
    }
    if (t == 255) regionCur[row] = tsum[255];
}

__device__ void proj_dev(int bid, int ngrid, const float* __restrict__ x,
                         const uint4* __restrict__ bfg, const float* __restrict__ pb,
                         unsigned short* __restrict__ hst, int N)
{
    __shared__ uint4 Bf[2048];   // 32 KB
    __shared__ float pbs[128];
    int t = threadIdx.x;
    for (int i = t; i < 2048; i += 256) Bf[i] = bfg[i];
    if (t < 128) pbs[t] = pb[t];
    __syncthreads();
    int wid = t >> 6, l = t & 63, l15 = l & 15, lhi = l >> 4;
    float bv[8];
    #pragma unroll
    for (int nt = 0; nt < 8; ++nt) bv[nt] = pbs[nt * 16 + l15];
    int ntiles = (N + 15) >> 4;
    const float4* X4 = reinterpret_cast<const float4*>(x);
    for (int rt = bid * 4 + wid; rt < ntiles; rt += ngrid * 4) {
        int row = rt * 16 + l15;
        f32x4 acc[8];
        #pragma unroll
        for (int nt = 0; nt < 8; ++nt) acc[nt] = (f32x4)(0.f);
        #pragma unroll
        for (int kt = 0; kt < 4; ++kt) {
            uint4 af = make_uint4(0u, 0u, 0u, 0u);
            if (row < N) {
                float4 xa = X4[(size_t)row * 32 + kt * 8 + lhi * 2];
                float4 xb = X4[(size_t)row * 32 + kt * 8 + lhi * 2 + 1];
                af.x = pack2bf(xa.x, xa.y); af.y = pack2bf(xa.z, xa.w);
                af.z = pack2bf(xb.x, xb.y); af.w = pack2bf(xb.z, xb.w);
            }
            short8 a = asfrag(af);
            #pragma unroll
            for (int nt = 0; nt < 8; ++nt)
                acc[nt] = mfma_bf16(a, asfrag(Bf[nt * 256 + kt * 64 + l]), acc[nt]);
        }
        #pragma unroll
        for (int r = 0; r < 4; ++r) {
            int orow = rt * 16 + lhi * 4 + r;
            if (orow < N) {
                #pragma unroll
                for (int nt = 0; nt < 8; ++nt)
                    hst[(size_t)orow * 128 + nt * 16 + l15] = f2bf(acc[nt][r] + bv[nt]);
            }
        }
    }
}

// K2: scanw (blocks 0-15) + proj (blocks 16-527).
__global__ __launch_bounds__(256) void proj_scanw_kernel(
    const float* __restrict__ x, const uint4* __restrict__ bfg,
    const float* __restrict__ pb, unsigned short* __restrict__ hst, int N,
    int* __restrict__ wcnt, int* __restrict__ regionCur)
{
    if (blockIdx.x < 16) scanw_dev(blockIdx.x, wcnt, regionCur);
    else proj_dev(blockIdx.x - 16, 512, x, bfg, pb, hst, N);
}

__device__ void scatter_dev(int bb, const int* __restrict__ ei0, int E0,
                            const int* __restrict__ ei1, int E1,
                            const int* __restrict__ wcnt,
                            unsigned* __restrict__ stage, int cap, int rsize)
{
    int mp = bb & 1;
    int b  = bb >> 1;
    const int* ei = mp ? ei1 : ei0;
    int E = mp ? E1 : E0;
    unsigned* st = stage + (size_t)mp * 8 * cap;
    int lane = threadIdx.x & 63;
    int gw = b * 4 + (threadIdx.x >> 6);
    int myBase = (lane < 8) ? wcnt[(mp * 8 + lane) * PW + gw] : 0;
    for (int base = gw * 64; base < E; base += PW * 64) {
        int e = base + lane;
        bool valid = e < E;
        int d = valid ? ei[E + e] : 0;
        int s = valid ? ei[e] : 0;
        int r = valid ? (d / rsize) : 8;
        unsigned packed = ((unsigned)(d - r * rsize) << 17) | (unsigned)s;
        #pragma unroll
        for (int rr = 0; rr < 8; ++rr) {
            unsigned long long mask = __ballot(r == rr);
            int bse = __shfl(myBase, rr);
            if (r == rr) {
                int pos = __popcll(mask & ((1ull << lane) - 1ull));
                st[(size_t)rr * cap + bse + pos] = packed;
            }
            if (lane == rr) myBase += __popcll(mask);
        }
    }
}

__device__ void alpha_dev(int bid, const unsigned* __restrict__ hbf,
    const float* __restrict__ ls0, const float* __restrict__ ld0,
    const float* __restrict__ ls1, const float* __restrict__ ld1,
    float* __restrict__ as0, float* __restrict__ ad0,
    float* __restrict__ as1, float* __restrict__ ad1, int N)
{
    __shared__ float lin[512];
    int t = threadIdx.x;
    for (int i = t; i < 128; i += 256) {
        lin[i] = ls0[i]; lin[128 + i] = ld0[i];
        lin[256 + i] = ls1[i]; lin[384 + i] = ld1[i];
    }
    __syncthreads();
    int idx = bid * 256 + t;
    if (idx >= N * 8) return;
    int node = idx >> 3, head = idx & 7;
    const uint4* H = reinterpret_cast<const uint4*>(hbf);
    uint4 va = H[(size_t)node * 16 + head * 2];
    uint4 vb = H[(size_t)node * 16 + head * 2 + 1];
    float h[16];
    h[0] = bflo(va.x); h[1] = bfhi(va.x); h[2] = bflo(va.y); h[3] = bfhi(va.y);
    h[4] = bflo(va.z); h[5] = bfhi(va.z); h[6] = bflo(va.w); h[7] = bfhi(va.w);
    h[8] = bflo(vb.x); h[9] = bfhi(vb.x); h[10] = bflo(vb.y); h[11] = bfhi(vb.y);
    h[12] = bflo(vb.z); h[13] = bfhi(vb.z); h[14] = bflo(vb.w); h[15] = bfhi(vb.w);
    int base = head * 16;
    float d0 = 0.f, d1 = 0.f, d2 = 0.f, d3 = 0.f;
    #pragma unroll
    for (int d = 0; d < 16; ++d) {
        float hv = h[d];
        d0 = fmaf(hv, lin[base + d], d0);
        d1 = fmaf(hv, lin[128 + base + d], d1);
        d2 = fmaf(hv, lin[256 + base + d], d2);
        d3 = fmaf(hv, lin[384 + base + d], d3);
    }
    as0[idx] = d0; ad0[idx] = d1; as1[idx] = d2; ad1[idx] = d3;
}

// K3: scatter (blocks 0-1023) + alpha (blocks 1024+).
__global__ __launch_bounds__(256) void alpha_scatter_kernel(
    const int* __restrict__ ei0, int E0, const int* __restrict__ ei1, int E1,
    const int* __restrict__ wcnt, unsigned* __restrict__ stage, int cap, int rsize,
    const unsigned* __restrict__ hbf,
    const float* __restrict__ ls0, const float* __restrict__ ld0,
    const float* __restrict__ ls1, const float* __restrict__ ld1,
    float* __restrict__ as0, float* __restrict__ ad0,
    float* __restrict__ as1, float* __restrict__ ad1, int N)
{
    if (blockIdx.x < 1024)
        scatter_dev(blockIdx.x, ei0, E0, ei1, E1, wcnt, stage, cap, rsize);
    else
        alpha_dev(blockIdx.x - 1024, hbf, ls0, ld0, ls1, ld1,
                  as0, ad0, as1, ad1, N);
}

// ---------------------------------------------------------------------------
// K4: single-owner sub-window bucket fill (fix for 13x write amplification).
// Block (mp, r, j): reads the ENTIRE region stream (L2-resident, cheap),
// keeps only entries with dst in its 782-node window, counts in LDS
// (zero global atomics), writes into a 200KB bucket window owned solely by
// this block -> every bucket line collects all writes before eviction.
// cnt written non-atomically at the end (single owner per node).
// ---------------------------------------------------------------------------
__global__ __launch_bounds__(256) void fill3b_kernel(
    const unsigned* __restrict__ stage, int cap, const int* __restrict__ regionCur,
    int* __restrict__ cnt0, int* __restrict__ perm3_0,
    int* __restrict__ cnt1, int* __restrict__ perm3_1, int rsize, int N)
{
    __shared__ int lcnt[1024];
    int j  = blockIdx.x & (JSUB - 1);
    int r  = (blockIdx.x >> 4) & 7;
    int mp = blockIdx.x >> 7;
    const unsigned* st = stage + ((size_t)mp * 8 + r) * cap;
    int cnt = regionCur[mp * 8 + r];
    int wsize = (rsize + JSUB - 1) / JSUB;
    int w0 = j * wsize;
    int w1 = w0 + wsize; if (w1 > rsize) w1 = rsize;
    int dbase = r * rsize;
    int* cn = mp ? cnt1 : cnt0;
    int* pm = mp ? perm3_1 : perm3_0;
    for (int i = threadIdx.x; i < wsize; i += 256) lcnt[i] = 0;
    __syncthreads();
    int i = threadIdx.x;
    for (; i + 768 < cnt; i += 1024) {
        unsigned v0 = st[i];
        unsigned v1 = st[i + 256];
        unsigned v2 = st[i + 512];
        unsigned v3 = st[i + 768];
        int d0 = (int)(v0 >> 17), d1 = (int)(v1 >> 17);
        int d2 = (int)(v2 >> 17), d3 = (int)(v3 >> 17);
        if (d0 >= w0 && d0 < w1) {
            int pos = atomicAdd(&lcnt[d0 - w0], 1);
            if (pos < CAP) pm[(size_t)(dbase + d0) * CAP + pos] = (int)(v0 & 0x1FFFFu);
        }
        if (d1 >= w0 && d1 < w1) {
            int pos = atomicAdd(&lcnt[d1 - w0], 1);
            if (pos < CAP) pm[(size_t)(dbase + d1) * CAP + pos] = (int)(v1 & 0x1FFFFu);
        }
        if (d2 >= w0 && d2 < w1) {
            int pos = atomicAdd(&lcnt[d2 - w0], 1);
            if (pos < CAP) pm[(size_t)(dbase + d2) * CAP + pos] = (int)(v2 & 0x1FFFFu);
        }
        if (d3 >= w0 && d3 < w1) {
            int pos = atomicAdd(&lcnt[d3 - w0], 1);
            if (pos < CAP) pm[(size_t)(dbase + d3) * CAP + pos] = (int)(v3 & 0x1FFFFu);
        }
    }
    for (; i < cnt; i += 256) {
        unsigned v = st[i];
        int dl = (int)(v >> 17);
        if (dl >= w0 && dl < w1) {
            int pos = atomicAdd(&lcnt[dl - w0], 1);
            if (pos < CAP) pm[(size_t)(dbase + dl) * CAP + pos] = (int)(v & 0x1FFFFu);
        }
    }
    __syncthreads();
    for (int k = threadIdx.x; k < wsize; k += 256) {
        int dl = w0 + k;
        int d = dbase + dl;
        if (dl < rsize && d < N) cn[d] = lcnt[k];
    }
}

// ---------------------------------------------------------------------------
// K5: per-destination aggregation (fused mp0+mp1), bucket layout.
// Lane-specialized weights + batched gather arrays (R15 structure).
// ---------------------------------------------------------------------------
__global__ __launch_bounds__(256) void agg_fused(
    const int* __restrict__ cnt0, const int* __restrict__ perm3_0,
    const float* __restrict__ as0, const float* __restrict__ ad0,
    const int* __restrict__ cnt1, const int* __restrict__ perm3_1,
    const float* __restrict__ as1, const float* __restrict__ ad1,
    const unsigned* __restrict__ hbf,
    unsigned* __restrict__ o0, unsigned* __restrict__ o1, int N)
{
    int mp = blockIdx.x & 1;
    int wid = (blockIdx.x >> 1) * 4 + (threadIdx.x >> 6);
    int lane = threadIdx.x & 63;
    if (wid >= N) return;
    const int* cn = mp ? cnt1 : cnt0;
    const int* perm = mp ? perm3_1 : perm3_0;
    const float* asrc = mp ? as1 : as0;
    const float* adst = mp ? ad1 : ad0;
    unsigned* outm = mp ? o1 : o0;
    int deg = cn[wid];
    deg = deg < CAP ? deg : CAP;
    int start = wid * CAP, end = start + deg;
    int h2 = lane >> 3;            // head: owns dims AND weight computation
    int esel = lane & 7;           // edge slot this lane computes weight for
    int wsrc = lane & 56;          // shuffle base: lane (wsrc|k) holds w[k][h2]
    float av = adst[wid * 8 + h2];
    float p0 = 0.f, p1 = 0.f, q0 = 0.f, q1 = 0.f;
    float sA = 0.f, sB = 0.f;
    for (int i = start; i < end; i += 8) {
        int idx = i + esel;
        int sm = perm[idx < end ? idx : start];
        int sk[8];
        #pragma unroll
        for (int k = 0; k < 8; ++k) sk[k] = __shfl(sm, k);
        unsigned u[8];
        #pragma unroll
        for (int k = 0; k < 8; ++k) u[k] = hbf[(unsigned)(sk[k] * 64) + lane];
        float alv = asrc[sm * 8 + h2] + av;
        alv = alv > 0.f ? alv : NEG * alv;
        float wm = (idx < end) ? __expf(alv) : 0.f;
        #pragma unroll
        for (int k = 0; k < 8; ++k) {
            float wk = __shfl(wm, wsrc | k);
            if (k & 1) {
                q0 = fmaf(bflo(u[k]), wk, q0);
                q1 = fmaf(bfhi(u[k]), wk, q1);
                sB += wk;
            } else {
                p0 = fmaf(bflo(u[k]), wk, p0);
                p1 = fmaf(bfhi(u[k]), wk, p1);
                sA += wk;
            }
        }
    }
    float acc0 = p0 + q0, acc1 = p1 + q1, ssum = sA + sB;
    float inv = 1.f / (ssum + 1e-16f);
    acc0 *= inv; acc1 *= inv;
    acc0 = acc0 > 0.f ? acc0 : 0.f;   // relu
    acc1 = acc1 > 0.f ? acc1 : 0.f;
    outm[(size_t)wid * 64 + lane] = pack2bf(acc0, acc1);
}

// ---------------------------------------------------------------------------
// K6: semantic-attention scores via MFMA over bf16 out0/out1.
// ---------------------------------------------------------------------------
__global__ __launch_bounds__(256) void score_mfma(
    const unsigned* __restrict__ o0, const unsigned* __restrict__ o1,
    const uint4* __restrict__ bfg, const float* __restrict__ kb,
    const float* __restrict__ q, float* __restrict__ partials, int N)
{
    __shared__ uint4 Bf[2048];   // 32 KB (k_w fragments)
    __shared__ float kbs[128], qs[128];
    __shared__ float red[2];
    int t = threadIdx.x;
    for (int i = t; i < 2048; i += 256) Bf[i] = bfg[i];
    if (t < 128) { kbs[t] = kb[t]; qs[t] = q[t]; }
    if (t < 2) red[t] = 0.f;
    __syncthreads();
    int wid = t >> 6, l = t & 63, l15 = l & 15, lhi = l >> 4;
    float qv[8], kbv[8];
    #pragma unroll
    for (int nt = 0; nt < 8; ++nt) {
        qv[nt] = qs[nt * 16 + l15];
        kbv[nt] = kbs[nt * 16 + l15];
    }
    int ntiles = (N + 15) >> 4;
    int ttiles = 2 * ntiles;
    const uint4* A0 = reinterpret_cast<const uint4*>(o0);
    const uint4* A1 = reinterpret_cast<const uint4*>(o1);
    for (int tid = blockIdx.x * 4 + wid; tid < ttiles; tid += gridDim.x * 4) {
        int m = (tid >= ntiles);
        int rt = tid - (m ? ntiles : 0);
        const uint4* A = m ? A1 : A0;
        int row = rt * 16 + l15;
        f32x4 acc[8];
        #pragma unroll
        for (int nt = 0; nt < 8; ++nt) acc[nt] = (f32x4)(0.f);
        #pragma unroll
        for (int kt = 0; kt < 4; ++kt) {
            uint4 av = (row < N) ? A[(size_t)row * 16 + kt * 4 + lhi]
                                 : make_uint4(0u, 0u, 0u, 0u);
            short8 a = asfrag(av);
            #pragma unroll
            for (int nt = 0; nt < 8; ++nt)
                acc[nt] = mfma_bf16(a, asfrag(Bf[nt * 256 + kt * 64 + l]), acc[nt]);
        }
        float partial = 0.f;
        int rbase = rt * 16 + lhi * 4;
        #pragma unroll
        for (int r = 0; r < 4; ++r) {
            if (rbase + r < N) {
                #pragma unroll
                for (int nt = 0; nt < 8; ++nt)
                    partial += qv[nt] * tanh_fast(acc[nt][r] + kbv[nt]);
            }
        }
        partial += __shfl_xor(partial, 1);
        partial += __shfl_xor(partial, 2);
        partial += __shfl_xor(partial, 4);
        partial += __shfl_xor(partial, 8);
        partial += __shfl_xor(partial, 16);
        partial += __shfl_xor(partial, 32);
        if (l == 0) atomicAdd(&red[m], partial);
    }
    __syncthreads();
    if (t < 2) partials[blockIdx.x * 2 + t] = red[t];
}

// ---------------------------------------------------------------------------
// K7: y = (b0*out0 + b1*out1) @ out_w + out_b via MFMA (f32 output).
// beta fused: every block redundantly reduces the 2*SG partials (4KB, L2).
// ---------------------------------------------------------------------------
__global__ __launch_bounds__(256) void final_mfma(
    const unsigned* __restrict__ o0, const unsigned* __restrict__ o1,
    const uint4* __restrict__ bfg, const float* __restrict__ ob,
    const float* __restrict__ partials, int G, float invN,
    float* __restrict__ y, int N)
{
    __shared__ uint4 Bf[1024];   // 16 KB (out_w fragments)
    __shared__ float obs[64];
    __shared__ float r0s[256], r1s[256];
    int t = threadIdx.x;
    for (int i = t; i < 1024; i += 256) Bf[i] = bfg[i];
    if (t < 64) obs[t] = ob[t];
    // inline beta reduction (replicated per block)
    float s0 = 0.f, s1 = 0.f;
    for (int i = t; i < G; i += 256) { s0 += partials[i * 2]; s1 += partials[i * 2 + 1]; }
    r0s[t] = s0; r1s[t] = s1;
    __syncthreads();
    for (int o = 128; o > 0; o >>= 1) {
        if (t < o) { r0s[t] += r0s[t + o]; r1s[t] += r1s[t + o]; }
        __syncthreads();
    }
    float a = r0s[0] * invN, b = r1s[0] * invN;
    float mx = fmaxf(a, b);
    float ea = __expf(a - mx), eb = __expf(b - mx);
    float binv = 1.f / (ea + eb);
    float b0 = ea * binv, b1 = eb * binv;
    int wid = t >> 6, l = t & 63, l15 = l & 15, lhi = l >> 4;
    float obv[4];
    #pragma unroll
    for (int nt = 0; nt < 4; ++nt) obv[nt] = obs[nt * 16 + l15];
    int ntiles = (N + 15) >> 4;
    const uint4* A0 = reinterpret_cast<const uint4*>(o0);
    const uint4* A1 = reinterpret_cast<const uint4*>(o1);
    for (int rt = blockIdx.x * 4 + wid; rt < ntiles; rt += gridDim.x * 4) {
        int row = rt * 16 + l15;
        f32x4 acc[4];
        #pragma unroll
        for (int nt = 0; nt < 4; ++nt) acc[nt] = (f32x4)(0.f);
        #pragma unroll
        for (int kt = 0; kt < 4; ++kt) {
            uint4 af = make_uint4(0u, 0u, 0u, 0u);
            if (row < N) {
                uint4 a0 = A0[(size_t)row * 16 + kt * 4 + lhi];
                uint4 a1 = A1[(size_t)row * 16 + kt * 4 + lhi];
                af.x = pack2bf(b0 * bflo(a0.x) + b1 * bflo(a1.x),
                               b0 * bfhi(a0.x) + b1 * bfhi(a1.x));
                af.y = pack2bf(b0 * bflo(a0.y) + b1 * bflo(a1.y),
                               b0 * bfhi(a0.y) + b1 * bfhi(a1.y));
                af.z = pack2bf(b0 * bflo(a0.z) + b1 * bflo(a1.z),
                               b0 * bfhi(a0.z) + b1 * bfhi(a1.z));
                af.w = pack2bf(b0 * bflo(a0.w) + b1 * bflo(a1.w),
                               b0 * bfhi(a0.w) + b1 * bfhi(a1.w));
            }
            short8 a = asfrag(af);
            #pragma unroll
            for (int nt = 0; nt < 4; ++nt)
                acc[nt] = mfma_bf16(a, asfrag(Bf[nt * 256 + kt * 64 + l]), acc[nt]);
        }
        #pragma unroll
        for (int r = 0; r < 4; ++r) {
            int orow = rt * 16 + lhi * 4 + r;
            if (orow < N) {
                #pragma unroll
                for (int nt = 0; nt < 4; ++nt)
                    y[(size_t)orow * 64 + nt * 16 + l15] = acc[nt][r] + obv[nt];
            }
        }
    }
}

// ---------------------------------------------------------------------------
extern "C" void kernel_launch(void* const* d_in, const int* in_sizes, int n_in,
                              void* d_out, int out_size, void* d_ws, size_t ws_size,
                              hipStream_t stream)
{
    const float* x   = (const float*)d_in[0];
    const int*   ei0 = (const int*)d_in[1];
    const int*   ei1 = (const int*)d_in[2];
    const float* pw  = (const float*)d_in[3];
    const float* pb  = (const float*)d_in[4];
    const float* ls0 = (const float*)d_in[5];
    const float* ld0 = (const float*)d_in[6];
    const float* ls1 = (const float*)d_in[7];
    const float* ld1 = (const float*)d_in[8];
    const float* kw  = (const float*)d_in[9];
    const float* kb  = (const float*)d_in[10];
    const float* q   = (const float*)d_in[11];
    const float* ow  = (const float*)d_in[12];
    const float* ob  = (const float*)d_in[13];
    int N  = in_sizes[0] / 128;
    int E0 = in_sizes[1] / 2;
    int E1 = in_sizes[2] / 2;

    char* w = (char*)d_ws;
    size_t o = 0;
    auto alloc = [&](size_t bytes) -> void* {
        void* p = w + o;
        o += (bytes + 255) & ~(size_t)255;
        return p;
    };
    unsigned* hbf  = (unsigned*)alloc((size_t)N * 128 * 2);   // bf16 h
    float* as0  = (float*)alloc((size_t)N * 8 * 4);
    float* ad0  = (float*)alloc((size_t)N * 8 * 4);
    float* as1  = (float*)alloc((size_t)N * 8 * 4);
    float* ad1  = (float*)alloc((size_t)N * 8 * 4);
    unsigned* out0 = (unsigned*)alloc((size_t)N * 128 * 2);   // bf16 out
    unsigned* out1 = (unsigned*)alloc((size_t)N * 128 * 2);
    int* cnt0 = (int*)alloc((size_t)N * 4);
    int* cnt1 = (int*)alloc((size_t)N * 4);
    int* regionCur = (int*)alloc(16 * 4);
    int* perm3_0 = (int*)alloc((size_t)N * CAP * 4);
    int* perm3_1 = (int*)alloc((size_t)N * CAP * 4);
    float* partials = (float*)alloc((size_t)2 * 2048 * 4);
    uint4* bfpw = (uint4*)alloc(2048 * 16);
    uint4* bfkw = (uint4*)alloc(2048 * 16);
    uint4* bfow = (uint4*)alloc(1024 * 16);
    int Emax = E0 > E1 ? E0 : E1;
    int cap = Emax / 8 + Emax / 16 + 1024;     // 1.5x expected + slack
    unsigned* stage = (unsigned*)alloc((size_t)2 * 8 * cap * 4);
    int* wcnt = (int*)alloc((size_t)16 * PW * 4);

    int rsize = (N + 7) / 8;   // dst-region size for XCD ownership

    // NOTE: no memset needed — cnt (fill3b), regionCur (scanw), wcnt (count)
    // are fully rewritten every call; other buffers fully written before read.

    // K1: prep (3 blocks) + count (1024 blocks) — independent
    prep_count_kernel<<<1027, 256, 0, stream>>>(pw, kw, ow, bfpw, bfkw, bfow,
                                                ei0, E0, ei1, E1, wcnt, rsize);

    // K2: scanw (16) + proj (512) — independent
    proj_scanw_kernel<<<528, 256, 0, stream>>>(x, bfpw, pb,
                                               (unsigned short*)hbf, N,
                                               wcnt, regionCur);

    // K3: scatter (1024) + alpha — independent
    int ablocks = (N * 8 + 255) / 256;
    alpha_scatter_kernel<<<1024 + ablocks, 256, 0, stream>>>(
        ei0, E0, ei1, E1, wcnt, stage, cap, rsize,
        hbf, ls0, ld0, ls1, ld1, as0, ad0, as1, ad1, N);

    // K4: single-owner sub-window bucket fill (write amp ~1, zero atomics)
    fill3b_kernel<<<2 * 8 * JSUB, 256, 0, stream>>>(stage, cap, regionCur,
                                                    cnt0, perm3_0,
                                                    cnt1, perm3_1, rsize, N);

    // K5: aggregation
    int aggBlocks = 2 * ((N + 3) / 4);
    agg_fused<<<aggBlocks, 256, 0, stream>>>(cnt0, perm3_0, as0, ad0,
                                             cnt1, perm3_1, as1, ad1,
                                             hbf, out0, out1, N);

    // K6: semantic scores
    const int SG = 512;
    score_mfma<<<SG, 256, 0, stream>>>(out0, out1, bfkw, kb, q, partials, N);

    // K7: final projection with inlined beta
    final_mfma<<<512, 256, 0, stream>>>(out0, out1, bfow, ob,
                                        partials, SG, 1.0f / (float)N,
                                        (float*)d_out, N);
}

// Round 22
// 296.585 us; speedup vs baseline: 16.9712x; 1.3410x over previous
//
#include <hip/hip_runtime.h>
#include <hip/hip_bf16.h>

#define NEG 0.2f
#define CAP 64    // per-node bucket capacity; Poisson(16) max over 200K nodes ~45
#define JSUB 32   // sub-windows per region (single-owner write windows)

typedef __attribute__((ext_vector_type(8))) short short8;  // 8 bf16 (4 VGPR)
typedef __attribute__((ext_vector_type(4))) float f32x4;

// bf16 helpers (manual RNE pack / unpack, branch-free, no NaN inputs here)
__device__ __forceinline__ unsigned short f2bf(float f) {
    unsigned u = __float_as_uint(f);
    u += 0x7fffu + ((u >> 16) & 1u);
    return (unsigned short)(u >> 16);
}
__device__ __forceinline__ unsigned pack2bf(float a, float b) {
    return (unsigned)f2bf(a) | ((unsigned)f2bf(b) << 16);
}
__device__ __forceinline__ float bflo(unsigned u) { return __uint_as_float(u << 16); }
__device__ __forceinline__ float bfhi(unsigned u) { return __uint_as_float(u & 0xffff0000u); }

__device__ __forceinline__ short8 asfrag(uint4 v) {
    union { uint4 u; short8 s; } x; x.u = v; return x.s;
}
__device__ __forceinline__ f32x4 mfma_bf16(short8 a, short8 b, f32x4 c) {
    return __builtin_amdgcn_mfma_f32_16x16x32_bf16(a, b, c, 0, 0, 0);
}
__device__ __forceinline__ float tanh_fast(float x) {
    x = fminf(fmaxf(x, -15.f), 15.f);
    float t = __expf(2.f * x);
    return (t - 1.f) / (t + 1.f);
}

#define PW 2048   // waves per metapath in count/scatter (512 blocks x 4)

// ---------------------------------------------------------------------------
// device helpers for the fused phases
// ---------------------------------------------------------------------------
__device__ void prep_dev(int b, const float* __restrict__ pw,
                         const float* __restrict__ kw, const float* __restrict__ ow,
                         uint4* __restrict__ bfpw, uint4* __restrict__ bfkw,
                         uint4* __restrict__ bfow)
{
    const float* src = (b == 0) ? pw : (b == 1) ? kw : ow;
    uint4* dst = (b == 0) ? bfpw : (b == 1) ? bfkw : bfow;
    int ncol  = (b == 2) ? 64 : 128;
    int slots = (b == 2) ? 1024 : 2048;
    for (int i = threadIdx.x; i < slots; i += 256) {
        int nt = i >> 8, kt = (i >> 6) & 3, lane = i & 63;
        int row0 = kt * 32 + ((lane >> 4) << 3);
        int col  = nt * 16 + (lane & 15);
        float e[8];
        #pragma unroll
        for (int j = 0; j < 8; ++j) e[j] = src[(row0 + j) * ncol + col];
        uint4 v;
        v.x = pack2bf(e[0], e[1]); v.y = pack2bf(e[2], e[3]);
        v.z = pack2bf(e[4], e[5]); v.w = pack2bf(e[6], e[7]);
        dst[i] = v;
    }
}

__device__ void count_dev(int bb, const int* __restrict__ ei0, int E0,
                          const int* __restrict__ ei1, int E1,
                          int* __restrict__ wcnt, int rsize)
{
    int mp = bb & 1;
    int b  = bb >> 1;
    const int* ei = mp ? ei1 : ei0;
    int E = mp ? E1 : E0;
    int lane = threadIdx.x & 63;
    int gw = b * 4 + (threadIdx.x >> 6);
    int myCnt = 0;
    for (int base = gw * 64; base < E; base += PW * 64) {
        int e = base + lane;
        int r = (e < E) ? (ei[E + e] / rsize) : 8;
        #pragma unroll
        for (int rr = 0; rr < 8; ++rr) {
            unsigned long long mask = __ballot(r == rr);
            if (lane == rr) myCnt += __popcll(mask);
        }
    }
    if (lane < 8) wcnt[(mp * 8 + lane) * PW + gw] = myCnt;
}

// K1: prep (blocks 0-2) + count (blocks 3-1026) — independent work fused.
__global__ __launch_bounds__(256) void prep_count_kernel(
    const float* __restrict__ pw, const float* __restrict__ kw,
    const float* __restrict__ ow,
    uint4* __restrict__ bfpw, uint4* __restrict__ bfkw, uint4* __restrict__ bfow,
    const int* __restrict__ ei0, int E0, const int* __restrict__ ei1, int E1,
    int* __restrict__ wcnt, int rsize)
{
    if (blockIdx.x < 3) prep_dev(blockIdx.x, pw, kw, ow, bfpw, bfkw, bfow);
    else count_dev(blockIdx.x - 3, ei0, E0, ei1, E1, wcnt, rsize);
}

__device__ void scanw_dev(int row, int* __restrict__ wcnt, int* __restrict__ regionCur)
{
    int* p = wcnt + row * PW;
    int t = threadIdx.x;
    __shared__ int tsum[256];
    int v[8];
    int s = 0;
    #pragma unroll
    for (int j = 0; j < 8; ++j) { v[j] = p[t * 8 + j]; s += v[j]; }
    tsum[t] = s;
    __syncthreads();
    for (int ofs = 1; ofs < 256; ofs <<= 1) {
        int x = (t >= ofs) ? tsum[t - ofs] : 0;
        __syncthreads();
        tsum[t] += x;
        __syncthreads();
    }
    int base = (t > 0) ? tsum[t - 1] : 0;   // exclusive
    #pragma unroll
    for (int j = 0; j < 8; ++j) {
        int val = v[j];
        p[t * 8 + j] = base;
        base += val;
    }
    if (t == 255) regionCur[row] = tsum[255];
}

__device__ void proj_dev(int bid, int ngrid, const float* __restrict__ x,
                         const uint4* __restrict__ bfg, const float* __restrict__ pb,
                         unsigned short* __restrict__ hst, int N)
{
    __shared__ uint4 Bf[2048];   // 32 KB
    __shared__ float pbs[128];
    int t = threadIdx.x;
    for (int i = t; i < 2048; i += 256) Bf[i] = bfg[i];
    if (t < 128) pbs[t] = pb[t];
    __syncthreads();
    int wid = t >> 6, l = t & 63, l15 = l & 15, lhi = l >> 4;
    float bv[8];
    #pragma unroll
    for (int nt = 0; nt < 8; ++nt) bv[nt] = pbs[nt * 16 + l15];
    int ntiles = (N + 15) >> 4;
    const float4* X4 = reinterpret_cast<const float4*>(x);
    for (int rt = bid * 4 + wid; rt < ntiles; rt += ngrid * 4) {
        int row = rt * 16 + l15;
        f32x4 acc[8];
        #pragma unroll
        for (int nt = 0; nt < 8; ++nt) acc[nt] = (f32x4)(0.f);
        #pragma unroll
        for (int kt = 0; kt < 4; ++kt) {
            uint4 af = make_uint4(0u, 0u, 0u, 0u);
            if (row < N) {
                float4 xa = X4[(size_t)row * 32 + kt * 8 + lhi * 2];
                float4 xb = X4[(size_t)row * 32 + kt * 8 + lhi * 2 + 1];
                af.x = pack2bf(xa.x, xa.y); af.y = pack2bf(xa.z, xa.w);
                af.z = pack2bf(xb.x, xb.y); af.w = pack2bf(xb.z, xb.w);
            }
            short8 a = asfrag(af);
            #pragma unroll
            for (int nt = 0; nt < 8; ++nt)
                acc[nt] = mfma_bf16(a, asfrag(Bf[nt * 256 + kt * 64 + l]), acc[nt]);
        }
        #pragma unroll
        for (int r = 0; r < 4; ++r) {
            int orow = rt * 16 + lhi * 4 + r;
            if (orow < N) {
                #pragma unroll
                for (int nt = 0; nt < 8; ++nt)
                    hst[(size_t)orow * 128 + nt * 16 + l15] = f2bf(acc[nt][r] + bv[nt]);
            }
        }
    }
}

// K2: scanw (blocks 0-15) + proj (blocks 16-527).
__global__ __launch_bounds__(256) void proj_scanw_kernel(
    const float* __restrict__ x, const uint4* __restrict__ bfg,
    const float* __restrict__ pb, unsigned short* __restrict__ hst, int N,
    int* __restrict__ wcnt, int* __restrict__ regionCur)
{
    if (blockIdx.x < 16) scanw_dev(blockIdx.x, wcnt, regionCur);
    else proj_dev(blockIdx.x - 16, 512, x, bfg, pb, hst, N);
}

__device__ void scatter_dev(int bb, const int* __restrict__ ei0, int E0,
                            const int* __restrict__ ei1, int E1,
                            const int* __restrict__ wcnt,
                            unsigned* __restrict__ stage, int cap, int rsize)
{
    int mp = bb & 1;
    int b  = bb >> 1;
    const int* ei = mp ? ei1 : ei0;
    int E = mp ? E1 : E0;
    unsigned* st = stage + (size_t)mp * 8 * cap;
    int lane = threadIdx.x & 63;
    int gw = b * 4 + (threadIdx.x >> 6);
    int myBase = (lane < 8) ? wcnt[(mp * 8 + lane) * PW + gw] : 0;
    for (int base = gw * 64; base < E; base += PW * 64) {
        int e = base + lane;
        bool valid = e < E;
        int d = valid ? ei[E + e] : 0;
        int s = valid ? ei[e] : 0;
        int r = valid ? (d / rsize) : 8;
        unsigned packed = ((unsigned)(d - r * rsize) << 17) | (unsigned)s;
        #pragma unroll
        for (int rr = 0; rr < 8; ++rr) {
            unsigned long long mask = __ballot(r == rr);
            int bse = __shfl(myBase, rr);
            if (r == rr) {
                int pos = __popcll(mask & ((1ull << lane) - 1ull));
                st[(size_t)rr * cap + bse + pos] = packed;
            }
            if (lane == rr) myBase += __popcll(mask);
        }
    }
}

__device__ void alpha_dev(int bid, const unsigned* __restrict__ hbf,
    const float* __restrict__ ls0, const float* __restrict__ ld0,
    const float* __restrict__ ls1, const float* __restrict__ ld1,
    float* __restrict__ as0, float* __restrict__ ad0,
    float* __restrict__ as1, float* __restrict__ ad1, int N)
{
    __shared__ float lin[512];
    int t = threadIdx.x;
    for (int i = t; i < 128; i += 256) {
        lin[i] = ls0[i]; lin[128 + i] = ld0[i];
        lin[256 + i] = ls1[i]; lin[384 + i] = ld1[i];
    }
    __syncthreads();
    int idx = bid * 256 + t;
    if (idx >= N * 8) return;
    int node = idx >> 3, head = idx & 7;
    const uint4* H = reinterpret_cast<const uint4*>(hbf);
    uint4 va = H[(size_t)node * 16 + head * 2];
    uint4 vb = H[(size_t)node * 16 + head * 2 + 1];
    float h[16];
    h[0] = bflo(va.x); h[1] = bfhi(va.x); h[2] = bflo(va.y); h[3] = bfhi(va.y);
    h[4] = bflo(va.z); h[5] = bfhi(va.z); h[6] = bflo(va.w); h[7] = bfhi(va.w);
    h[8] = bflo(vb.x); h[9] = bfhi(vb.x); h[10] = bflo(vb.y); h[11] = bfhi(vb.y);
    h[12] = bflo(vb.z); h[13] = bfhi(vb.z); h[14] = bflo(vb.w); h[15] = bfhi(vb.w);
    int base = head * 16;
    float d0 = 0.f, d1 = 0.f, d2 = 0.f, d3 = 0.f;
    #pragma unroll
    for (int d = 0; d < 16; ++d) {
        float hv = h[d];
        d0 = fmaf(hv, lin[base + d], d0);
        d1 = fmaf(hv, lin[128 + base + d], d1);
        d2 = fmaf(hv, lin[256 + base + d], d2);
        d3 = fmaf(hv, lin[384 + base + d], d3);
    }
    as0[idx] = d0; ad0[idx] = d1; as1[idx] = d2; ad1[idx] = d3;
}

// K3: scatter (blocks 0-1023) + alpha (blocks 1024+).
__global__ __launch_bounds__(256) void alpha_scatter_kernel(
    const int* __restrict__ ei0, int E0, const int* __restrict__ ei1, int E1,
    const int* __restrict__ wcnt, unsigned* __restrict__ stage, int cap, int rsize,
    const unsigned* __restrict__ hbf,
    const float* __restrict__ ls0, const float* __restrict__ ld0,
    const float* __restrict__ ls1, const float* __restrict__ ld1,
    float* __restrict__ as0, float* __restrict__ ad0,
    float* __restrict__ as1, float* __restrict__ ad1, int N)
{
    if (blockIdx.x < 1024)
        scatter_dev(blockIdx.x, ei0, E0, ei1, E1, wcnt, stage, cap, rsize);
    else
        alpha_dev(blockIdx.x - 1024, hbf, ls0, ld0, ls1, ld1,
                  as0, ad0, as1, ad1, N);
}

// ---------------------------------------------------------------------------
// K4: single-owner sub-window bucket fill, HIGH-OCCUPANCY version.
// R19 showed 11% occupancy (256 blocks x 256 thr = 1 block/CU, 4 waves) ->
// stream read latency-bound at 754 GB/s.  Now 512 blocks x 1024 thr =
// 2 blocks/CU, 32 waves/CU.  Window = rsize/32 (~391 nodes); still single
// owner -> zero global atomics, write amp ~1, cnt written non-atomically.
// ---------------------------------------------------------------------------
__global__ __launch_bounds__(1024) void fill3b_kernel(
    const unsigned* __restrict__ stage, int cap, const int* __restrict__ regionCur,
    int* __restrict__ cnt0, int* __restrict__ perm3_0,
    int* __restrict__ cnt1, int* __restrict__ perm3_1, int rsize, int N)
{
    __shared__ int lcnt[512];
    int j  = blockIdx.x & (JSUB - 1);
    int r  = (blockIdx.x / JSUB) & 7;
    int mp = blockIdx.x / (JSUB * 8);
    const unsigned* st = stage + ((size_t)mp * 8 + r) * cap;
    int cnt = regionCur[mp * 8 + r];
    int wsize = (rsize + JSUB - 1) / JSUB;
    int w0 = j * wsize;
    int w1 = w0 + wsize; if (w1 > rsize) w1 = rsize;
    int dbase = r * rsize;
    int* cn = mp ? cnt1 : cnt0;
    int* pm = mp ? perm3_1 : perm3_0;
    for (int i = threadIdx.x; i < wsize; i += 1024) lcnt[i] = 0;
    __syncthreads();
    int i = threadIdx.x;
    for (; i + 3072 < cnt; i += 4096) {
        unsigned v0 = st[i];
        unsigned v1 = st[i + 1024];
        unsigned v2 = st[i + 2048];
        unsigned v3 = st[i + 3072];
        int d0 = (int)(v0 >> 17), d1 = (int)(v1 >> 17);
        int d2 = (int)(v2 >> 17), d3 = (int)(v3 >> 17);
        if (d0 >= w0 && d0 < w1) {
            int pos = atomicAdd(&lcnt[d0 - w0], 1);
            if (pos < CAP) pm[(size_t)(dbase + d0) * CAP + pos] = (int)(v0 & 0x1FFFFu);
        }
        if (d1 >= w0 && d1 < w1) {
            int pos = atomicAdd(&lcnt[d1 - w0], 1);
            if (pos < CAP) pm[(size_t)(dbase + d1) * CAP + pos] = (int)(v1 & 0x1FFFFu);
        }
        if (d2 >= w0 && d2 < w1) {
            int pos = atomicAdd(&lcnt[d2 - w0], 1);
            if (pos < CAP) pm[(size_t)(dbase + d2) * CAP + pos] = (int)(v2 & 0x1FFFFu);
        }
        if (d3 >= w0 && d3 < w1) {
            int pos = atomicAdd(&lcnt[d3 - w0], 1);
            if (pos < CAP) pm[(size_t)(dbase + d3) * CAP + pos] = (int)(v3 & 0x1FFFFu);
        }
    }
    for (; i < cnt; i += 1024) {
        unsigned v = st[i];
        int dl = (int)(v >> 17);
        if (dl >= w0 && dl < w1) {
            int pos = atomicAdd(&lcnt[dl - w0], 1);
            if (pos < CAP) pm[(size_t)(dbase + dl) * CAP + pos] = (int)(v & 0x1FFFFu);
        }
    }
    __syncthreads();
    for (int k = threadIdx.x; k < wsize; k += 1024) {
        int dl = w0 + k;
        int d = dbase + dl;
        if (dl < rsize && d < N) cn[d] = lcnt[k];
    }
}

// ---------------------------------------------------------------------------
// K5: per-destination aggregation (fused mp0+mp1), bucket layout.
// Lane-specialized weights + batched gather arrays (R15 structure).
// ---------------------------------------------------------------------------
__global__ __launch_bounds__(256) void agg_fused(
    const int* __restrict__ cnt0, const int* __restrict__ perm3_0,
    const float* __restrict__ as0, const float* __restrict__ ad0,
    const int* __restrict__ cnt1, const int* __restrict__ perm3_1,
    const float* __restrict__ as1, const float* __restrict__ ad1,
    const unsigned* __restrict__ hbf,
    unsigned* __restrict__ o0, unsigned* __restrict__ o1, int N)
{
    int mp = blockIdx.x & 1;
    int wid = (blockIdx.x >> 1) * 4 + (threadIdx.x >> 6);
    int lane = threadIdx.x & 63;
    if (wid >= N) return;
    const int* cn = mp ? cnt1 : cnt0;
    const int* perm = mp ? perm3_1 : perm3_0;
    const float* asrc = mp ? as1 : as0;
    const float* adst = mp ? ad1 : ad0;
    unsigned* outm = mp ? o1 : o0;
    int deg = cn[wid];
    deg = deg < CAP ? deg : CAP;
    int start = wid * CAP, end = start + deg;
    int h2 = lane >> 3;            // head: owns dims AND weight computation
    int esel = lane & 7;           // edge slot this lane computes weight for
    int wsrc = lane & 56;          // shuffle base: lane (wsrc|k) holds w[k][h2]
    float av = adst[wid * 8 + h2];
    float p0 = 0.f, p1 = 0.f, q0 = 0.f, q1 = 0.f;
    float sA = 0.f, sB = 0.f;
    for (int i = start; i < end; i += 8) {
        int idx = i + esel;
        int sm = perm[idx < end ? idx : start];
        int sk[8];
        #pragma unroll
        for (int k = 0; k < 8; ++k) sk[k] = __shfl(sm, k);
        unsigned u[8];
        #pragma unroll
        for (int k = 0; k < 8; ++k) u[k] = hbf[(unsigned)(sk[k] * 64) + lane];
        float alv = asrc[sm * 8 + h2] + av;
        alv = alv > 0.f ? alv : NEG * alv;
        float wm = (idx < end) ? __expf(alv) : 0.f;
        #pragma unroll
        for (int k = 0; k < 8; ++k) {
            float wk = __shfl(wm, wsrc | k);
            if (k & 1) {
                q0 = fmaf(bflo(u[k]), wk, q0);
                q1 = fmaf(bfhi(u[k]), wk, q1);
                sB += wk;
            } else {
                p0 = fmaf(bflo(u[k]), wk, p0);
                p1 = fmaf(bfhi(u[k]), wk, p1);
                sA += wk;
            }
        }
    }
    float acc0 = p0 + q0, acc1 = p1 + q1, ssum = sA + sB;
    float inv = 1.f / (ssum + 1e-16f);
    acc0 *= inv; acc1 *= inv;
    acc0 = acc0 > 0.f ? acc0 : 0.f;   // relu
    acc1 = acc1 > 0.f ? acc1 : 0.f;
    outm[(size_t)wid * 64 + lane] = pack2bf(acc0, acc1);
}

// ---------------------------------------------------------------------------
// K6: semantic-attention scores via MFMA over bf16 out0/out1.
// ---------------------------------------------------------------------------
__global__ __launch_bounds__(256) void score_mfma(
    const unsigned* __restrict__ o0, const unsigned* __restrict__ o1,
    const uint4* __restrict__ bfg, const float* __restrict__ kb,
    const float* __restrict__ q, float* __restrict__ partials, int N)
{
    __shared__ uint4 Bf[2048];   // 32 KB (k_w fragments)
    __shared__ float kbs[128], qs[128];
    __shared__ float red[2];
    int t = threadIdx.x;
    for (int i = t; i < 2048; i += 256) Bf[i] = bfg[i];
    if (t < 128) { kbs[t] = kb[t]; qs[t] = q[t]; }
    if (t < 2) red[t] = 0.f;
    __syncthreads();
    int wid = t >> 6, l = t & 63, l15 = l & 15, lhi = l >> 4;
    float qv[8], kbv[8];
    #pragma unroll
    for (int nt = 0; nt < 8; ++nt) {
        qv[nt] = qs[nt * 16 + l15];
        kbv[nt] = kbs[nt * 16 + l15];
    }
    int ntiles = (N + 15) >> 4;
    int ttiles = 2 * ntiles;
    const uint4* A0 = reinterpret_cast<const uint4*>(o0);
    const uint4* A1 = reinterpret_cast<const uint4*>(o1);
    for (int tid = blockIdx.x * 4 + wid; tid < ttiles; tid += gridDim.x * 4) {
        int m = (tid >= ntiles);
        int rt = tid - (m ? ntiles : 0);
        const uint4* A = m ? A1 : A0;
        int row = rt * 16 + l15;
        f32x4 acc[8];
        #pragma unroll
        for (int nt = 0; nt < 8; ++nt) acc[nt] = (f32x4)(0.f);
        #pragma unroll
        for (int kt = 0; kt < 4; ++kt) {
            uint4 av = (row < N) ? A[(size_t)row * 16 + kt * 4 + lhi]
                                 : make_uint4(0u, 0u, 0u, 0u);
            short8 a = asfrag(av);
            #pragma unroll
            for (int nt = 0; nt < 8; ++nt)
                acc[nt] = mfma_bf16(a, asfrag(Bf[nt * 256 + kt * 64 + l]), acc[nt]);
        }
        float partial = 0.f;
        int rbase = rt * 16 + lhi * 4;
        #pragma unroll
        for (int r = 0; r < 4; ++r) {
            if (rbase + r < N) {
                #pragma unroll
                for (int nt = 0; nt < 8; ++nt)
                    partial += qv[nt] * tanh_fast(acc[nt][r] + kbv[nt]);
            }
        }
        partial += __shfl_xor(partial, 1);
        partial += __shfl_xor(partial, 2);
        partial += __shfl_xor(partial, 4);
        partial += __shfl_xor(partial, 8);
        partial += __shfl_xor(partial, 16);
        partial += __shfl_xor(partial, 32);
        if (l == 0) atomicAdd(&red[m], partial);
    }
    __syncthreads();
    if (t < 2) partials[blockIdx.x * 2 + t] = red[t];
}

// ---------------------------------------------------------------------------
// K7: y = (b0*out0 + b1*out1) @ out_w + out_b via MFMA (f32 output).
// beta fused: every block redundantly reduces the 2*SG partials (4KB, L2).
// ---------------------------------------------------------------------------
__global__ __launch_bounds__(256) void final_mfma(
    const unsigned* __restrict__ o0, const unsigned* __restrict__ o1,
    const uint4* __restrict__ bfg, const float* __restrict__ ob,
    const float* __restrict__ partials, int G, float invN,
    float* __restrict__ y, int N)
{
    __shared__ uint4 Bf[1024];   // 16 KB (out_w fragments)
    __shared__ float obs[64];
    __shared__ float r0s[256], r1s[256];
    int t = threadIdx.x;
    for (int i = t; i < 1024; i += 256) Bf[i] = bfg[i];
    if (t < 64) obs[t] = ob[t];
    // inline beta reduction (replicated per block)
    float s0 = 0.f, s1 = 0.f;
    for (int i = t; i < G; i += 256) { s0 += partials[i * 2]; s1 += partials[i * 2 + 1]; }
    r0s[t] = s0; r1s[t] = s1;
    __syncthreads();
    for (int o = 128; o > 0; o >>= 1) {
        if (t < o) { r0s[t] += r0s[t + o]; r1s[t] += r1s[t + o]; }
        __syncthreads();
    }
    float a = r0s[0] * invN, b = r1s[0] * invN;
    float mx = fmaxf(a, b);
    float ea = __expf(a - mx), eb = __expf(b - mx);
    float binv = 1.f / (ea + eb);
    float b0 = ea * binv, b1 = eb * binv;
    int wid = t >> 6, l = t & 63, l15 = l & 15, lhi = l >> 4;
    float obv[4];
    #pragma unroll
    for (int nt = 0; nt < 4; ++nt) obv[nt] = obs[nt * 16 + l15];
    int ntiles = (N + 15) >> 4;
    const uint4* A0 = reinterpret_cast<const uint4*>(o0);
    const uint4* A1 = reinterpret_cast<const uint4*>(o1);
    for (int rt = blockIdx.x * 4 + wid; rt < ntiles; rt += gridDim.x * 4) {
        int row = rt * 16 + l15;
        f32x4 acc[4];
        #pragma unroll
        for (int nt = 0; nt < 4; ++nt) acc[nt] = (f32x4)(0.f);
        #pragma unroll
        for (int kt = 0; kt < 4; ++kt) {
            uint4 af = make_uint4(0u, 0u, 0u, 0u);
            if (row < N) {
                uint4 a0 = A0[(size_t)row * 16 + kt * 4 + lhi];
                uint4 a1 = A1[(size_t)row * 16 + kt * 4 + lhi];
                af.x = pack2bf(b0 * bflo(a0.x) + b1 * bflo(a1.x),
                               b0 * bfhi(a0.x) + b1 * bfhi(a1.x));
                af.y = pack2bf(b0 * bflo(a0.y) + b1 * bflo(a1.y),
                               b0 * bfhi(a0.y) + b1 * bfhi(a1.y));
                af.z = pack2bf(b0 * bflo(a0.z) + b1 * bflo(a1.z),
                               b0 * bfhi(a0.z) + b1 * bfhi(a1.z));
                af.w = pack2bf(b0 * bflo(a0.w) + b1 * bflo(a1.w),
                               b0 * bfhi(a0.w) + b1 * bfhi(a1.w));
            }
            short8 a = asfrag(af);
            #pragma unroll
            for (int nt = 0; nt < 4; ++nt)
                acc[nt] = mfma_bf16(a, asfrag(Bf[nt * 256 + kt * 64 + l]), acc[nt]);
        }
        #pragma unroll
        for (int r = 0; r < 4; ++r) {
            int orow = rt * 16 + lhi * 4 + r;
            if (orow < N) {
                #pragma unroll
                for (int nt = 0; nt < 4; ++nt)
                    y[(size_t)orow * 64 + nt * 16 + l15] = acc[nt][r] + obv[nt];
            }
        }
    }
}

// ---------------------------------------------------------------------------
extern "C" void kernel_launch(void* const* d_in, const int* in_sizes, int n_in,
                              void* d_out, int out_size, void* d_ws, size_t ws_size,
                              hipStream_t stream)
{
    const float* x   = (const float*)d_in[0];
    const int*   ei0 = (const int*)d_in[1];
    const int*   ei1 = (const int*)d_in[2];
    const float* pw  = (const float*)d_in[3];
    const float* pb  = (const float*)d_in[4];
    const float* ls0 = (const float*)d_in[5];
    const float* ld0 = (const float*)d_in[6];
    const float* ls1 = (const float*)d_in[7];
    const float* ld1 = (const float*)d_in[8];
    const float* kw  = (const float*)d_in[9];
    const float* kb  = (const float*)d_in[10];
    const float* q   = (const float*)d_in[11];
    const float* ow  = (const float*)d_in[12];
    const float* ob  = (const float*)d_in[13];
    int N  = in_sizes[0] / 128;
    int E0 = in_sizes[1] / 2;
    int E1 = in_sizes[2] / 2;

    char* w = (char*)d_ws;
    size_t o = 0;
    auto alloc = [&](size_t bytes) -> void* {
        void* p = w + o;
        o += (bytes + 255) & ~(size_t)255;
        return p;
    };
    unsigned* hbf  = (unsigned*)alloc((size_t)N * 128 * 2);   // bf16 h
    float* as0  = (float*)alloc((size_t)N * 8 * 4);
    float* ad0  = (float*)alloc((size_t)N * 8 * 4);
    float* as1  = (float*)alloc((size_t)N * 8 * 4);
    float* ad1  = (float*)alloc((size_t)N * 8 * 4);
    unsigned* out0 = (unsigned*)alloc((size_t)N * 128 * 2);   // bf16 out
    unsigned* out1 = (unsigned*)alloc((size_t)N * 128 * 2);
    int* cnt0 = (int*)alloc((size_t)N * 4);
    int* cnt1 = (int*)alloc((size_t)N * 4);
    int* regionCur = (int*)alloc(16 * 4);
    int* perm3_0 = (int*)alloc((size_t)N * CAP * 4);
    int* perm3_1 = (int*)alloc((size_t)N * CAP * 4);
    float* partials = (float*)alloc((size_t)2 * 2048 * 4);
    uint4* bfpw = (uint4*)alloc(2048 * 16);
    uint4* bfkw = (uint4*)alloc(2048 * 16);
    uint4* bfow = (uint4*)alloc(1024 * 16);
    int Emax = E0 > E1 ? E0 : E1;
    int cap = Emax / 8 + Emax / 16 + 1024;     // 1.5x expected + slack
    unsigned* stage = (unsigned*)alloc((size_t)2 * 8 * cap * 4);
    int* wcnt = (int*)alloc((size_t)16 * PW * 4);

    int rsize = (N + 7) / 8;   // dst-region size for XCD ownership

    // NOTE: no memset needed — cnt (fill3b), regionCur (scanw), wcnt (count)
    // are fully rewritten every call; other buffers fully written before read.

    // K1: prep (3 blocks) + count (1024 blocks) — independent
    prep_count_kernel<<<1027, 256, 0, stream>>>(pw, kw, ow, bfpw, bfkw, bfow,
                                                ei0, E0, ei1, E1, wcnt, rsize);

    // K2: scanw (16) + proj (512) — independent
    proj_scanw_kernel<<<528, 256, 0, stream>>>(x, bfpw, pb,
                                               (unsigned short*)hbf, N,
                                               wcnt, regionCur);

    // K3: scatter (1024) + alpha — independent
    int ablocks = (N * 8 + 255) / 256;
    alpha_scatter_kernel<<<1024 + ablocks, 256, 0, stream>>>(
        ei0, E0, ei1, E1, wcnt, stage, cap, rsize,
        hbf, ls0, ld0, ls1, ld1, as0, ad0, as1, ad1, N);

    // K4: single-owner sub-window bucket fill (high occupancy)
    fill3b_kernel<<<2 * 8 * JSUB, 1024, 0, stream>>>(stage, cap, regionCur,
                                                     cnt0, perm3_0,
                                                     cnt1, perm3_1, rsize, N);

    // K5: aggregation
    int aggBlocks = 2 * ((N + 3) / 4);
    agg_fused<<<aggBlocks, 256, 0, stream>>>(cnt0, perm3_0, as0, ad0,
                                             cnt1, perm3_1, as1, ad1,
                                             hbf, out0, out1, N);

    // K6: semantic scores
    const int SG = 512;
    score_mfma<<<SG, 256, 0, stream>>>(out0, out1, bfkw, kb, q, partials, N);

    // K7: final projection with inlined beta
    final_mfma<<<512, 256, 0, stream>>>(out0, out1, bfow, ob,
                                        partials, SG, 1.0f / (float)N,
                                        (float*)d_out, N);
}